// Round 8
// baseline (723.851 us; speedup 1.0000x reference)
//
#include <hip/hip_runtime.h>
#include <hip/hip_bf16.h>

#define BB 32
#define NN 512
#define DA 100
#define DIN 64
#define HH 128
#define E1 4
#define DOUT 16
#define NPROP 5
#define NS2V 3
#define MHALF 8192          // rows per half-batch (16 graphs)

typedef __attribute__((ext_vector_type(8))) short bf16x8;
typedef __attribute__((ext_vector_type(4))) float f32x4;
typedef __attribute__((ext_vector_type(4))) unsigned short us4;
typedef __attribute__((ext_vector_type(8))) unsigned short us8;
typedef unsigned short ushort_t;

__device__ __forceinline__ unsigned short f2bf(float f) {
    __hip_bfloat16 h = __float2bfloat16(f);
    return *reinterpret_cast<unsigned short*>(&h);
}
__device__ __forceinline__ float bf2f(unsigned short u) {
    unsigned v = ((unsigned)u) << 16;
    float f;
    __builtin_memcpy(&f, &v, 4);
    return f;
}

// ---------------- pack A bits: L[b,m,n,e] != 0 -> bit n%32 of Abits[((b*E1+e)*N+m)*16 + n/32]
__global__ void pack_A_kernel(const float* __restrict__ L, unsigned* __restrict__ Abits) {
    int t = blockIdx.x * blockDim.x + threadIdx.x;   // (b, m, w)
    if (t >= BB * NN * (NN / 32)) return;
    int w = t & 15;
    int m = (t >> 4) & (NN - 1);
    int b = t >> (4 + 9);
    const float* src = L + ((size_t)(b * NN + m) * NN + 32 * w) * E1;
    unsigned bits[E1] = {0u, 0u, 0u, 0u};
    #pragma unroll 8
    for (int j = 0; j < 32; ++j) {
        float4 v = *reinterpret_cast<const float4*>(src + j * 4);
        if (v.x != 0.f) bits[0] |= (1u << j);
        if (v.y != 0.f) bits[1] |= (1u << j);
        if (v.z != 0.f) bits[2] |= (1u << j);
        if (v.w != 0.f) bits[3] |= (1u << j);
    }
    #pragma unroll
    for (int e = 0; e < E1; ++e)
        Abits[((b * E1 + e) * NN + m) * 16 + w] = bits[e];
}

// ---------------- fused-weight precompute:
// U[j, e*128+h] = sum_k wih[j, e*128+k] * edge_emb[e, h*128+k]   (fp32, then split bf16)
// whh split bf16
__global__ void convW_kernel(const float* __restrict__ EE, const float* __restrict__ wih,
                             const float* __restrict__ whh,
                             ushort_t* __restrict__ U_h, ushort_t* __restrict__ U_l,
                             ushort_t* __restrict__ whh_h, ushort_t* __restrict__ whh_l) {
    int t = blockIdx.x * blockDim.x + threadIdx.x;
    if (t < 384 * 512) {
        int col = t & 511;
        int j = t >> 9;
        int e = col >> 7, h = col & 127;
        const float4* wp = reinterpret_cast<const float4*>(wih + (size_t)j * 512 + e * 128);
        const float4* ep = reinterpret_cast<const float4*>(EE + (size_t)e * 16384 + h * 128);
        float acc = 0.f;
        #pragma unroll 8
        for (int k4 = 0; k4 < 32; ++k4) {
            float4 a = wp[k4], b = ep[k4];
            acc = fmaf(a.x, b.x, fmaf(a.y, b.y, fmaf(a.z, b.z, fmaf(a.w, b.w, acc))));
        }
        unsigned short hi = f2bf(acc);
        U_h[t] = hi;
        U_l[t] = f2bf(acc - bf2f(hi));
        return;
    }
    int t2 = t - 384 * 512;
    if (t2 < 384 * 128) {
        float v = whh[t2];
        unsigned short hi = f2bf(v);
        whh_h[t2] = hi;
        whh_l[t2] = f2bf(v - bf2f(hi));
    }
}

// ---------------- embed: state[row, h] = node_emb[nf[row]] . W_in[h,:] + b_in[h] -> split planes
__global__ void embed_kernel(const int* __restrict__ nf, const float* __restrict__ emb,
                             const float* __restrict__ Win, const float* __restrict__ bin,
                             ushort_t* __restrict__ s_hi, ushort_t* __restrict__ s_lo) {
    int row = blockIdx.x;
    int h = threadIdx.x;
    __shared__ float e[DIN];
    int a = nf[row];
    if (h < DIN) e[h] = emb[a * DIN + h];
    __syncthreads();
    float acc = bin[h];
    const float* w = Win + h * DIN;
    #pragma unroll
    for (int d = 0; d < DIN; ++d) acc = fmaf(e[d], w[d], acc);
    unsigned short hi = f2bf(acc);
    s_hi[row * HH + h] = hi;
    s_lo[row * HH + h] = f2bf(acc - bf2f(hi));
}

// ---------------- transpose state planes: [16384][128] -> [128][16384]  (once, after embed)
__global__ __launch_bounds__(256) void transpose_kernel(const ushort_t* __restrict__ src,
                                                        ushort_t* __restrict__ dst,
                                                        size_t splane) {
    __shared__ __align__(16) ushort_t tile[128][72];
    int row0 = blockIdx.x * 64;
    int tid = threadIdx.x;
    #pragma unroll
    for (int pl = 0; pl < 2; ++pl) {
        const ushort_t* s = src + pl * splane;
        ushort_t* d = dst + pl * splane;
        #pragma unroll
        for (int q = 0; q < 4; ++q) {
            int idx = q * 256 + tid;
            int r = idx >> 4, h8 = idx & 15;
            bf16x8 v = *reinterpret_cast<const bf16x8*>(s + (size_t)(row0 + r) * HH + h8 * 8);
            #pragma unroll
            for (int j = 0; j < 8; ++j) tile[h8 * 8 + j][r] = (ushort_t)v[j];
        }
        __syncthreads();
        {
            int h = tid >> 1, rseg = (tid & 1) * 32;
            #pragma unroll
            for (int s8 = 0; s8 < 4; ++s8) {
                us8 v = *reinterpret_cast<const us8*>(&tile[h][rseg + s8 * 8]);
                *reinterpret_cast<us8*>(&d[(size_t)h * 16384 + row0 + rseg + s8 * 8]) = v;
            }
        }
        __syncthreads();
    }
}

// ---------------- split-bf16 MFMA GEMM (S2 path): C = A_bits @ stateT^T per (b,e)
// BM=128, BN=64, BK=32, 256 threads = 4 waves (2x2)
template <int MODE, bool AGG, bool XBITS, int K, bool XSPLIT, bool WSPLIT>
__global__ __launch_bounds__(256) void mm_kernel(const void* __restrict__ Xp, size_t xplane,
                                                 const ushort_t* __restrict__ W, size_t wplane,
                                                 const float* __restrict__ bias,
                                                 void* __restrict__ outv, size_t oplane,
                                                 int ldx, int ldw, int ldo) {
    __shared__ __align__(16) ushort_t Xs[2][128 * 40];
    __shared__ __align__(16) ushort_t Ws[2][64 * 40];
    int tid = threadIdx.x;
    int row0 = blockIdx.y * 128, col0 = blockIdx.x * 64;
    const ushort_t* X = (const ushort_t*)Xp;
    const unsigned* Xb = (const unsigned*)Xp;
    size_t out_off = 0;
    int wko = 0;
    if constexpr (AGG) {
        int e = blockIdx.z & 3, bl = blockIdx.z >> 2;
        Xb += (size_t)blockIdx.z * NN * 16;               // A bits for (b_local, e)
        wko = bl * NN;                                    // stateT column offset (n base)
        out_off = (size_t)bl * NN * NN + (size_t)e * HH;  // S2cat[(bl*512+m)*512 + e*128 + h]
    }
    int lane = tid & 63;
    int wave = tid >> 6;
    int wm = wave & 1, wn = wave >> 1;
    int r16 = lane & 15, kg = lane >> 4;

    f32x4 acc[4][2] = {};

    for (int k0 = 0; k0 < K; k0 += 32) {
        bf16x8 xh[2], xl[2];
        unsigned xword;
        if constexpr (XBITS) {
            int m = tid >> 1;
            xword = Xb[(size_t)(row0 + m) * 16 + (k0 >> 5)];
        } else {
            #pragma unroll
            for (int q = 0; q < 2; ++q) {
                int chunk = q * 256 + tid;
                int r = chunk >> 2, kc = chunk & 3;
                const ushort_t* xp = X + (size_t)(row0 + r) * ldx + k0 + kc * 8;
                xh[q] = *reinterpret_cast<const bf16x8*>(xp);
                if constexpr (XSPLIT) xl[q] = *reinterpret_cast<const bf16x8*>(xp + xplane);
            }
        }
        bf16x8 wh, wl;
        {
            int r = tid >> 2, kc = tid & 3;
            const ushort_t* wp2 = W + (size_t)(col0 + r) * ldw + wko + k0 + kc * 8;
            wh = *reinterpret_cast<const bf16x8*>(wp2);
            if constexpr (WSPLIT) wl = *reinterpret_cast<const bf16x8*>(wp2 + wplane);
        }
        __syncthreads();
        if constexpr (XBITS) {
            int m = tid >> 1, sel = tid & 1;
            #pragma unroll
            for (int j8 = 0; j8 < 2; ++j8) {
                bf16x8 xv;
                #pragma unroll
                for (int j = 0; j < 8; ++j)
                    xv[j] = (short)(((xword >> (sel * 16 + j8 * 8 + j)) & 1u) ? 0x3F80 : 0);
                *reinterpret_cast<bf16x8*>(&Xs[0][m * 40 + sel * 16 + j8 * 8]) = xv;
            }
        } else {
            #pragma unroll
            for (int q = 0; q < 2; ++q) {
                int chunk = q * 256 + tid;
                int r = chunk >> 2, kc = chunk & 3;
                *reinterpret_cast<bf16x8*>(&Xs[0][r * 40 + kc * 8]) = xh[q];
                if constexpr (XSPLIT)
                    *reinterpret_cast<bf16x8*>(&Xs[1][r * 40 + kc * 8]) = xl[q];
            }
        }
        {
            int r = tid >> 2, kc = tid & 3;
            *reinterpret_cast<bf16x8*>(&Ws[0][r * 40 + kc * 8]) = wh;
            if constexpr (WSPLIT)
                *reinterpret_cast<bf16x8*>(&Ws[1][r * 40 + kc * 8]) = wl;
        }
        __syncthreads();
        bf16x8 af_h[4], af_l[4], bf_h[2], bf_l[2];
        #pragma unroll
        for (int mi = 0; mi < 4; ++mi) {
            af_h[mi] = *reinterpret_cast<const bf16x8*>(&Xs[0][(wm * 64 + mi * 16 + r16) * 40 + kg * 8]);
            if constexpr (XSPLIT)
                af_l[mi] = *reinterpret_cast<const bf16x8*>(&Xs[1][(wm * 64 + mi * 16 + r16) * 40 + kg * 8]);
        }
        #pragma unroll
        for (int ni = 0; ni < 2; ++ni) {
            bf_h[ni] = *reinterpret_cast<const bf16x8*>(&Ws[0][(wn * 32 + ni * 16 + r16) * 40 + kg * 8]);
            if constexpr (WSPLIT)
                bf_l[ni] = *reinterpret_cast<const bf16x8*>(&Ws[1][(wn * 32 + ni * 16 + r16) * 40 + kg * 8]);
        }
        #pragma unroll
        for (int mi = 0; mi < 4; ++mi)
            #pragma unroll
            for (int ni = 0; ni < 2; ++ni) {
                acc[mi][ni] = __builtin_amdgcn_mfma_f32_16x16x32_bf16(af_h[mi], bf_h[ni], acc[mi][ni], 0, 0, 0);
                if constexpr (XSPLIT)
                    acc[mi][ni] = __builtin_amdgcn_mfma_f32_16x16x32_bf16(af_l[mi], bf_h[ni], acc[mi][ni], 0, 0, 0);
                if constexpr (WSPLIT)
                    acc[mi][ni] = __builtin_amdgcn_mfma_f32_16x16x32_bf16(af_h[mi], bf_l[ni], acc[mi][ni], 0, 0, 0);
            }
    }

    if constexpr (MODE == 3) {
        float* out = (float*)outv;
        #pragma unroll
        for (int ni = 0; ni < 2; ++ni) {
            int col = col0 + wn * 32 + ni * 16 + r16;
            float bv = bias[col];
            #pragma unroll
            for (int mi = 0; mi < 4; ++mi) {
                int rowb = row0 + wm * 64 + mi * 16 + kg * 4;
                #pragma unroll
                for (int j = 0; j < 4; ++j)
                    out[(size_t)(rowb + j) * ldo + col] = acc[mi][ni][j] + bv;
            }
        }
    } else {
        ushort_t* out = (ushort_t*)outv + out_off;
        #pragma unroll
        for (int ni = 0; ni < 2; ++ni) {
            int col = col0 + wn * 32 + ni * 16 + r16;
            #pragma unroll
            for (int mi = 0; mi < 4; ++mi) {
                int rowb = row0 + wm * 64 + mi * 16 + kg * 4;
                #pragma unroll
                for (int j = 0; j < 4; ++j) {
                    float v = acc[mi][ni][j];
                    unsigned short hv = f2bf(v);
                    out[(size_t)(rowb + j) * ldo + col] = hv;
                    out[oplane + (size_t)(rowb + j) * ldo + col] = f2bf(v - bf2f(hv));
                }
            }
        }
    }
}

// ---------------- merged gi+gh GEMM: grid (12, M/128)
// blocks x<6: gi = S2 @ U^T + bih (K=512); x>=6: gh = state @ whh^T + bhh (K=128)
// same fragment math as mm_kernel<3,...,true,true>, runtime K (ldw == ldx == K)
__global__ __launch_bounds__(256) void gigh_kernel(
        const ushort_t* __restrict__ S2p, size_t s2pl,
        const ushort_t* __restrict__ Sp, size_t spl,
        const ushort_t* __restrict__ Up, size_t upl,
        const ushort_t* __restrict__ Whp, size_t whpl,
        const float* __restrict__ bih, const float* __restrict__ bhh,
        float* __restrict__ gip, float* __restrict__ ghp) {
    __shared__ __align__(16) ushort_t Xs[2][128 * 40];
    __shared__ __align__(16) ushort_t Ws[2][64 * 40];
    int tid = threadIdx.x;
    int row0 = blockIdx.y * 128;
    const ushort_t* X; const ushort_t* W; const float* bias; float* out;
    size_t xplane, wplane; int ld, Kr, col0;
    if (blockIdx.x < 6) {
        X = S2p; xplane = s2pl; W = Up; wplane = upl; bias = bih; out = gip;
        ld = 512; Kr = 512; col0 = blockIdx.x * 64;
    } else {
        X = Sp; xplane = spl; W = Whp; wplane = whpl; bias = bhh; out = ghp;
        ld = 128; Kr = 128; col0 = (blockIdx.x - 6) * 64;
    }
    int lane = tid & 63, wave = tid >> 6;
    int wm = wave & 1, wn = wave >> 1;
    int r16 = lane & 15, kg = lane >> 4;

    f32x4 acc[4][2] = {};

    for (int k0 = 0; k0 < Kr; k0 += 32) {
        bf16x8 xh[2], xl[2], wh, wl;
        #pragma unroll
        for (int q = 0; q < 2; ++q) {
            int chunk = q * 256 + tid;
            int r = chunk >> 2, kc = chunk & 3;
            const ushort_t* xp = X + (size_t)(row0 + r) * ld + k0 + kc * 8;
            xh[q] = *reinterpret_cast<const bf16x8*>(xp);
            xl[q] = *reinterpret_cast<const bf16x8*>(xp + xplane);
        }
        {
            int r = tid >> 2, kc = tid & 3;
            const ushort_t* wp2 = W + (size_t)(col0 + r) * ld + k0 + kc * 8;
            wh = *reinterpret_cast<const bf16x8*>(wp2);
            wl = *reinterpret_cast<const bf16x8*>(wp2 + wplane);
        }
        __syncthreads();
        #pragma unroll
        for (int q = 0; q < 2; ++q) {
            int chunk = q * 256 + tid;
            int r = chunk >> 2, kc = chunk & 3;
            *reinterpret_cast<bf16x8*>(&Xs[0][r * 40 + kc * 8]) = xh[q];
            *reinterpret_cast<bf16x8*>(&Xs[1][r * 40 + kc * 8]) = xl[q];
        }
        {
            int r = tid >> 2, kc = tid & 3;
            *reinterpret_cast<bf16x8*>(&Ws[0][r * 40 + kc * 8]) = wh;
            *reinterpret_cast<bf16x8*>(&Ws[1][r * 40 + kc * 8]) = wl;
        }
        __syncthreads();
        bf16x8 af_h[4], af_l[4], bf_h[2], bf_l[2];
        #pragma unroll
        for (int mi = 0; mi < 4; ++mi) {
            af_h[mi] = *reinterpret_cast<const bf16x8*>(&Xs[0][(wm * 64 + mi * 16 + r16) * 40 + kg * 8]);
            af_l[mi] = *reinterpret_cast<const bf16x8*>(&Xs[1][(wm * 64 + mi * 16 + r16) * 40 + kg * 8]);
        }
        #pragma unroll
        for (int ni = 0; ni < 2; ++ni) {
            bf_h[ni] = *reinterpret_cast<const bf16x8*>(&Ws[0][(wn * 32 + ni * 16 + r16) * 40 + kg * 8]);
            bf_l[ni] = *reinterpret_cast<const bf16x8*>(&Ws[1][(wn * 32 + ni * 16 + r16) * 40 + kg * 8]);
        }
        #pragma unroll
        for (int mi = 0; mi < 4; ++mi)
            #pragma unroll
            for (int ni = 0; ni < 2; ++ni) {
                acc[mi][ni] = __builtin_amdgcn_mfma_f32_16x16x32_bf16(af_h[mi], bf_h[ni], acc[mi][ni], 0, 0, 0);
                acc[mi][ni] = __builtin_amdgcn_mfma_f32_16x16x32_bf16(af_l[mi], bf_h[ni], acc[mi][ni], 0, 0, 0);
                acc[mi][ni] = __builtin_amdgcn_mfma_f32_16x16x32_bf16(af_h[mi], bf_l[ni], acc[mi][ni], 0, 0, 0);
            }
    }

    #pragma unroll
    for (int ni = 0; ni < 2; ++ni) {
        int col = col0 + wn * 32 + ni * 16 + r16;
        float bv = bias[col];
        #pragma unroll
        for (int mi = 0; mi < 4; ++mi) {
            int rowb = row0 + wm * 64 + mi * 16 + kg * 4;
            #pragma unroll
            for (int j = 0; j < 4; ++j)
                out[(size_t)(rowb + j) * 384 + col] = acc[mi][ni][j] + bv;
        }
    }
}

// ---------------- GRU gates + fused stateT transpose
// grid: rows/16 blocks, 256 threads; thread = (r_loc = tid>>4, j0 = (tid&15)*8)
// gate math per element identical to the proven scalar kernel (bit-exact).
__global__ __launch_bounds__(256) void gate_t_kernel(const float* __restrict__ gi,
        const float* __restrict__ gh,
        ushort_t* __restrict__ s_hi, ushort_t* __restrict__ s_lo,
        ushort_t* __restrict__ t_hi, ushort_t* __restrict__ t_lo, int row_base) {
    __shared__ __align__(16) ushort_t th[HH][24];
    __shared__ __align__(16) ushort_t tl[HH][24];
    int tid = threadIdx.x;
    int r_loc = tid >> 4;            // 0..15
    int j0 = (tid & 15) * 8;         // 0..120
    int row_l = blockIdx.x * 16 + r_loc;
    size_t grow = (size_t)(row_base + row_l);
    const float* gir = gi + (size_t)row_l * 384;
    const float* ghr = gh + (size_t)row_l * 384;
    ushort_t* sh = s_hi + grow * HH;
    ushort_t* sl = s_lo + grow * HH;
    __align__(16) ushort_t hb[8], lb[8];
    #pragma unroll
    for (int g4 = 0; g4 < 2; ++g4) {
        int j = j0 + g4 * 4;
        float4 ir4 = *reinterpret_cast<const float4*>(gir + j);
        float4 iz4 = *reinterpret_cast<const float4*>(gir + 128 + j);
        float4 in4 = *reinterpret_cast<const float4*>(gir + 256 + j);
        float4 hr4 = *reinterpret_cast<const float4*>(ghr + j);
        float4 hz4 = *reinterpret_cast<const float4*>(ghr + 128 + j);
        float4 hn4 = *reinterpret_cast<const float4*>(ghr + 256 + j);
        us4 oh4 = *reinterpret_cast<const us4*>(sh + j);
        us4 ol4 = *reinterpret_cast<const us4*>(sl + j);
        const float* irp = reinterpret_cast<const float*>(&ir4);
        const float* izp = reinterpret_cast<const float*>(&iz4);
        const float* inp = reinterpret_cast<const float*>(&in4);
        const float* hrp = reinterpret_cast<const float*>(&hr4);
        const float* hzp = reinterpret_cast<const float*>(&hz4);
        const float* hnp = reinterpret_cast<const float*>(&hn4);
        #pragma unroll
        for (int c = 0; c < 4; ++c) {
            float r = 1.f / (1.f + expf(-(irp[c] + hrp[c])));
            float z = 1.f / (1.f + expf(-(izp[c] + hzp[c])));
            float n = tanhf(inp[c] + r * hnp[c]);
            float h = bf2f(oh4[c]) + bf2f(ol4[c]);
            float v = (1.f - z) * n + z * h;
            unsigned short hv = f2bf(v);
            hb[g4 * 4 + c] = hv;
            lb[g4 * 4 + c] = f2bf(v - bf2f(hv));
        }
    }
    *reinterpret_cast<us8*>(sh + j0) = *reinterpret_cast<us8*>(&hb[0]);
    *reinterpret_cast<us8*>(sl + j0) = *reinterpret_cast<us8*>(&lb[0]);
    #pragma unroll
    for (int k = 0; k < 8; ++k) {
        th[j0 + k][r_loc] = hb[k];
        tl[j0 + k][r_loc] = lb[k];
    }
    __syncthreads();
    {
        int j = tid >> 1, seg = (tid & 1) * 8;
        size_t colb = (size_t)row_base + (size_t)blockIdx.x * 16 + seg;
        *reinterpret_cast<us8*>(t_hi + (size_t)j * 16384 + colb) =
            *reinterpret_cast<const us8*>(&th[j][seg]);
        *reinterpret_cast<us8*>(t_lo + (size_t)j * 16384 + colb) =
            *reinterpret_cast<const us8*>(&tl[j][seg]);
    }
}

// ================= set2vec, phase-split =================

__global__ __launch_bounds__(256) void s2v_g_kernel(int step,
        const float* __restrict__ hvec, const float* __restrict__ rpart,
        const float* __restrict__ wih, const float* __restrict__ whh,
        const float* __restrict__ bih, const float* __restrict__ bhh,
        float* __restrict__ g_all) {
    int b = blockIdx.y, tid = threadIdx.x;
    int j = blockIdx.x * 256 + tid;
    __shared__ float q[256];
    if (step > 0) {
        if (tid < 128) q[tid] = hvec[b * 128 + tid];
        else {
            int h2 = tid - 128;
            const float* rp = rpart + (size_t)b * 512;
            q[tid] = rp[h2] + rp[128 + h2] + rp[256 + h2] + rp[384 + h2];
        }
    } else {
        q[tid] = 0.f;
    }
    __syncthreads();
    float acc = bih[j] + bhh[j];
    if (step > 0) {
        const float4* wi = reinterpret_cast<const float4*>(wih + (size_t)j * 256);
        #pragma unroll 8
        for (int d4 = 0; d4 < 64; ++d4) {
            float4 w = wi[d4];
            acc = fmaf(q[d4 * 4 + 0], w.x, fmaf(q[d4 * 4 + 1], w.y,
                  fmaf(q[d4 * 4 + 2], w.z, fmaf(q[d4 * 4 + 3], w.w, acc))));
        }
        const float4* wp = reinterpret_cast<const float4*>(whh + (size_t)j * 128);
        #pragma unroll 8
        for (int d4 = 0; d4 < 32; ++d4) {
            float4 w = wp[d4];
            acc = fmaf(q[d4 * 4 + 0], w.x, fmaf(q[d4 * 4 + 1], w.y,
                  fmaf(q[d4 * 4 + 2], w.z, fmaf(q[d4 * 4 + 3], w.w, acc))));
        }
    }
    g_all[(size_t)b * 512 + j] = acc;
}

__global__ __launch_bounds__(256) void s2v_cl_kernel(int step,
        const float* __restrict__ g_all, float* __restrict__ cvec, float* __restrict__ hvec,
        const ushort_t* __restrict__ s_hi, const ushort_t* __restrict__ s_lo,
        float* __restrict__ logits) {
    int b = blockIdx.y, chunk = blockIdx.x, tid = threadIdx.x;
    __shared__ float hs[HH];
    if (tid < HH) {
        const float* g = g_all + (size_t)b * 512;
        float i_ = 1.f / (1.f + expf(-g[tid]));
        float f_ = 1.f / (1.f + expf(-g[128 + tid]));
        float g_ = tanhf(g[256 + tid]);
        float o_ = 1.f / (1.f + expf(-g[384 + tid]));
        float c0 = (step == 0) ? 0.f : cvec[b * 128 + tid];
        float c2 = f_ * c0 + i_ * g_;
        float hn = o_ * tanhf(c2);
        hs[tid] = hn;
        if (chunk == 0) { cvec[b * 128 + tid] = c2; hvec[b * 128 + tid] = hn; }
    }
    __syncthreads();
    int n = chunk * 256 + tid;
    const ushort_t* ph = s_hi + ((size_t)b * NN + n) * HH;
    const ushort_t* pl = s_lo + ((size_t)b * NN + n) * HH;
    float lg = 0.f;
    #pragma unroll
    for (int i8 = 0; i8 < 16; ++i8) {
        bf16x8 vh = *reinterpret_cast<const bf16x8*>(ph + i8 * 8);
        bf16x8 vl = *reinterpret_cast<const bf16x8*>(pl + i8 * 8);
        #pragma unroll
        for (int k = 0; k < 8; ++k)
            lg = fmaf(bf2f((ushort_t)vh[k]) + bf2f((ushort_t)vl[k]), hs[i8 * 8 + k], lg);
    }
    logits[(size_t)b * 512 + n] = lg;
}

__global__ __launch_bounds__(256) void s2v_read_kernel(const float* __restrict__ logits,
        const ushort_t* __restrict__ t_hi, const ushort_t* __restrict__ t_lo,
        float* __restrict__ rpart) {
    int b = blockIdx.y, chunk = blockIdx.x, tid = threadIdx.x;
    __shared__ float lgs[NN];
    __shared__ float att[128];
    __shared__ float wred[8];
    __shared__ float red[256];
    lgs[tid] = logits[(size_t)b * 512 + tid];
    lgs[256 + tid] = logits[(size_t)b * 512 + 256 + tid];
    __syncthreads();
    float mv = fmaxf(lgs[tid], lgs[tid + 256]);
    #pragma unroll
    for (int m = 32; m >= 1; m >>= 1) mv = fmaxf(mv, __shfl_xor(mv, m));
    if ((tid & 63) == 0) wred[tid >> 6] = mv;
    __syncthreads();
    float mx = fmaxf(fmaxf(wred[0], wred[1]), fmaxf(wred[2], wred[3]));
    float sv = expf(lgs[tid] - mx) + expf(lgs[tid + 256] - mx);
    #pragma unroll
    for (int m = 32; m >= 1; m >>= 1) sv += __shfl_xor(sv, m);
    if ((tid & 63) == 0) wred[4 + (tid >> 6)] = sv;
    __syncthreads();
    float inv = 1.f / (wred[4] + wred[5] + wred[6] + wred[7]);
    if (tid < 128) att[tid] = expf(lgs[chunk * 128 + tid] - mx) * inv;
    __syncthreads();
    int hh = tid & 127, half = tid >> 7;
    int colb = b * NN + chunk * 128 + half * 64;
    const ushort_t* ph = t_hi + (size_t)hh * 16384 + colb;
    const ushort_t* pl = t_lo + (size_t)hh * 16384 + colb;
    float racc = 0.f;
    #pragma unroll
    for (int i8 = 0; i8 < 8; ++i8) {
        bf16x8 vh = *reinterpret_cast<const bf16x8*>(ph + i8 * 8);
        bf16x8 vl = *reinterpret_cast<const bf16x8*>(pl + i8 * 8);
        #pragma unroll
        for (int k = 0; k < 8; ++k)
            racc = fmaf(att[half * 64 + i8 * 8 + k],
                        bf2f((ushort_t)vh[k]) + bf2f((ushort_t)vl[k]), racc);
    }
    red[tid] = racc;
    __syncthreads();
    if (tid < 128)
        rpart[(size_t)b * 512 + chunk * 128 + tid] = red[tid] + red[128 + tid];
}

__global__ __launch_bounds__(256) void s2v_out_kernel(const float* __restrict__ hvec,
        const float* __restrict__ rpart, const float* __restrict__ Wout,
        const float* __restrict__ bout, float* __restrict__ out) {
    int b = blockIdx.x, tid = threadIdx.x;
    __shared__ float q[256];
    if (tid < 128) q[tid] = hvec[b * 128 + tid];
    else {
        int h2 = tid - 128;
        const float* rp = rpart + (size_t)b * 512;
        q[tid] = rp[h2] + rp[128 + h2] + rp[256 + h2] + rp[384 + h2];
    }
    __syncthreads();
    if (tid < DOUT) {
        float acc = bout[tid];
        const float4* w = reinterpret_cast<const float4*>(Wout + (size_t)tid * 256);
        #pragma unroll 8
        for (int d4 = 0; d4 < 64; ++d4) {
            float4 wv = w[d4];
            acc = fmaf(q[d4 * 4 + 0], wv.x, fmaf(q[d4 * 4 + 1], wv.y,
                  fmaf(q[d4 * 4 + 2], wv.z, fmaf(q[d4 * 4 + 3], wv.w, acc))));
        }
        out[b * DOUT + tid] = acc;
    }
}

extern "C" void kernel_launch(void* const* d_in, const int* in_sizes, int n_in,
                              void* d_out, int out_size, void* d_ws, size_t ws_size,
                              hipStream_t stream) {
    const int*   node_feat = (const int*)d_in[0];
    const float* L         = (const float*)d_in[1];
    const float* node_emb  = (const float*)d_in[2];
    const float* W_in      = (const float*)d_in[3];
    const float* b_in      = (const float*)d_in[4];
    const float* edge_emb  = (const float*)d_in[5];
    const float* gru_wih   = (const float*)d_in[6];
    const float* gru_whh   = (const float*)d_in[7];
    const float* gru_bih   = (const float*)d_in[8];
    const float* gru_bhh   = (const float*)d_in[9];
    const float* lstm_wih  = (const float*)d_in[10];
    const float* lstm_whh  = (const float*)d_in[11];
    const float* lstm_bih  = (const float*)d_in[12];
    const float* lstm_bhh  = (const float*)d_in[13];
    const float* W_out     = (const float*)d_in[14];
    const float* b_out     = (const float*)d_in[15];
    float* out = (float*)d_out;

    char* ws = (char*)d_ws;
    const bool full = ws_size >= ((size_t)110 << 20);

    // common: state hi/lo [0..8), stateT hi/lo [8..16), Abits [16..20)
    // full : S2 [20..52) plane 8388608 | gi [52..76) | gh [76..100) | W [100..101) | s2v [101..]
    // half : S2 [20..36) plane 4194304 | gi [36..48) | gh [48..60) | W [60..61)  | s2v [61..]
    ushort_t* state_hi  = (ushort_t*)ws;
    ushort_t* stateT_hi = (ushort_t*)(ws + (8u << 20));
    unsigned* Abits     = (unsigned*)(ws + (16u << 20));
    ushort_t* S2        = (ushort_t*)(ws + (20u << 20));
    size_t s2plane      = full ? 8388608u : 4194304u;
    float*    gi        = (float*)(ws + (full ? (52ull << 20) : (36ull << 20)));
    float*    gh        = (float*)(ws + (full ? (76ull << 20) : (48ull << 20)));
    ushort_t* U_h       = (ushort_t*)(ws + (full ? (100ull << 20) : (60ull << 20)));
    ushort_t* U_l       = U_h + 196608;
    ushort_t* whh_h     = U_l + 196608;
    ushort_t* whh_l     = whh_h + 49152;
    float*    s2v       = (float*)(ws + (full ? (101ull << 20) : (61ull << 20)));
    float*    g_all     = s2v;            // 16384
    float*    logits    = s2v + 16384;    // 16384
    float*    hvec      = s2v + 32768;    // 4096
    float*    cvec      = s2v + 36864;    // 4096
    float*    rpart     = s2v + 40960;    // 16384

    const size_t SPLANE = 2097152;    // state/stateT plane stride (elems)

    pack_A_kernel<<<(BB * NN * 16) / 256, 256, 0, stream>>>(L, Abits);
    convW_kernel<<<(384 * 512 + 384 * 128) / 256, 256, 0, stream>>>(
        edge_emb, gru_wih, gru_whh, U_h, U_l, whh_h, whh_l);
    embed_kernel<<<BB * NN, 128, 0, stream>>>(node_feat, node_emb, W_in, b_in,
                                              state_hi, state_hi + SPLANE);
    transpose_kernel<<<256, 256, 0, stream>>>(state_hi, stateT_hi, SPLANE);

    const int nh   = full ? 1 : 2;
    const int zdim = full ? 128 : 64;    // graphs in dispatch * E1
    const int ydim = full ? 128 : 64;    // M / 128
    const int rows = full ? 16384 : MHALF;

    for (int p = 0; p < NPROP; ++p) {
        for (int half = 0; half < nh; ++half) {
            const unsigned* Ab = Abits + (size_t)half * 16 * E1 * NN * 16;
            // S2[(bl*512+m)][e*128+h] = A_be @ state_b : per z M=512, N=128, K=512
            mm_kernel<4, true, true, 512, false, true><<<dim3(2, 4, zdim), 256, 0, stream>>>(
                Ab, 0, stateT_hi + (size_t)half * MHALF, SPLANE, nullptr,
                S2, s2plane, 0, 16384, 512);
            // gi = S2 @ U^T + bih (K=512) and gh = state @ whh^T + bhh (K=128), one dispatch
            gigh_kernel<<<dim3(12, ydim), 256, 0, stream>>>(
                S2, s2plane,
                state_hi + (size_t)half * MHALF * HH, SPLANE,
                U_h, 196608, whh_h, 49152,
                gru_bih, gru_bhh, gi, gh);
            // gates -> state planes + fused stateT transpose
            gate_t_kernel<<<rows / 16, 256, 0, stream>>>(
                gi, gh, state_hi, state_hi + SPLANE,
                stateT_hi, stateT_hi + SPLANE, half * MHALF);
        }
    }

    for (int step = 0; step < NS2V; ++step) {
        s2v_g_kernel<<<dim3(2, BB), 256, 0, stream>>>(step, hvec, rpart,
                                                      lstm_wih, lstm_whh, lstm_bih, lstm_bhh,
                                                      g_all);
        s2v_cl_kernel<<<dim3(2, BB), 256, 0, stream>>>(step, g_all, cvec, hvec,
                                                       state_hi, state_hi + SPLANE, logits);
        s2v_read_kernel<<<dim3(4, BB), 256, 0, stream>>>(logits, stateT_hi,
                                                         stateT_hi + SPLANE, rpart);
    }
    s2v_out_kernel<<<BB, 256, 0, stream>>>(hvec, rpart, W_out, b_out, out);
}

// Round 9
// 713.503 us; speedup vs baseline: 1.0145x; 1.0145x over previous
//
#include <hip/hip_runtime.h>
#include <hip/hip_bf16.h>

#define BB 32
#define NN 512
#define DA 100
#define DIN 64
#define HH 128
#define E1 4
#define DOUT 16
#define NPROP 5
#define NS2V 3
#define MHALF 8192          // rows per half-batch (16 graphs)

typedef __attribute__((ext_vector_type(8))) short bf16x8;
typedef __attribute__((ext_vector_type(4))) float f32x4;
typedef __attribute__((ext_vector_type(4))) unsigned short us4;
typedef __attribute__((ext_vector_type(8))) unsigned short us8;
typedef unsigned short ushort_t;

__device__ __forceinline__ unsigned short f2bf(float f) {
    __hip_bfloat16 h = __float2bfloat16(f);
    return *reinterpret_cast<unsigned short*>(&h);
}
__device__ __forceinline__ float bf2f(unsigned short u) {
    unsigned v = ((unsigned)u) << 16;
    float f;
    __builtin_memcpy(&f, &v, 4);
    return f;
}

// ---------------- pack A bits: L[b,m,n,e] != 0 -> bit n%32 of Abits[((b*E1+e)*N+m)*16 + n/32]
__global__ void pack_A_kernel(const float* __restrict__ L, unsigned* __restrict__ Abits) {
    int t = blockIdx.x * blockDim.x + threadIdx.x;   // (b, m, w)
    if (t >= BB * NN * (NN / 32)) return;
    int w = t & 15;
    int m = (t >> 4) & (NN - 1);
    int b = t >> (4 + 9);
    const float* src = L + ((size_t)(b * NN + m) * NN + 32 * w) * E1;
    unsigned bits[E1] = {0u, 0u, 0u, 0u};
    #pragma unroll 8
    for (int j = 0; j < 32; ++j) {
        float4 v = *reinterpret_cast<const float4*>(src + j * 4);
        if (v.x != 0.f) bits[0] |= (1u << j);
        if (v.y != 0.f) bits[1] |= (1u << j);
        if (v.z != 0.f) bits[2] |= (1u << j);
        if (v.w != 0.f) bits[3] |= (1u << j);
    }
    #pragma unroll
    for (int e = 0; e < E1; ++e)
        Abits[((b * E1 + e) * NN + m) * 16 + w] = bits[e];
}

// ---------------- fused-weight precompute:
// U[j, e*128+h] = sum_k wih[j, e*128+k] * edge_emb[e, h*128+k]   (fp32, then split bf16)
// whh split bf16
__global__ void convW_kernel(const float* __restrict__ EE, const float* __restrict__ wih,
                             const float* __restrict__ whh,
                             ushort_t* __restrict__ U_h, ushort_t* __restrict__ U_l,
                             ushort_t* __restrict__ whh_h, ushort_t* __restrict__ whh_l) {
    int t = blockIdx.x * blockDim.x + threadIdx.x;
    if (t < 384 * 512) {
        int col = t & 511;
        int j = t >> 9;
        int e = col >> 7, h = col & 127;
        const float4* wp = reinterpret_cast<const float4*>(wih + (size_t)j * 512 + e * 128);
        const float4* ep = reinterpret_cast<const float4*>(EE + (size_t)e * 16384 + h * 128);
        float acc = 0.f;
        #pragma unroll 8
        for (int k4 = 0; k4 < 32; ++k4) {
            float4 a = wp[k4], b = ep[k4];
            acc = fmaf(a.x, b.x, fmaf(a.y, b.y, fmaf(a.z, b.z, fmaf(a.w, b.w, acc))));
        }
        unsigned short hi = f2bf(acc);
        U_h[t] = hi;
        U_l[t] = f2bf(acc - bf2f(hi));
        return;
    }
    int t2 = t - 384 * 512;
    if (t2 < 384 * 128) {
        float v = whh[t2];
        unsigned short hi = f2bf(v);
        whh_h[t2] = hi;
        whh_l[t2] = f2bf(v - bf2f(hi));
    }
}

// ---------------- embed: state[row, h] = node_emb[nf[row]] . W_in[h,:] + b_in[h] -> split planes
__global__ void embed_kernel(const int* __restrict__ nf, const float* __restrict__ emb,
                             const float* __restrict__ Win, const float* __restrict__ bin,
                             ushort_t* __restrict__ s_hi, ushort_t* __restrict__ s_lo) {
    int row = blockIdx.x;
    int h = threadIdx.x;
    __shared__ float e[DIN];
    int a = nf[row];
    if (h < DIN) e[h] = emb[a * DIN + h];
    __syncthreads();
    float acc = bin[h];
    const float* w = Win + h * DIN;
    #pragma unroll
    for (int d = 0; d < DIN; ++d) acc = fmaf(e[d], w[d], acc);
    unsigned short hi = f2bf(acc);
    s_hi[row * HH + h] = hi;
    s_lo[row * HH + h] = f2bf(acc - bf2f(hi));
}

// ---------------- transpose state planes: [16384][128] -> [128][16384]
__global__ __launch_bounds__(256) void transpose_kernel(const ushort_t* __restrict__ src,
                                                        ushort_t* __restrict__ dst,
                                                        size_t splane) {
    __shared__ __align__(16) ushort_t tile[128][72];
    int row0 = blockIdx.x * 64;
    int tid = threadIdx.x;
    #pragma unroll
    for (int pl = 0; pl < 2; ++pl) {
        const ushort_t* s = src + pl * splane;
        ushort_t* d = dst + pl * splane;
        #pragma unroll
        for (int q = 0; q < 4; ++q) {
            int idx = q * 256 + tid;
            int r = idx >> 4, h8 = idx & 15;
            bf16x8 v = *reinterpret_cast<const bf16x8*>(s + (size_t)(row0 + r) * HH + h8 * 8);
            #pragma unroll
            for (int j = 0; j < 8; ++j) tile[h8 * 8 + j][r] = (ushort_t)v[j];
        }
        __syncthreads();
        {
            int h = tid >> 1, rseg = (tid & 1) * 32;
            #pragma unroll
            for (int s8 = 0; s8 < 4; ++s8) {
                us8 v = *reinterpret_cast<const us8*>(&tile[h][rseg + s8 * 8]);
                *reinterpret_cast<us8*>(&d[(size_t)h * 16384 + row0 + rseg + s8 * 8]) = v;
            }
        }
        __syncthreads();
    }
}

// ---------------- S2 GEMM: per (b,e): C[m][h] = sum_n A[m][n] * state[n][h]
// A from packed bits (exact bf16 0/1); state via split stateT (hi + lo planes).
// BM=128, BN=128 (full h width), BK=32, 256 threads = 4 waves (2x2); per wave 64x64 (4x4 frags).
// Per-element accumulation order identical to the previous BN=64 kernel (bit-exact).
__global__ __launch_bounds__(256) void s2_kernel(const unsigned* __restrict__ Abits,
                                                 const ushort_t* __restrict__ tS, size_t tplane,
                                                 ushort_t* __restrict__ outp, size_t oplane) {
    __shared__ __align__(16) ushort_t Xs[128 * 40];
    __shared__ __align__(16) ushort_t Ws[2][128 * 40];
    int tid = threadIdx.x;
    int row0 = blockIdx.x * 128;
    int z = blockIdx.y;
    int e = z & 3, bl = z >> 2;
    const unsigned* Xb = Abits + (size_t)z * NN * 16;
    const ushort_t* W = tS + (size_t)bl * NN;                 // stateT cols shifted to graph bl
    ushort_t* out = outp + (size_t)bl * NN * NN + (size_t)e * HH;
    int lane = tid & 63, wave = tid >> 6;
    int wm = wave & 1, wn = wave >> 1;
    int r16 = lane & 15, kg = lane >> 4;

    f32x4 acc[4][4] = {};

    for (int k0 = 0; k0 < NN; k0 += 32) {
        unsigned xword;
        { int m = tid >> 1; xword = Xb[(size_t)(row0 + m) * 16 + (k0 >> 5)]; }
        bf16x8 wh[2], wl[2];
        {
            int r = tid >> 1, kc = (tid & 1) * 16;
            const ushort_t* wp2 = W + (size_t)r * 16384 + k0 + kc;
            wh[0] = *reinterpret_cast<const bf16x8*>(wp2);
            wh[1] = *reinterpret_cast<const bf16x8*>(wp2 + 8);
            wl[0] = *reinterpret_cast<const bf16x8*>(wp2 + tplane);
            wl[1] = *reinterpret_cast<const bf16x8*>(wp2 + tplane + 8);
        }
        __syncthreads();
        {
            int m = tid >> 1, sel = tid & 1;
            #pragma unroll
            for (int j8 = 0; j8 < 2; ++j8) {
                bf16x8 xv;
                #pragma unroll
                for (int j = 0; j < 8; ++j)
                    xv[j] = (short)(((xword >> (sel * 16 + j8 * 8 + j)) & 1u) ? 0x3F80 : 0);
                *reinterpret_cast<bf16x8*>(&Xs[m * 40 + sel * 16 + j8 * 8]) = xv;
            }
            int r = tid >> 1, kc = (tid & 1) * 16;
            *reinterpret_cast<bf16x8*>(&Ws[0][r * 40 + kc]) = wh[0];
            *reinterpret_cast<bf16x8*>(&Ws[0][r * 40 + kc + 8]) = wh[1];
            *reinterpret_cast<bf16x8*>(&Ws[1][r * 40 + kc]) = wl[0];
            *reinterpret_cast<bf16x8*>(&Ws[1][r * 40 + kc + 8]) = wl[1];
        }
        __syncthreads();
        bf16x8 af[4], bh[4], blo[4];
        #pragma unroll
        for (int mi = 0; mi < 4; ++mi)
            af[mi] = *reinterpret_cast<const bf16x8*>(&Xs[(wm * 64 + mi * 16 + r16) * 40 + kg * 8]);
        #pragma unroll
        for (int ni = 0; ni < 4; ++ni) {
            bh[ni]  = *reinterpret_cast<const bf16x8*>(&Ws[0][(wn * 64 + ni * 16 + r16) * 40 + kg * 8]);
            blo[ni] = *reinterpret_cast<const bf16x8*>(&Ws[1][(wn * 64 + ni * 16 + r16) * 40 + kg * 8]);
        }
        #pragma unroll
        for (int mi = 0; mi < 4; ++mi)
            #pragma unroll
            for (int ni = 0; ni < 4; ++ni) {
                acc[mi][ni] = __builtin_amdgcn_mfma_f32_16x16x32_bf16(af[mi], bh[ni], acc[mi][ni], 0, 0, 0);
                acc[mi][ni] = __builtin_amdgcn_mfma_f32_16x16x32_bf16(af[mi], blo[ni], acc[mi][ni], 0, 0, 0);
            }
    }
    #pragma unroll
    for (int ni = 0; ni < 4; ++ni) {
        int col = wn * 64 + ni * 16 + r16;
        #pragma unroll
        for (int mi = 0; mi < 4; ++mi) {
            int rowb = row0 + wm * 64 + mi * 16 + kg * 4;
            #pragma unroll
            for (int j = 0; j < 4; ++j) {
                float v = acc[mi][ni][j];
                unsigned short hv = f2bf(v);
                out[(size_t)(rowb + j) * 512 + col] = hv;
                out[oplane + (size_t)(rowb + j) * 512 + col] = f2bf(v - bf2f(hv));
            }
        }
    }
}

// ---------------- split-bf16 MFMA GEMM (gi/gh): C[M x N] = X[M x K] @ W[N x K]^T + bias (fp32 out)
// BM=128, BN=64, BK=32, 256 threads = 4 waves (2x2)
template <int K>
__global__ __launch_bounds__(256) void mm_kernel(const ushort_t* __restrict__ X, size_t xplane,
                                                 const ushort_t* __restrict__ W, size_t wplane,
                                                 const float* __restrict__ bias,
                                                 float* __restrict__ out, int ldo) {
    __shared__ __align__(16) ushort_t Xs[2][128 * 40];
    __shared__ __align__(16) ushort_t Ws[2][64 * 40];
    int tid = threadIdx.x;
    int row0 = blockIdx.y * 128, col0 = blockIdx.x * 64;
    int lane = tid & 63;
    int wave = tid >> 6;
    int wm = wave & 1, wn = wave >> 1;
    int r16 = lane & 15, kg = lane >> 4;

    f32x4 acc[4][2] = {};

    for (int k0 = 0; k0 < K; k0 += 32) {
        bf16x8 xh[2], xl[2], wh, wl;
        #pragma unroll
        for (int q = 0; q < 2; ++q) {
            int chunk = q * 256 + tid;
            int r = chunk >> 2, kc = chunk & 3;
            const ushort_t* xp = X + (size_t)(row0 + r) * K + k0 + kc * 8;
            xh[q] = *reinterpret_cast<const bf16x8*>(xp);
            xl[q] = *reinterpret_cast<const bf16x8*>(xp + xplane);
        }
        {
            int r = tid >> 2, kc = tid & 3;
            const ushort_t* wp2 = W + (size_t)(col0 + r) * K + k0 + kc * 8;
            wh = *reinterpret_cast<const bf16x8*>(wp2);
            wl = *reinterpret_cast<const bf16x8*>(wp2 + wplane);
        }
        __syncthreads();
        #pragma unroll
        for (int q = 0; q < 2; ++q) {
            int chunk = q * 256 + tid;
            int r = chunk >> 2, kc = chunk & 3;
            *reinterpret_cast<bf16x8*>(&Xs[0][r * 40 + kc * 8]) = xh[q];
            *reinterpret_cast<bf16x8*>(&Xs[1][r * 40 + kc * 8]) = xl[q];
        }
        {
            int r = tid >> 2, kc = tid & 3;
            *reinterpret_cast<bf16x8*>(&Ws[0][r * 40 + kc * 8]) = wh;
            *reinterpret_cast<bf16x8*>(&Ws[1][r * 40 + kc * 8]) = wl;
        }
        __syncthreads();
        bf16x8 af_h[4], af_l[4], bf_h[2], bf_l[2];
        #pragma unroll
        for (int mi = 0; mi < 4; ++mi) {
            af_h[mi] = *reinterpret_cast<const bf16x8*>(&Xs[0][(wm * 64 + mi * 16 + r16) * 40 + kg * 8]);
            af_l[mi] = *reinterpret_cast<const bf16x8*>(&Xs[1][(wm * 64 + mi * 16 + r16) * 40 + kg * 8]);
        }
        #pragma unroll
        for (int ni = 0; ni < 2; ++ni) {
            bf_h[ni] = *reinterpret_cast<const bf16x8*>(&Ws[0][(wn * 32 + ni * 16 + r16) * 40 + kg * 8]);
            bf_l[ni] = *reinterpret_cast<const bf16x8*>(&Ws[1][(wn * 32 + ni * 16 + r16) * 40 + kg * 8]);
        }
        #pragma unroll
        for (int mi = 0; mi < 4; ++mi)
            #pragma unroll
            for (int ni = 0; ni < 2; ++ni) {
                acc[mi][ni] = __builtin_amdgcn_mfma_f32_16x16x32_bf16(af_h[mi], bf_h[ni], acc[mi][ni], 0, 0, 0);
                acc[mi][ni] = __builtin_amdgcn_mfma_f32_16x16x32_bf16(af_l[mi], bf_h[ni], acc[mi][ni], 0, 0, 0);
                acc[mi][ni] = __builtin_amdgcn_mfma_f32_16x16x32_bf16(af_h[mi], bf_l[ni], acc[mi][ni], 0, 0, 0);
            }
    }

    #pragma unroll
    for (int ni = 0; ni < 2; ++ni) {
        int col = col0 + wn * 32 + ni * 16 + r16;
        float bv = bias[col];
        #pragma unroll
        for (int mi = 0; mi < 4; ++mi) {
            int rowb = row0 + wm * 64 + mi * 16 + kg * 4;
            #pragma unroll
            for (int j = 0; j < 4; ++j)
                out[(size_t)(rowb + j) * ldo + col] = acc[mi][ni][j] + bv;
        }
    }
}

// ---------------- GRU gates from fp32 gi/gh; updates split state planes
__global__ void gru_gate_kernel(const float* __restrict__ gi, const float* __restrict__ gh,
                                ushort_t* __restrict__ s_hi, ushort_t* __restrict__ s_lo,
                                size_t half_off, int total) {
    int t = blockIdx.x * blockDim.x + threadIdx.x;
    if (t >= total) return;
    int row = t >> 7, j = t & 127;
    const float* gir = gi + (size_t)row * 384;
    const float* ghr = gh + (size_t)row * 384;
    float ir = gir[j], iz = gir[128 + j], in_ = gir[256 + j];
    float hr = ghr[j], hz = ghr[128 + j], hn = ghr[256 + j];
    float r = 1.f / (1.f + expf(-(ir + hr)));
    float z = 1.f / (1.f + expf(-(iz + hz)));
    float n = tanhf(in_ + r * hn);
    size_t g = half_off + (size_t)t;
    float h = bf2f(s_hi[g]) + bf2f(s_lo[g]);
    float v = (1.f - z) * n + z * h;
    unsigned short hv = f2bf(v);
    s_hi[g] = hv;
    s_lo[g] = f2bf(v - bf2f(hv));
}

// ================= set2vec, phase-split =================

__global__ __launch_bounds__(256) void s2v_g_kernel(int step,
        const float* __restrict__ hvec, const float* __restrict__ rpart,
        const float* __restrict__ wih, const float* __restrict__ whh,
        const float* __restrict__ bih, const float* __restrict__ bhh,
        float* __restrict__ g_all) {
    int b = blockIdx.y, tid = threadIdx.x;
    int j = blockIdx.x * 256 + tid;
    __shared__ float q[256];
    if (step > 0) {
        if (tid < 128) q[tid] = hvec[b * 128 + tid];
        else {
            int h2 = tid - 128;
            const float* rp = rpart + (size_t)b * 512;
            q[tid] = rp[h2] + rp[128 + h2] + rp[256 + h2] + rp[384 + h2];
        }
    } else {
        q[tid] = 0.f;
    }
    __syncthreads();
    float acc = bih[j] + bhh[j];
    if (step > 0) {
        const float4* wi = reinterpret_cast<const float4*>(wih + (size_t)j * 256);
        #pragma unroll 8
        for (int d4 = 0; d4 < 64; ++d4) {
            float4 w = wi[d4];
            acc = fmaf(q[d4 * 4 + 0], w.x, fmaf(q[d4 * 4 + 1], w.y,
                  fmaf(q[d4 * 4 + 2], w.z, fmaf(q[d4 * 4 + 3], w.w, acc))));
        }
        const float4* wp = reinterpret_cast<const float4*>(whh + (size_t)j * 128);
        #pragma unroll 8
        for (int d4 = 0; d4 < 32; ++d4) {
            float4 w = wp[d4];
            acc = fmaf(q[d4 * 4 + 0], w.x, fmaf(q[d4 * 4 + 1], w.y,
                  fmaf(q[d4 * 4 + 2], w.z, fmaf(q[d4 * 4 + 3], w.w, acc))));
        }
    }
    g_all[(size_t)b * 512 + j] = acc;
}

__global__ __launch_bounds__(256) void s2v_cl_kernel(int step,
        const float* __restrict__ g_all, float* __restrict__ cvec, float* __restrict__ hvec,
        const ushort_t* __restrict__ s_hi, const ushort_t* __restrict__ s_lo,
        float* __restrict__ logits) {
    int b = blockIdx.y, chunk = blockIdx.x, tid = threadIdx.x;
    __shared__ float hs[HH];
    if (tid < HH) {
        const float* g = g_all + (size_t)b * 512;
        float i_ = 1.f / (1.f + expf(-g[tid]));
        float f_ = 1.f / (1.f + expf(-g[128 + tid]));
        float g_ = tanhf(g[256 + tid]);
        float o_ = 1.f / (1.f + expf(-g[384 + tid]));
        float c0 = (step == 0) ? 0.f : cvec[b * 128 + tid];
        float c2 = f_ * c0 + i_ * g_;
        float hn = o_ * tanhf(c2);
        hs[tid] = hn;
        if (chunk == 0) { cvec[b * 128 + tid] = c2; hvec[b * 128 + tid] = hn; }
    }
    __syncthreads();
    int n = chunk * 256 + tid;
    const ushort_t* ph = s_hi + ((size_t)b * NN + n) * HH;
    const ushort_t* pl = s_lo + ((size_t)b * NN + n) * HH;
    float lg = 0.f;
    #pragma unroll
    for (int i8 = 0; i8 < 16; ++i8) {
        bf16x8 vh = *reinterpret_cast<const bf16x8*>(ph + i8 * 8);
        bf16x8 vl = *reinterpret_cast<const bf16x8*>(pl + i8 * 8);
        #pragma unroll
        for (int k = 0; k < 8; ++k)
            lg = fmaf(bf2f((ushort_t)vh[k]) + bf2f((ushort_t)vl[k]), hs[i8 * 8 + k], lg);
    }
    logits[(size_t)b * 512 + n] = lg;
}

__global__ __launch_bounds__(256) void s2v_read_kernel(const float* __restrict__ logits,
        const ushort_t* __restrict__ t_hi, const ushort_t* __restrict__ t_lo,
        float* __restrict__ rpart) {
    int b = blockIdx.y, chunk = blockIdx.x, tid = threadIdx.x;
    __shared__ float lgs[NN];
    __shared__ float att[128];
    __shared__ float wred[8];
    __shared__ float red[256];
    lgs[tid] = logits[(size_t)b * 512 + tid];
    lgs[256 + tid] = logits[(size_t)b * 512 + 256 + tid];
    __syncthreads();
    float mv = fmaxf(lgs[tid], lgs[tid + 256]);
    #pragma unroll
    for (int m = 32; m >= 1; m >>= 1) mv = fmaxf(mv, __shfl_xor(mv, m));
    if ((tid & 63) == 0) wred[tid >> 6] = mv;
    __syncthreads();
    float mx = fmaxf(fmaxf(wred[0], wred[1]), fmaxf(wred[2], wred[3]));
    float sv = expf(lgs[tid] - mx) + expf(lgs[tid + 256] - mx);
    #pragma unroll
    for (int m = 32; m >= 1; m >>= 1) sv += __shfl_xor(sv, m);
    if ((tid & 63) == 0) wred[4 + (tid >> 6)] = sv;
    __syncthreads();
    float inv = 1.f / (wred[4] + wred[5] + wred[6] + wred[7]);
    if (tid < 128) att[tid] = expf(lgs[chunk * 128 + tid] - mx) * inv;
    __syncthreads();
    int hh = tid & 127, half = tid >> 7;
    int colb = b * NN + chunk * 128 + half * 64;
    const ushort_t* ph = t_hi + (size_t)hh * 16384 + colb;
    const ushort_t* pl = t_lo + (size_t)hh * 16384 + colb;
    float racc = 0.f;
    #pragma unroll
    for (int i8 = 0; i8 < 8; ++i8) {
        bf16x8 vh = *reinterpret_cast<const bf16x8*>(ph + i8 * 8);
        bf16x8 vl = *reinterpret_cast<const bf16x8*>(pl + i8 * 8);
        #pragma unroll
        for (int k = 0; k < 8; ++k)
            racc = fmaf(att[half * 64 + i8 * 8 + k],
                        bf2f((ushort_t)vh[k]) + bf2f((ushort_t)vl[k]), racc);
    }
    red[tid] = racc;
    __syncthreads();
    if (tid < 128)
        rpart[(size_t)b * 512 + chunk * 128 + tid] = red[tid] + red[128 + tid];
}

__global__ __launch_bounds__(256) void s2v_out_kernel(const float* __restrict__ hvec,
        const float* __restrict__ rpart, const float* __restrict__ Wout,
        const float* __restrict__ bout, float* __restrict__ out) {
    int b = blockIdx.x, tid = threadIdx.x;
    __shared__ float q[256];
    if (tid < 128) q[tid] = hvec[b * 128 + tid];
    else {
        int h2 = tid - 128;
        const float* rp = rpart + (size_t)b * 512;
        q[tid] = rp[h2] + rp[128 + h2] + rp[256 + h2] + rp[384 + h2];
    }
    __syncthreads();
    if (tid < DOUT) {
        float acc = bout[tid];
        const float4* w = reinterpret_cast<const float4*>(Wout + (size_t)tid * 256);
        #pragma unroll 8
        for (int d4 = 0; d4 < 64; ++d4) {
            float4 wv = w[d4];
            acc = fmaf(q[d4 * 4 + 0], wv.x, fmaf(q[d4 * 4 + 1], wv.y,
                  fmaf(q[d4 * 4 + 2], wv.z, fmaf(q[d4 * 4 + 3], wv.w, acc))));
        }
        out[b * DOUT + tid] = acc;
    }
}

extern "C" void kernel_launch(void* const* d_in, const int* in_sizes, int n_in,
                              void* d_out, int out_size, void* d_ws, size_t ws_size,
                              hipStream_t stream) {
    const int*   node_feat = (const int*)d_in[0];
    const float* L         = (const float*)d_in[1];
    const float* node_emb  = (const float*)d_in[2];
    const float* W_in      = (const float*)d_in[3];
    const float* b_in      = (const float*)d_in[4];
    const float* edge_emb  = (const float*)d_in[5];
    const float* gru_wih   = (const float*)d_in[6];
    const float* gru_whh   = (const float*)d_in[7];
    const float* gru_bih   = (const float*)d_in[8];
    const float* gru_bhh   = (const float*)d_in[9];
    const float* lstm_wih  = (const float*)d_in[10];
    const float* lstm_whh  = (const float*)d_in[11];
    const float* lstm_bih  = (const float*)d_in[12];
    const float* lstm_bhh  = (const float*)d_in[13];
    const float* W_out     = (const float*)d_in[14];
    const float* b_out     = (const float*)d_in[15];
    float* out = (float*)d_out;

    char* ws = (char*)d_ws;
    const bool full = ws_size >= ((size_t)110 << 20);

    // common: state hi/lo [0..8), stateT hi/lo [8..16), Abits [16..20)
    // full : S2 [20..52) plane 8388608 | gi [52..76) | gh [76..100) | W [100..101) | s2v [101..]
    // half : S2 [20..36) plane 4194304 | gi [36..48) | gh [48..60) | W [60..61)  | s2v [61..]
    ushort_t* state_hi  = (ushort_t*)ws;
    ushort_t* stateT_hi = (ushort_t*)(ws + (8u << 20));
    unsigned* Abits     = (unsigned*)(ws + (16u << 20));
    ushort_t* S2        = (ushort_t*)(ws + (20u << 20));
    size_t s2plane      = full ? 8388608u : 4194304u;
    float*    gi        = (float*)(ws + (full ? (52ull << 20) : (36ull << 20)));
    float*    gh        = (float*)(ws + (full ? (76ull << 20) : (48ull << 20)));
    ushort_t* U_h       = (ushort_t*)(ws + (full ? (100ull << 20) : (60ull << 20)));
    ushort_t* U_l       = U_h + 196608;
    ushort_t* whh_h     = U_l + 196608;
    ushort_t* whh_l     = whh_h + 49152;
    float*    s2v       = (float*)(ws + (full ? (101ull << 20) : (61ull << 20)));
    float*    g_all     = s2v;            // 16384
    float*    logits    = s2v + 16384;    // 16384
    float*    hvec      = s2v + 32768;    // 4096
    float*    cvec      = s2v + 36864;    // 4096
    float*    rpart     = s2v + 40960;    // 16384

    const size_t SPLANE = 2097152;    // state/stateT plane stride (elems)

    pack_A_kernel<<<(BB * NN * 16) / 256, 256, 0, stream>>>(L, Abits);
    convW_kernel<<<(384 * 512 + 384 * 128) / 256, 256, 0, stream>>>(
        edge_emb, gru_wih, gru_whh, U_h, U_l, whh_h, whh_l);
    embed_kernel<<<BB * NN, 128, 0, stream>>>(node_feat, node_emb, W_in, b_in,
                                              state_hi, state_hi + SPLANE);

    const int nh   = full ? 1 : 2;
    const int zdim = full ? 128 : 64;    // graphs in dispatch * E1
    const int ydim = full ? 128 : 64;    // M / 128
    const int rows = full ? 16384 : MHALF;

    for (int p = 0; p < NPROP; ++p) {
        transpose_kernel<<<256, 256, 0, stream>>>(state_hi, stateT_hi, SPLANE);
        for (int half = 0; half < nh; ++half) {
            const unsigned* Ab = Abits + (size_t)half * 16 * E1 * NN * 16;
            // S2[(bl*512+m)][e*128+h] = A_be @ state_b : per z M=512, N=128, K=512 (BN=128 tile)
            s2_kernel<<<dim3(4, zdim), 256, 0, stream>>>(
                Ab, stateT_hi + (size_t)half * MHALF, SPLANE, S2, s2plane);
            // gi = S2 @ U^T + bih : N=384, K=512 -> fp32
            mm_kernel<512><<<dim3(6, ydim), 256, 0, stream>>>(
                S2, s2plane, U_h, 196608, gru_bih, gi, 384);
            // gh = state @ whh^T + bhh : N=384, K=128 -> fp32
            mm_kernel<128><<<dim3(6, ydim), 256, 0, stream>>>(
                state_hi + (size_t)half * MHALF * HH, SPLANE, whh_h, 49152, gru_bhh, gh, 384);
            // gates -> state planes
            gru_gate_kernel<<<(rows * HH) / 256, 256, 0, stream>>>(
                gi, gh, state_hi, state_hi + SPLANE,
                (size_t)half * MHALF * HH, rows * HH);
        }
    }
    // fresh stateT for the s2v read phase
    transpose_kernel<<<256, 256, 0, stream>>>(state_hi, stateT_hi, SPLANE);

    for (int step = 0; step < NS2V; ++step) {
        s2v_g_kernel<<<dim3(2, BB), 256, 0, stream>>>(step, hvec, rpart,
                                                      lstm_wih, lstm_whh, lstm_bih, lstm_bhh,
                                                      g_all);
        s2v_cl_kernel<<<dim3(2, BB), 256, 0, stream>>>(step, g_all, cvec, hvec,
                                                       state_hi, state_hi + SPLANE, logits);
        s2v_read_kernel<<<dim3(4, BB), 256, 0, stream>>>(logits, stateT_hi,
                                                         stateT_hi + SPLANE, rpart);
    }
    s2v_out_kernel<<<BB, 256, 0, stream>>>(hvec, rpart, W_out, b_out, out);
}

// Round 10
// 681.870 us; speedup vs baseline: 1.0616x; 1.0464x over previous
//
#include <hip/hip_runtime.h>
#include <hip/hip_bf16.h>

#define BB 32
#define NN 512
#define DA 100
#define DIN 64
#define HH 128
#define E1 4
#define DOUT 16
#define NPROP 5
#define NS2V 3
#define MHALF 8192          // rows per half-batch (16 graphs)

typedef __attribute__((ext_vector_type(8))) short bf16x8;
typedef __attribute__((ext_vector_type(4))) float f32x4;
typedef __attribute__((ext_vector_type(4))) unsigned short us4;
typedef __attribute__((ext_vector_type(8))) unsigned short us8;
typedef unsigned short ushort_t;

__device__ __forceinline__ unsigned short f2bf(float f) {
    __hip_bfloat16 h = __float2bfloat16(f);
    return *reinterpret_cast<unsigned short*>(&h);
}
__device__ __forceinline__ float bf2f(unsigned short u) {
    unsigned v = ((unsigned)u) << 16;
    float f;
    __builtin_memcpy(&f, &v, 4);
    return f;
}

// ---------------- pack A bits (coalesced + ballot):
// thread handles one (b,m,n): float4 covers e=0..3. Lane i -> n = base+i (16B/lane coalesced).
// __ballot assembles the per-e 64-bit mask; lanes 0-7 write the 8 words.
// Output layout identical to before: bit n%32 of Abits[((b*E1+e)*N+m)*16 + n/32]
__global__ __launch_bounds__(256) void pack_A_kernel(const float* __restrict__ L,
                                                     unsigned* __restrict__ Abits) {
    int t = blockIdx.x * 256 + threadIdx.x;    // (b, m, n)
    int n = t & (NN - 1);
    int m = (t >> 9) & (NN - 1);
    int b = t >> 18;
    float4 v = *reinterpret_cast<const float4*>(L + ((size_t)(b * NN + m) * NN + n) * E1);
    unsigned long long mk[E1];
    mk[0] = __ballot(v.x != 0.f);
    mk[1] = __ballot(v.y != 0.f);
    mk[2] = __ballot(v.z != 0.f);
    mk[3] = __ballot(v.w != 0.f);
    int lane = threadIdx.x & 63;
    if (lane < 8) {
        int e = lane >> 1, half = lane & 1;
        unsigned word = half ? (unsigned)(mk[e] >> 32) : (unsigned)mk[e];
        int wbase = (n >> 5) & ~1;             // word index of wave's first n
        Abits[((size_t)(b * E1 + e) * NN + m) * 16 + wbase + half] = word;
    }
}

// ---------------- fused-weight precompute:
// U[j, e*128+h] = sum_k wih[j, e*128+k] * edge_emb[e, h*128+k]   (fp32, then split bf16)
// whh split bf16
__global__ void convW_kernel(const float* __restrict__ EE, const float* __restrict__ wih,
                             const float* __restrict__ whh,
                             ushort_t* __restrict__ U_h, ushort_t* __restrict__ U_l,
                             ushort_t* __restrict__ whh_h, ushort_t* __restrict__ whh_l) {
    int t = blockIdx.x * blockDim.x + threadIdx.x;
    if (t < 384 * 512) {
        int col = t & 511;
        int j = t >> 9;
        int e = col >> 7, h = col & 127;
        const float4* wp = reinterpret_cast<const float4*>(wih + (size_t)j * 512 + e * 128);
        const float4* ep = reinterpret_cast<const float4*>(EE + (size_t)e * 16384 + h * 128);
        float acc = 0.f;
        #pragma unroll 8
        for (int k4 = 0; k4 < 32; ++k4) {
            float4 a = wp[k4], b = ep[k4];
            acc = fmaf(a.x, b.x, fmaf(a.y, b.y, fmaf(a.z, b.z, fmaf(a.w, b.w, acc))));
        }
        unsigned short hi = f2bf(acc);
        U_h[t] = hi;
        U_l[t] = f2bf(acc - bf2f(hi));
        return;
    }
    int t2 = t - 384 * 512;
    if (t2 < 384 * 128) {
        float v = whh[t2];
        unsigned short hi = f2bf(v);
        whh_h[t2] = hi;
        whh_l[t2] = f2bf(v - bf2f(hi));
    }
}

// ---------------- embed: state[row, h] = node_emb[nf[row]] . W_in[h,:] + b_in[h] -> split planes
__global__ void embed_kernel(const int* __restrict__ nf, const float* __restrict__ emb,
                             const float* __restrict__ Win, const float* __restrict__ bin,
                             ushort_t* __restrict__ s_hi, ushort_t* __restrict__ s_lo) {
    int row = blockIdx.x;
    int h = threadIdx.x;
    __shared__ float e[DIN];
    int a = nf[row];
    if (h < DIN) e[h] = emb[a * DIN + h];
    __syncthreads();
    float acc = bin[h];
    const float* w = Win + h * DIN;
    #pragma unroll
    for (int d = 0; d < DIN; ++d) acc = fmaf(e[d], w[d], acc);
    unsigned short hi = f2bf(acc);
    s_hi[row * HH + h] = hi;
    s_lo[row * HH + h] = f2bf(acc - bf2f(hi));
}

// ---------------- transpose state planes: [16384][128] -> [128][16384]
__global__ __launch_bounds__(256) void transpose_kernel(const ushort_t* __restrict__ src,
                                                        ushort_t* __restrict__ dst,
                                                        size_t splane) {
    __shared__ __align__(16) ushort_t tile[128][72];
    int row0 = blockIdx.x * 64;
    int tid = threadIdx.x;
    #pragma unroll
    for (int pl = 0; pl < 2; ++pl) {
        const ushort_t* s = src + pl * splane;
        ushort_t* d = dst + pl * splane;
        #pragma unroll
        for (int q = 0; q < 4; ++q) {
            int idx = q * 256 + tid;
            int r = idx >> 4, h8 = idx & 15;
            bf16x8 v = *reinterpret_cast<const bf16x8*>(s + (size_t)(row0 + r) * HH + h8 * 8);
            #pragma unroll
            for (int j = 0; j < 8; ++j) tile[h8 * 8 + j][r] = (ushort_t)v[j];
        }
        __syncthreads();
        {
            int h = tid >> 1, rseg = (tid & 1) * 32;
            #pragma unroll
            for (int s8 = 0; s8 < 4; ++s8) {
                us8 v = *reinterpret_cast<const us8*>(&tile[h][rseg + s8 * 8]);
                *reinterpret_cast<us8*>(&d[(size_t)h * 16384 + row0 + rseg + s8 * 8]) = v;
            }
        }
        __syncthreads();
    }
}

// ---------------- split-bf16 MFMA GEMM: C[M x N] = X[M x K] @ W[N x K]^T
// BM=128, BN=64, BK=32, 256 threads = 4 waves (2x2), per-wave 64x32 (4x2 16x16 frags)
template <int MODE, bool AGG, bool XBITS, int K, bool XSPLIT, bool WSPLIT>
__global__ __launch_bounds__(256) void mm_kernel(const void* __restrict__ Xp, size_t xplane,
                                                 const ushort_t* __restrict__ W, size_t wplane,
                                                 const float* __restrict__ bias,
                                                 void* __restrict__ outv, size_t oplane,
                                                 int ldx, int ldw, int ldo) {
    __shared__ __align__(16) ushort_t Xs[2][128 * 40];
    __shared__ __align__(16) ushort_t Ws[2][64 * 40];
    int tid = threadIdx.x;
    int row0 = blockIdx.y * 128, col0 = blockIdx.x * 64;
    const ushort_t* X = (const ushort_t*)Xp;
    const unsigned* Xb = (const unsigned*)Xp;
    size_t out_off = 0;
    int wko = 0;
    if constexpr (AGG) {
        int e = blockIdx.z & 3, bl = blockIdx.z >> 2;
        Xb += (size_t)blockIdx.z * NN * 16;               // A bits for (b_local, e)
        wko = bl * NN;                                    // stateT column offset (n base)
        out_off = (size_t)bl * NN * NN + (size_t)e * HH;  // S2cat[(bl*512+m)*512 + e*128 + h]
    }
    int lane = tid & 63;
    int wave = tid >> 6;
    int wm = wave & 1, wn = wave >> 1;
    int r16 = lane & 15, kg = lane >> 4;

    f32x4 acc[4][2] = {};

    for (int k0 = 0; k0 < K; k0 += 32) {
        bf16x8 xh[2], xl[2];
        unsigned xword;
        if constexpr (XBITS) {
            int m = tid >> 1;
            xword = Xb[(size_t)(row0 + m) * 16 + (k0 >> 5)];
        } else {
            #pragma unroll
            for (int q = 0; q < 2; ++q) {
                int chunk = q * 256 + tid;
                int r = chunk >> 2, kc = chunk & 3;
                const ushort_t* xp = X + (size_t)(row0 + r) * ldx + k0 + kc * 8;
                xh[q] = *reinterpret_cast<const bf16x8*>(xp);
                if constexpr (XSPLIT) xl[q] = *reinterpret_cast<const bf16x8*>(xp + xplane);
            }
        }
        bf16x8 wh, wl;
        {
            int r = tid >> 2, kc = tid & 3;
            const ushort_t* wp2 = W + (size_t)(col0 + r) * ldw + wko + k0 + kc * 8;
            wh = *reinterpret_cast<const bf16x8*>(wp2);
            if constexpr (WSPLIT) wl = *reinterpret_cast<const bf16x8*>(wp2 + wplane);
        }
        __syncthreads();
        if constexpr (XBITS) {
            int m = tid >> 1, sel = tid & 1;
            #pragma unroll
            for (int j8 = 0; j8 < 2; ++j8) {
                bf16x8 xv;
                #pragma unroll
                for (int j = 0; j < 8; ++j)
                    xv[j] = (short)(((xword >> (sel * 16 + j8 * 8 + j)) & 1u) ? 0x3F80 : 0);
                *reinterpret_cast<bf16x8*>(&Xs[0][m * 40 + sel * 16 + j8 * 8]) = xv;
            }
        } else {
            #pragma unroll
            for (int q = 0; q < 2; ++q) {
                int chunk = q * 256 + tid;
                int r = chunk >> 2, kc = chunk & 3;
                *reinterpret_cast<bf16x8*>(&Xs[0][r * 40 + kc * 8]) = xh[q];
                if constexpr (XSPLIT)
                    *reinterpret_cast<bf16x8*>(&Xs[1][r * 40 + kc * 8]) = xl[q];
            }
        }
        {
            int r = tid >> 2, kc = tid & 3;
            *reinterpret_cast<bf16x8*>(&Ws[0][r * 40 + kc * 8]) = wh;
            if constexpr (WSPLIT)
                *reinterpret_cast<bf16x8*>(&Ws[1][r * 40 + kc * 8]) = wl;
        }
        __syncthreads();
        bf16x8 af_h[4], af_l[4], bf_h[2], bf_l[2];
        #pragma unroll
        for (int mi = 0; mi < 4; ++mi) {
            af_h[mi] = *reinterpret_cast<const bf16x8*>(&Xs[0][(wm * 64 + mi * 16 + r16) * 40 + kg * 8]);
            if constexpr (XSPLIT)
                af_l[mi] = *reinterpret_cast<const bf16x8*>(&Xs[1][(wm * 64 + mi * 16 + r16) * 40 + kg * 8]);
        }
        #pragma unroll
        for (int ni = 0; ni < 2; ++ni) {
            bf_h[ni] = *reinterpret_cast<const bf16x8*>(&Ws[0][(wn * 32 + ni * 16 + r16) * 40 + kg * 8]);
            if constexpr (WSPLIT)
                bf_l[ni] = *reinterpret_cast<const bf16x8*>(&Ws[1][(wn * 32 + ni * 16 + r16) * 40 + kg * 8]);
        }
        #pragma unroll
        for (int mi = 0; mi < 4; ++mi)
            #pragma unroll
            for (int ni = 0; ni < 2; ++ni) {
                acc[mi][ni] = __builtin_amdgcn_mfma_f32_16x16x32_bf16(af_h[mi], bf_h[ni], acc[mi][ni], 0, 0, 0);
                if constexpr (XSPLIT)
                    acc[mi][ni] = __builtin_amdgcn_mfma_f32_16x16x32_bf16(af_l[mi], bf_h[ni], acc[mi][ni], 0, 0, 0);
                if constexpr (WSPLIT)
                    acc[mi][ni] = __builtin_amdgcn_mfma_f32_16x16x32_bf16(af_h[mi], bf_l[ni], acc[mi][ni], 0, 0, 0);
            }
    }

    if constexpr (MODE == 3) {
        float* out = (float*)outv;
        #pragma unroll
        for (int ni = 0; ni < 2; ++ni) {
            int col = col0 + wn * 32 + ni * 16 + r16;
            float bv = bias[col];
            #pragma unroll
            for (int mi = 0; mi < 4; ++mi) {
                int rowb = row0 + wm * 64 + mi * 16 + kg * 4;
                #pragma unroll
                for (int j = 0; j < 4; ++j)
                    out[(size_t)(rowb + j) * ldo + col] = acc[mi][ni][j] + bv;
            }
        }
    } else {
        ushort_t* out = (ushort_t*)outv + out_off;
        #pragma unroll
        for (int ni = 0; ni < 2; ++ni) {
            int col = col0 + wn * 32 + ni * 16 + r16;
            #pragma unroll
            for (int mi = 0; mi < 4; ++mi) {
                int rowb = row0 + wm * 64 + mi * 16 + kg * 4;
                #pragma unroll
                for (int j = 0; j < 4; ++j) {
                    float v = acc[mi][ni][j];
                    unsigned short hv = f2bf(v);
                    out[(size_t)(rowb + j) * ldo + col] = hv;
                    out[oplane + (size_t)(rowb + j) * ldo + col] = f2bf(v - bf2f(hv));
                }
            }
        }
    }
}

// ---------------- GRU gates from fp32 gi/gh; updates split state planes
__global__ void gru_gate_kernel(const float* __restrict__ gi, const float* __restrict__ gh,
                                ushort_t* __restrict__ s_hi, ushort_t* __restrict__ s_lo,
                                size_t half_off, int total) {
    int t = blockIdx.x * blockDim.x + threadIdx.x;
    if (t >= total) return;
    int row = t >> 7, j = t & 127;
    const float* gir = gi + (size_t)row * 384;
    const float* ghr = gh + (size_t)row * 384;
    float ir = gir[j], iz = gir[128 + j], in_ = gir[256 + j];
    float hr = ghr[j], hz = ghr[128 + j], hn = ghr[256 + j];
    float r = 1.f / (1.f + expf(-(ir + hr)));
    float z = 1.f / (1.f + expf(-(iz + hz)));
    float n = tanhf(in_ + r * hn);
    size_t g = half_off + (size_t)t;
    float h = bf2f(s_hi[g]) + bf2f(s_lo[g]);
    float v = (1.f - z) * n + z * h;
    unsigned short hv = f2bf(v);
    s_hi[g] = hv;
    s_lo[g] = f2bf(v - bf2f(hv));
}

// ================= set2vec, phase-split =================

__global__ __launch_bounds__(256) void s2v_g_kernel(int step,
        const float* __restrict__ hvec, const float* __restrict__ rpart,
        const float* __restrict__ wih, const float* __restrict__ whh,
        const float* __restrict__ bih, const float* __restrict__ bhh,
        float* __restrict__ g_all) {
    int b = blockIdx.y, tid = threadIdx.x;
    int j = blockIdx.x * 256 + tid;
    __shared__ float q[256];
    if (step > 0) {
        if (tid < 128) q[tid] = hvec[b * 128 + tid];
        else {
            int h2 = tid - 128;
            const float* rp = rpart + (size_t)b * 512;
            q[tid] = rp[h2] + rp[128 + h2] + rp[256 + h2] + rp[384 + h2];
        }
    } else {
        q[tid] = 0.f;
    }
    __syncthreads();
    float acc = bih[j] + bhh[j];
    if (step > 0) {
        const float4* wi = reinterpret_cast<const float4*>(wih + (size_t)j * 256);
        #pragma unroll 8
        for (int d4 = 0; d4 < 64; ++d4) {
            float4 w = wi[d4];
            acc = fmaf(q[d4 * 4 + 0], w.x, fmaf(q[d4 * 4 + 1], w.y,
                  fmaf(q[d4 * 4 + 2], w.z, fmaf(q[d4 * 4 + 3], w.w, acc))));
        }
        const float4* wp = reinterpret_cast<const float4*>(whh + (size_t)j * 128);
        #pragma unroll 8
        for (int d4 = 0; d4 < 32; ++d4) {
            float4 w = wp[d4];
            acc = fmaf(q[d4 * 4 + 0], w.x, fmaf(q[d4 * 4 + 1], w.y,
                  fmaf(q[d4 * 4 + 2], w.z, fmaf(q[d4 * 4 + 3], w.w, acc))));
        }
    }
    g_all[(size_t)b * 512 + j] = acc;
}

__global__ __launch_bounds__(256) void s2v_cl_kernel(int step,
        const float* __restrict__ g_all, float* __restrict__ cvec, float* __restrict__ hvec,
        const ushort_t* __restrict__ s_hi, const ushort_t* __restrict__ s_lo,
        float* __restrict__ logits) {
    int b = blockIdx.y, chunk = blockIdx.x, tid = threadIdx.x;
    __shared__ float hs[HH];
    if (tid < HH) {
        const float* g = g_all + (size_t)b * 512;
        float i_ = 1.f / (1.f + expf(-g[tid]));
        float f_ = 1.f / (1.f + expf(-g[128 + tid]));
        float g_ = tanhf(g[256 + tid]);
        float o_ = 1.f / (1.f + expf(-g[384 + tid]));
        float c0 = (step == 0) ? 0.f : cvec[b * 128 + tid];
        float c2 = f_ * c0 + i_ * g_;
        float hn = o_ * tanhf(c2);
        hs[tid] = hn;
        if (chunk == 0) { cvec[b * 128 + tid] = c2; hvec[b * 128 + tid] = hn; }
    }
    __syncthreads();
    int n = chunk * 256 + tid;
    const ushort_t* ph = s_hi + ((size_t)b * NN + n) * HH;
    const ushort_t* pl = s_lo + ((size_t)b * NN + n) * HH;
    float lg = 0.f;
    #pragma unroll
    for (int i8 = 0; i8 < 16; ++i8) {
        bf16x8 vh = *reinterpret_cast<const bf16x8*>(ph + i8 * 8);
        bf16x8 vl = *reinterpret_cast<const bf16x8*>(pl + i8 * 8);
        #pragma unroll
        for (int k = 0; k < 8; ++k)
            lg = fmaf(bf2f((ushort_t)vh[k]) + bf2f((ushort_t)vl[k]), hs[i8 * 8 + k], lg);
    }
    logits[(size_t)b * 512 + n] = lg;
}

__global__ __launch_bounds__(256) void s2v_read_kernel(const float* __restrict__ logits,
        const ushort_t* __restrict__ t_hi, const ushort_t* __restrict__ t_lo,
        float* __restrict__ rpart) {
    int b = blockIdx.y, chunk = blockIdx.x, tid = threadIdx.x;
    __shared__ float lgs[NN];
    __shared__ float att[128];
    __shared__ float wred[8];
    __shared__ float red[256];
    lgs[tid] = logits[(size_t)b * 512 + tid];
    lgs[256 + tid] = logits[(size_t)b * 512 + 256 + tid];
    __syncthreads();
    float mv = fmaxf(lgs[tid], lgs[tid + 256]);
    #pragma unroll
    for (int m = 32; m >= 1; m >>= 1) mv = fmaxf(mv, __shfl_xor(mv, m));
    if ((tid & 63) == 0) wred[tid >> 6] = mv;
    __syncthreads();
    float mx = fmaxf(fmaxf(wred[0], wred[1]), fmaxf(wred[2], wred[3]));
    float sv = expf(lgs[tid] - mx) + expf(lgs[tid + 256] - mx);
    #pragma unroll
    for (int m = 32; m >= 1; m >>= 1) sv += __shfl_xor(sv, m);
    if ((tid & 63) == 0) wred[4 + (tid >> 6)] = sv;
    __syncthreads();
    float inv = 1.f / (wred[4] + wred[5] + wred[6] + wred[7]);
    if (tid < 128) att[tid] = expf(lgs[chunk * 128 + tid] - mx) * inv;
    __syncthreads();
    int hh = tid & 127, half = tid >> 7;
    int colb = b * NN + chunk * 128 + half * 64;
    const ushort_t* ph = t_hi + (size_t)hh * 16384 + colb;
    const ushort_t* pl = t_lo + (size_t)hh * 16384 + colb;
    float racc = 0.f;
    #pragma unroll
    for (int i8 = 0; i8 < 8; ++i8) {
        bf16x8 vh = *reinterpret_cast<const bf16x8*>(ph + i8 * 8);
        bf16x8 vl = *reinterpret_cast<const bf16x8*>(pl + i8 * 8);
        #pragma unroll
        for (int k = 0; k < 8; ++k)
            racc = fmaf(att[half * 64 + i8 * 8 + k],
                        bf2f((ushort_t)vh[k]) + bf2f((ushort_t)vl[k]), racc);
    }
    red[tid] = racc;
    __syncthreads();
    if (tid < 128)
        rpart[(size_t)b * 512 + chunk * 128 + tid] = red[tid] + red[128 + tid];
}

__global__ __launch_bounds__(256) void s2v_out_kernel(const float* __restrict__ hvec,
        const float* __restrict__ rpart, const float* __restrict__ Wout,
        const float* __restrict__ bout, float* __restrict__ out) {
    int b = blockIdx.x, tid = threadIdx.x;
    __shared__ float q[256];
    if (tid < 128) q[tid] = hvec[b * 128 + tid];
    else {
        int h2 = tid - 128;
        const float* rp = rpart + (size_t)b * 512;
        q[tid] = rp[h2] + rp[128 + h2] + rp[256 + h2] + rp[384 + h2];
    }
    __syncthreads();
    if (tid < DOUT) {
        float acc = bout[tid];
        const float4* w = reinterpret_cast<const float4*>(Wout + (size_t)tid * 256);
        #pragma unroll 8
        for (int d4 = 0; d4 < 64; ++d4) {
            float4 wv = w[d4];
            acc = fmaf(q[d4 * 4 + 0], wv.x, fmaf(q[d4 * 4 + 1], wv.y,
                  fmaf(q[d4 * 4 + 2], wv.z, fmaf(q[d4 * 4 + 3], wv.w, acc))));
        }
        out[b * DOUT + tid] = acc;
    }
}

extern "C" void kernel_launch(void* const* d_in, const int* in_sizes, int n_in,
                              void* d_out, int out_size, void* d_ws, size_t ws_size,
                              hipStream_t stream) {
    const int*   node_feat = (const int*)d_in[0];
    const float* L         = (const float*)d_in[1];
    const float* node_emb  = (const float*)d_in[2];
    const float* W_in      = (const float*)d_in[3];
    const float* b_in      = (const float*)d_in[4];
    const float* edge_emb  = (const float*)d_in[5];
    const float* gru_wih   = (const float*)d_in[6];
    const float* gru_whh   = (const float*)d_in[7];
    const float* gru_bih   = (const float*)d_in[8];
    const float* gru_bhh   = (const float*)d_in[9];
    const float* lstm_wih  = (const float*)d_in[10];
    const float* lstm_whh  = (const float*)d_in[11];
    const float* lstm_bih  = (const float*)d_in[12];
    const float* lstm_bhh  = (const float*)d_in[13];
    const float* W_out     = (const float*)d_in[14];
    const float* b_out     = (const float*)d_in[15];
    float* out = (float*)d_out;

    char* ws = (char*)d_ws;
    const bool full = ws_size >= ((size_t)110 << 20);

    // common: state hi/lo [0..8), stateT hi/lo [8..16), Abits [16..20)
    // full : S2 [20..52) plane 8388608 | gi [52..76) | gh [76..100) | W [100..101) | s2v [101..]
    // half : S2 [20..36) plane 4194304 | gi [36..48) | gh [48..60) | W [60..61)  | s2v [61..]
    ushort_t* state_hi  = (ushort_t*)ws;
    ushort_t* stateT_hi = (ushort_t*)(ws + (8u << 20));
    unsigned* Abits     = (unsigned*)(ws + (16u << 20));
    ushort_t* S2        = (ushort_t*)(ws + (20u << 20));
    size_t s2plane      = full ? 8388608u : 4194304u;
    float*    gi        = (float*)(ws + (full ? (52ull << 20) : (36ull << 20)));
    float*    gh        = (float*)(ws + (full ? (76ull << 20) : (48ull << 20)));
    ushort_t* U_h       = (ushort_t*)(ws + (full ? (100ull << 20) : (60ull << 20)));
    ushort_t* U_l       = U_h + 196608;
    ushort_t* whh_h     = U_l + 196608;
    ushort_t* whh_l     = whh_h + 49152;
    float*    s2v       = (float*)(ws + (full ? (101ull << 20) : (61ull << 20)));
    float*    g_all     = s2v;            // 16384
    float*    logits    = s2v + 16384;    // 16384
    float*    hvec      = s2v + 32768;    // 4096
    float*    cvec      = s2v + 36864;    // 4096
    float*    rpart     = s2v + 40960;    // 16384

    const size_t SPLANE = 2097152;    // state/stateT plane stride (elems)

    pack_A_kernel<<<(BB * NN * NN) / 256, 256, 0, stream>>>(L, Abits);
    convW_kernel<<<(384 * 512 + 384 * 128) / 256, 256, 0, stream>>>(
        edge_emb, gru_wih, gru_whh, U_h, U_l, whh_h, whh_l);
    embed_kernel<<<BB * NN, 128, 0, stream>>>(node_feat, node_emb, W_in, b_in,
                                              state_hi, state_hi + SPLANE);

    const int nh   = full ? 1 : 2;
    const int zdim = full ? 128 : 64;    // graphs in dispatch * E1
    const int ydim = full ? 128 : 64;    // M / 128
    const int rows = full ? 16384 : MHALF;

    for (int p = 0; p < NPROP; ++p) {
        transpose_kernel<<<256, 256, 0, stream>>>(state_hi, stateT_hi, SPLANE);
        for (int half = 0; half < nh; ++half) {
            const unsigned* Ab = Abits + (size_t)half * 16 * E1 * NN * 16;
            // S2[(bl*512+m)][e*128+h] = A_be @ state_b : per z M=512, N=128, K=512
            mm_kernel<4, true, true, 512, false, true><<<dim3(2, 4, zdim), 256, 0, stream>>>(
                Ab, 0, stateT_hi + (size_t)half * MHALF, SPLANE, nullptr,
                S2, s2plane, 0, 16384, 512);
            // gi = S2 @ U^T + bih : N=384, K=512 -> fp32
            mm_kernel<3, false, false, 512, true, true><<<dim3(6, ydim), 256, 0, stream>>>(
                S2, s2plane, U_h, 196608, gru_bih, gi, 0, 512, 512, 384);
            // gh = state @ whh^T + bhh : N=384, K=128 -> fp32
            mm_kernel<3, false, false, 128, true, true><<<dim3(6, ydim), 256, 0, stream>>>(
                state_hi + (size_t)half * MHALF * HH, SPLANE, whh_h, 49152, gru_bhh,
                gh, 0, 128, 128, 384);
            // gates -> state planes
            gru_gate_kernel<<<(rows * HH) / 256, 256, 0, stream>>>(
                gi, gh, state_hi, state_hi + SPLANE,
                (size_t)half * MHALF * HH, rows * HH);
        }
    }
    // fresh stateT for the s2v read phase
    transpose_kernel<<<256, 256, 0, stream>>>(state_hi, stateT_hi, SPLANE);

    for (int step = 0; step < NS2V; ++step) {
        s2v_g_kernel<<<dim3(2, BB), 256, 0, stream>>>(step, hvec, rpart,
                                                      lstm_wih, lstm_whh, lstm_bih, lstm_bhh,
                                                      g_all);
        s2v_cl_kernel<<<dim3(2, BB), 256, 0, stream>>>(step, g_all, cvec, hvec,
                                                       state_hi, state_hi + SPLANE, logits);
        s2v_read_kernel<<<dim3(4, BB), 256, 0, stream>>>(logits, stateT_hi,
                                                         stateT_hi + SPLANE, rpart);
    }
    s2v_out_kernel<<<BB, 256, 0, stream>>>(hvec, rpart, W_out, b_out, out);
}

// Round 11
// 596.855 us; speedup vs baseline: 1.2128x; 1.1424x over previous
//
#include <hip/hip_runtime.h>
#include <hip/hip_bf16.h>

#define BB 32
#define NN 512
#define DA 100
#define DIN 64
#define HH 128
#define E1 4
#define DOUT 16
#define NPROP 5
#define NS2V 3
#define MHALF 8192          // rows per half-batch (16 graphs)

typedef __attribute__((ext_vector_type(8))) short bf16x8;
typedef __attribute__((ext_vector_type(4))) float f32x4;
typedef __attribute__((ext_vector_type(4))) unsigned short us4;
typedef __attribute__((ext_vector_type(8))) unsigned short us8;
typedef unsigned short ushort_t;

__device__ __forceinline__ unsigned short f2bf(float f) {
    __hip_bfloat16 h = __float2bfloat16(f);
    return *reinterpret_cast<unsigned short*>(&h);
}
__device__ __forceinline__ float bf2f(unsigned short u) {
    unsigned v = ((unsigned)u) << 16;
    float f;
    __builtin_memcpy(&f, &v, 4);
    return f;
}

// ---------------- pack A bits (coalesced + ballot):
// thread handles one (b,m,n): float4 covers e=0..3. Lane i -> n = base+i (16B/lane coalesced).
// __ballot assembles the per-e 64-bit mask; lanes 0-7 write the 8 words.
// Output layout identical to before: bit n%32 of Abits[((b*E1+e)*N+m)*16 + n/32]
__global__ __launch_bounds__(256) void pack_A_kernel(const float* __restrict__ L,
                                                     unsigned* __restrict__ Abits) {
    int t = blockIdx.x * 256 + threadIdx.x;    // (b, m, n)
    int n = t & (NN - 1);
    int m = (t >> 9) & (NN - 1);
    int b = t >> 18;
    float4 v = *reinterpret_cast<const float4*>(L + ((size_t)(b * NN + m) * NN + n) * E1);
    unsigned long long mk[E1];
    mk[0] = __ballot(v.x != 0.f);
    mk[1] = __ballot(v.y != 0.f);
    mk[2] = __ballot(v.z != 0.f);
    mk[3] = __ballot(v.w != 0.f);
    int lane = threadIdx.x & 63;
    if (lane < 8) {
        int e = lane >> 1, half = lane & 1;
        unsigned word = half ? (unsigned)(mk[e] >> 32) : (unsigned)mk[e];
        int wbase = (n >> 5) & ~1;             // word index of wave's first n
        Abits[((size_t)(b * E1 + e) * NN + m) * 16 + wbase + half] = word;
    }
}

// ---------------- fused-weight precompute:
// U[j, e*128+h] = sum_k wih[j, e*128+k] * edge_emb[e, h*128+k]   (fp32, then split bf16)
// whh split bf16
__global__ void convW_kernel(const float* __restrict__ EE, const float* __restrict__ wih,
                             const float* __restrict__ whh,
                             ushort_t* __restrict__ U_h, ushort_t* __restrict__ U_l,
                             ushort_t* __restrict__ whh_h, ushort_t* __restrict__ whh_l) {
    int t = blockIdx.x * blockDim.x + threadIdx.x;
    if (t < 384 * 512) {
        int col = t & 511;
        int j = t >> 9;
        int e = col >> 7, h = col & 127;
        const float4* wp = reinterpret_cast<const float4*>(wih + (size_t)j * 512 + e * 128);
        const float4* ep = reinterpret_cast<const float4*>(EE + (size_t)e * 16384 + h * 128);
        float acc = 0.f;
        #pragma unroll 8
        for (int k4 = 0; k4 < 32; ++k4) {
            float4 a = wp[k4], b = ep[k4];
            acc = fmaf(a.x, b.x, fmaf(a.y, b.y, fmaf(a.z, b.z, fmaf(a.w, b.w, acc))));
        }
        unsigned short hi = f2bf(acc);
        U_h[t] = hi;
        U_l[t] = f2bf(acc - bf2f(hi));
        return;
    }
    int t2 = t - 384 * 512;
    if (t2 < 384 * 128) {
        float v = whh[t2];
        unsigned short hi = f2bf(v);
        whh_h[t2] = hi;
        whh_l[t2] = f2bf(v - bf2f(hi));
    }
}

// ---------------- embed: state[row, h] = node_emb[nf[row]] . W_in[h,:] + b_in[h] -> split planes
__global__ void embed_kernel(const int* __restrict__ nf, const float* __restrict__ emb,
                             const float* __restrict__ Win, const float* __restrict__ bin,
                             ushort_t* __restrict__ s_hi, ushort_t* __restrict__ s_lo) {
    int row = blockIdx.x;
    int h = threadIdx.x;
    __shared__ float e[DIN];
    int a = nf[row];
    if (h < DIN) e[h] = emb[a * DIN + h];
    __syncthreads();
    float acc = bin[h];
    const float* w = Win + h * DIN;
    #pragma unroll
    for (int d = 0; d < DIN; ++d) acc = fmaf(e[d], w[d], acc);
    unsigned short hi = f2bf(acc);
    s_hi[row * HH + h] = hi;
    s_lo[row * HH + h] = f2bf(acc - bf2f(hi));
}

// ---------------- transpose state planes: [16384][128] -> [128][16384]
__global__ __launch_bounds__(256) void transpose_kernel(const ushort_t* __restrict__ src,
                                                        ushort_t* __restrict__ dst,
                                                        size_t splane) {
    __shared__ __align__(16) ushort_t tile[128][72];
    int row0 = blockIdx.x * 64;
    int tid = threadIdx.x;
    #pragma unroll
    for (int pl = 0; pl < 2; ++pl) {
        const ushort_t* s = src + pl * splane;
        ushort_t* d = dst + pl * splane;
        #pragma unroll
        for (int q = 0; q < 4; ++q) {
            int idx = q * 256 + tid;
            int r = idx >> 4, h8 = idx & 15;
            bf16x8 v = *reinterpret_cast<const bf16x8*>(s + (size_t)(row0 + r) * HH + h8 * 8);
            #pragma unroll
            for (int j = 0; j < 8; ++j) tile[h8 * 8 + j][r] = (ushort_t)v[j];
        }
        __syncthreads();
        {
            int h = tid >> 1, rseg = (tid & 1) * 32;
            #pragma unroll
            for (int s8 = 0; s8 < 4; ++s8) {
                us8 v = *reinterpret_cast<const us8*>(&tile[h][rseg + s8 * 8]);
                *reinterpret_cast<us8*>(&d[(size_t)h * 16384 + row0 + rseg + s8 * 8]) = v;
            }
        }
        __syncthreads();
    }
}

// ---------------- split-bf16 MFMA GEMM: C[M x N] = X[M x K] @ W[N x K]^T
// BM=128, BN=64, BK=32, 256 threads = 4 waves (2x2), per-wave 64x32 (4x2 16x16 frags)
// MODE 3 grid is (row, col) = (blockIdx.x, blockIdx.y) so the col-blocks sharing one
// X row-panel sit 128 linear-ids apart -> same XCD (128 % 8 == 0) -> X L2-shared.
template <int MODE, bool AGG, bool XBITS, int K, bool XSPLIT, bool WSPLIT>
__global__ __launch_bounds__(256) void mm_kernel(const void* __restrict__ Xp, size_t xplane,
                                                 const ushort_t* __restrict__ W, size_t wplane,
                                                 const float* __restrict__ bias,
                                                 void* __restrict__ outv, size_t oplane,
                                                 int ldx, int ldw, int ldo) {
    __shared__ __align__(16) ushort_t Xs[2][128 * 40];
    __shared__ __align__(16) ushort_t Ws[2][64 * 40];
    int tid = threadIdx.x;
    int row0, col0;
    if constexpr (MODE == 3) {
        row0 = blockIdx.x * 128; col0 = blockIdx.y * 64;
    } else {
        row0 = blockIdx.y * 128; col0 = blockIdx.x * 64;
    }
    const ushort_t* X = (const ushort_t*)Xp;
    const unsigned* Xb = (const unsigned*)Xp;
    size_t out_off = 0;
    int wko = 0;
    if constexpr (AGG) {
        int e = blockIdx.z & 3, bl = blockIdx.z >> 2;
        Xb += (size_t)blockIdx.z * NN * 16;               // A bits for (b_local, e)
        wko = bl * NN;                                    // stateT column offset (n base)
        out_off = (size_t)bl * NN * NN + (size_t)e * HH;  // S2cat[(bl*512+m)*512 + e*128 + h]
    }
    int lane = tid & 63;
    int wave = tid >> 6;
    int wm = wave & 1, wn = wave >> 1;
    int r16 = lane & 15, kg = lane >> 4;

    f32x4 acc[4][2] = {};

    for (int k0 = 0; k0 < K; k0 += 32) {
        bf16x8 xh[2], xl[2];
        unsigned xword;
        if constexpr (XBITS) {
            int m = tid >> 1;
            xword = Xb[(size_t)(row0 + m) * 16 + (k0 >> 5)];
        } else {
            #pragma unroll
            for (int q = 0; q < 2; ++q) {
                int chunk = q * 256 + tid;
                int r = chunk >> 2, kc = chunk & 3;
                const ushort_t* xp = X + (size_t)(row0 + r) * ldx + k0 + kc * 8;
                xh[q] = *reinterpret_cast<const bf16x8*>(xp);
                if constexpr (XSPLIT) xl[q] = *reinterpret_cast<const bf16x8*>(xp + xplane);
            }
        }
        bf16x8 wh, wl;
        {
            int r = tid >> 2, kc = tid & 3;
            const ushort_t* wp2 = W + (size_t)(col0 + r) * ldw + wko + k0 + kc * 8;
            wh = *reinterpret_cast<const bf16x8*>(wp2);
            if constexpr (WSPLIT) wl = *reinterpret_cast<const bf16x8*>(wp2 + wplane);
        }
        __syncthreads();
        if constexpr (XBITS) {
            int m = tid >> 1, sel = tid & 1;
            #pragma unroll
            for (int j8 = 0; j8 < 2; ++j8) {
                bf16x8 xv;
                #pragma unroll
                for (int j = 0; j < 8; ++j)
                    xv[j] = (short)(((xword >> (sel * 16 + j8 * 8 + j)) & 1u) ? 0x3F80 : 0);
                *reinterpret_cast<bf16x8*>(&Xs[0][m * 40 + sel * 16 + j8 * 8]) = xv;
            }
        } else {
            #pragma unroll
            for (int q = 0; q < 2; ++q) {
                int chunk = q * 256 + tid;
                int r = chunk >> 2, kc = chunk & 3;
                *reinterpret_cast<bf16x8*>(&Xs[0][r * 40 + kc * 8]) = xh[q];
                if constexpr (XSPLIT)
                    *reinterpret_cast<bf16x8*>(&Xs[1][r * 40 + kc * 8]) = xl[q];
            }
        }
        {
            int r = tid >> 2, kc = tid & 3;
            *reinterpret_cast<bf16x8*>(&Ws[0][r * 40 + kc * 8]) = wh;
            if constexpr (WSPLIT)
                *reinterpret_cast<bf16x8*>(&Ws[1][r * 40 + kc * 8]) = wl;
        }
        __syncthreads();
        bf16x8 af_h[4], af_l[4], bf_h[2], bf_l[2];
        #pragma unroll
        for (int mi = 0; mi < 4; ++mi) {
            af_h[mi] = *reinterpret_cast<const bf16x8*>(&Xs[0][(wm * 64 + mi * 16 + r16) * 40 + kg * 8]);
            if constexpr (XSPLIT)
                af_l[mi] = *reinterpret_cast<const bf16x8*>(&Xs[1][(wm * 64 + mi * 16 + r16) * 40 + kg * 8]);
        }
        #pragma unroll
        for (int ni = 0; ni < 2; ++ni) {
            bf_h[ni] = *reinterpret_cast<const bf16x8*>(&Ws[0][(wn * 32 + ni * 16 + r16) * 40 + kg * 8]);
            if constexpr (WSPLIT)
                bf_l[ni] = *reinterpret_cast<const bf16x8*>(&Ws[1][(wn * 32 + ni * 16 + r16) * 40 + kg * 8]);
        }
        #pragma unroll
        for (int mi = 0; mi < 4; ++mi)
            #pragma unroll
            for (int ni = 0; ni < 2; ++ni) {
                acc[mi][ni] = __builtin_amdgcn_mfma_f32_16x16x32_bf16(af_h[mi], bf_h[ni], acc[mi][ni], 0, 0, 0);
                if constexpr (XSPLIT)
                    acc[mi][ni] = __builtin_amdgcn_mfma_f32_16x16x32_bf16(af_l[mi], bf_h[ni], acc[mi][ni], 0, 0, 0);
                if constexpr (WSPLIT)
                    acc[mi][ni] = __builtin_amdgcn_mfma_f32_16x16x32_bf16(af_h[mi], bf_l[ni], acc[mi][ni], 0, 0, 0);
            }
    }

    if constexpr (MODE == 3) {
        float* out = (float*)outv;
        #pragma unroll
        for (int ni = 0; ni < 2; ++ni) {
            int col = col0 + wn * 32 + ni * 16 + r16;
            float bv = bias[col];
            #pragma unroll
            for (int mi = 0; mi < 4; ++mi) {
                int rowb = row0 + wm * 64 + mi * 16 + kg * 4;
                #pragma unroll
                for (int j = 0; j < 4; ++j)
                    out[(size_t)(rowb + j) * ldo + col] = acc[mi][ni][j] + bv;
            }
        }
    } else {
        ushort_t* out = (ushort_t*)outv + out_off;
        #pragma unroll
        for (int ni = 0; ni < 2; ++ni) {
            int col = col0 + wn * 32 + ni * 16 + r16;
            #pragma unroll
            for (int mi = 0; mi < 4; ++mi) {
                int rowb = row0 + wm * 64 + mi * 16 + kg * 4;
                #pragma unroll
                for (int j = 0; j < 4; ++j) {
                    float v = acc[mi][ni][j];
                    unsigned short hv = f2bf(v);
                    out[(size_t)(rowb + j) * ldo + col] = hv;
                    out[oplane + (size_t)(rowb + j) * ldo + col] = f2bf(v - bf2f(hv));
                }
            }
        }
    }
}

// ---------------- GRU gates from fp32 gi/gh; updates split state planes
__global__ void gru_gate_kernel(const float* __restrict__ gi, const float* __restrict__ gh,
                                ushort_t* __restrict__ s_hi, ushort_t* __restrict__ s_lo,
                                size_t half_off, int total) {
    int t = blockIdx.x * blockDim.x + threadIdx.x;
    if (t >= total) return;
    int row = t >> 7, j = t & 127;
    const float* gir = gi + (size_t)row * 384;
    const float* ghr = gh + (size_t)row * 384;
    float ir = gir[j], iz = gir[128 + j], in_ = gir[256 + j];
    float hr = ghr[j], hz = ghr[128 + j], hn = ghr[256 + j];
    float r = 1.f / (1.f + expf(-(ir + hr)));
    float z = 1.f / (1.f + expf(-(iz + hz)));
    float n = tanhf(in_ + r * hn);
    size_t g = half_off + (size_t)t;
    float h = bf2f(s_hi[g]) + bf2f(s_lo[g]);
    float v = (1.f - z) * n + z * h;
    unsigned short hv = f2bf(v);
    s_hi[g] = hv;
    s_lo[g] = f2bf(v - bf2f(hv));
}

// ================= set2vec, phase-split =================

__global__ __launch_bounds__(256) void s2v_g_kernel(int step,
        const float* __restrict__ hvec, const float* __restrict__ rpart,
        const float* __restrict__ wih, const float* __restrict__ whh,
        const float* __restrict__ bih, const float* __restrict__ bhh,
        float* __restrict__ g_all) {
    int b = blockIdx.y, tid = threadIdx.x;
    int j = blockIdx.x * 256 + tid;
    __shared__ float q[256];
    if (step > 0) {
        if (tid < 128) q[tid] = hvec[b * 128 + tid];
        else {
            int h2 = tid - 128;
            const float* rp = rpart + (size_t)b * 512;
            q[tid] = rp[h2] + rp[128 + h2] + rp[256 + h2] + rp[384 + h2];
        }
    } else {
        q[tid] = 0.f;
    }
    __syncthreads();
    float acc = bih[j] + bhh[j];
    if (step > 0) {
        const float4* wi = reinterpret_cast<const float4*>(wih + (size_t)j * 256);
        #pragma unroll 8
        for (int d4 = 0; d4 < 64; ++d4) {
            float4 w = wi[d4];
            acc = fmaf(q[d4 * 4 + 0], w.x, fmaf(q[d4 * 4 + 1], w.y,
                  fmaf(q[d4 * 4 + 2], w.z, fmaf(q[d4 * 4 + 3], w.w, acc))));
        }
        const float4* wp = reinterpret_cast<const float4*>(whh + (size_t)j * 128);
        #pragma unroll 8
        for (int d4 = 0; d4 < 32; ++d4) {
            float4 w = wp[d4];
            acc = fmaf(q[d4 * 4 + 0], w.x, fmaf(q[d4 * 4 + 1], w.y,
                  fmaf(q[d4 * 4 + 2], w.z, fmaf(q[d4 * 4 + 3], w.w, acc))));
        }
    }
    g_all[(size_t)b * 512 + j] = acc;
}

__global__ __launch_bounds__(256) void s2v_cl_kernel(int step,
        const float* __restrict__ g_all, float* __restrict__ cvec, float* __restrict__ hvec,
        const ushort_t* __restrict__ s_hi, const ushort_t* __restrict__ s_lo,
        float* __restrict__ logits) {
    int b = blockIdx.y, chunk = blockIdx.x, tid = threadIdx.x;
    __shared__ float hs[HH];
    if (tid < HH) {
        const float* g = g_all + (size_t)b * 512;
        float i_ = 1.f / (1.f + expf(-g[tid]));
        float f_ = 1.f / (1.f + expf(-g[128 + tid]));
        float g_ = tanhf(g[256 + tid]);
        float o_ = 1.f / (1.f + expf(-g[384 + tid]));
        float c0 = (step == 0) ? 0.f : cvec[b * 128 + tid];
        float c2 = f_ * c0 + i_ * g_;
        float hn = o_ * tanhf(c2);
        hs[tid] = hn;
        if (chunk == 0) { cvec[b * 128 + tid] = c2; hvec[b * 128 + tid] = hn; }
    }
    __syncthreads();
    int n = chunk * 256 + tid;
    const ushort_t* ph = s_hi + ((size_t)b * NN + n) * HH;
    const ushort_t* pl = s_lo + ((size_t)b * NN + n) * HH;
    float lg = 0.f;
    #pragma unroll
    for (int i8 = 0; i8 < 16; ++i8) {
        bf16x8 vh = *reinterpret_cast<const bf16x8*>(ph + i8 * 8);
        bf16x8 vl = *reinterpret_cast<const bf16x8*>(pl + i8 * 8);
        #pragma unroll
        for (int k = 0; k < 8; ++k)
            lg = fmaf(bf2f((ushort_t)vh[k]) + bf2f((ushort_t)vl[k]), hs[i8 * 8 + k], lg);
    }
    logits[(size_t)b * 512 + n] = lg;
}

__global__ __launch_bounds__(256) void s2v_read_kernel(const float* __restrict__ logits,
        const ushort_t* __restrict__ t_hi, const ushort_t* __restrict__ t_lo,
        float* __restrict__ rpart) {
    int b = blockIdx.y, chunk = blockIdx.x, tid = threadIdx.x;
    __shared__ float lgs[NN];
    __shared__ float att[128];
    __shared__ float wred[8];
    __shared__ float red[256];
    lgs[tid] = logits[(size_t)b * 512 + tid];
    lgs[256 + tid] = logits[(size_t)b * 512 + 256 + tid];
    __syncthreads();
    float mv = fmaxf(lgs[tid], lgs[tid + 256]);
    #pragma unroll
    for (int m = 32; m >= 1; m >>= 1) mv = fmaxf(mv, __shfl_xor(mv, m));
    if ((tid & 63) == 0) wred[tid >> 6] = mv;
    __syncthreads();
    float mx = fmaxf(fmaxf(wred[0], wred[1]), fmaxf(wred[2], wred[3]));
    float sv = expf(lgs[tid] - mx) + expf(lgs[tid + 256] - mx);
    #pragma unroll
    for (int m = 32; m >= 1; m >>= 1) sv += __shfl_xor(sv, m);
    if ((tid & 63) == 0) wred[4 + (tid >> 6)] = sv;
    __syncthreads();
    float inv = 1.f / (wred[4] + wred[5] + wred[6] + wred[7]);
    if (tid < 128) att[tid] = expf(lgs[chunk * 128 + tid] - mx) * inv;
    __syncthreads();
    int hh = tid & 127, half = tid >> 7;
    int colb = b * NN + chunk * 128 + half * 64;
    const ushort_t* ph = t_hi + (size_t)hh * 16384 + colb;
    const ushort_t* pl = t_lo + (size_t)hh * 16384 + colb;
    float racc = 0.f;
    #pragma unroll
    for (int i8 = 0; i8 < 8; ++i8) {
        bf16x8 vh = *reinterpret_cast<const bf16x8*>(ph + i8 * 8);
        bf16x8 vl = *reinterpret_cast<const bf16x8*>(pl + i8 * 8);
        #pragma unroll
        for (int k = 0; k < 8; ++k)
            racc = fmaf(att[half * 64 + i8 * 8 + k],
                        bf2f((ushort_t)vh[k]) + bf2f((ushort_t)vl[k]), racc);
    }
    red[tid] = racc;
    __syncthreads();
    if (tid < 128)
        rpart[(size_t)b * 512 + chunk * 128 + tid] = red[tid] + red[128 + tid];
}

__global__ __launch_bounds__(256) void s2v_out_kernel(const float* __restrict__ hvec,
        const float* __restrict__ rpart, const float* __restrict__ Wout,
        const float* __restrict__ bout, float* __restrict__ out) {
    int b = blockIdx.x, tid = threadIdx.x;
    __shared__ float q[256];
    if (tid < 128) q[tid] = hvec[b * 128 + tid];
    else {
        int h2 = tid - 128;
        const float* rp = rpart + (size_t)b * 512;
        q[tid] = rp[h2] + rp[128 + h2] + rp[256 + h2] + rp[384 + h2];
    }
    __syncthreads();
    if (tid < DOUT) {
        float acc = bout[tid];
        const float4* w = reinterpret_cast<const float4*>(Wout + (size_t)tid * 256);
        #pragma unroll 8
        for (int d4 = 0; d4 < 64; ++d4) {
            float4 wv = w[d4];
            acc = fmaf(q[d4 * 4 + 0], wv.x, fmaf(q[d4 * 4 + 1], wv.y,
                  fmaf(q[d4 * 4 + 2], wv.z, fmaf(q[d4 * 4 + 3], wv.w, acc))));
        }
        out[b * DOUT + tid] = acc;
    }
}

extern "C" void kernel_launch(void* const* d_in, const int* in_sizes, int n_in,
                              void* d_out, int out_size, void* d_ws, size_t ws_size,
                              hipStream_t stream) {
    const int*   node_feat = (const int*)d_in[0];
    const float* L         = (const float*)d_in[1];
    const float* node_emb  = (const float*)d_in[2];
    const float* W_in      = (const float*)d_in[3];
    const float* b_in      = (const float*)d_in[4];
    const float* edge_emb  = (const float*)d_in[5];
    const float* gru_wih   = (const float*)d_in[6];
    const float* gru_whh   = (const float*)d_in[7];
    const float* gru_bih   = (const float*)d_in[8];
    const float* gru_bhh   = (const float*)d_in[9];
    const float* lstm_wih  = (const float*)d_in[10];
    const float* lstm_whh  = (const float*)d_in[11];
    const float* lstm_bih  = (const float*)d_in[12];
    const float* lstm_bhh  = (const float*)d_in[13];
    const float* W_out     = (const float*)d_in[14];
    const float* b_out     = (const float*)d_in[15];
    float* out = (float*)d_out;

    char* ws = (char*)d_ws;
    const bool full = ws_size >= ((size_t)110 << 20);

    // common: state hi/lo [0..8), stateT hi/lo [8..16), Abits [16..20)
    // full : S2 [20..52) plane 8388608 | gi [52..76) | gh [76..100) | W [100..101) | s2v [101..]
    // half : S2 [20..36) plane 4194304 | gi [36..48) | gh [48..60) | W [60..61)  | s2v [61..]
    ushort_t* state_hi  = (ushort_t*)ws;
    ushort_t* stateT_hi = (ushort_t*)(ws + (8u << 20));
    unsigned* Abits     = (unsigned*)(ws + (16u << 20));
    ushort_t* S2        = (ushort_t*)(ws + (20u << 20));
    size_t s2plane      = full ? 8388608u : 4194304u;
    float*    gi        = (float*)(ws + (full ? (52ull << 20) : (36ull << 20)));
    float*    gh        = (float*)(ws + (full ? (76ull << 20) : (48ull << 20)));
    ushort_t* U_h       = (ushort_t*)(ws + (full ? (100ull << 20) : (60ull << 20)));
    ushort_t* U_l       = U_h + 196608;
    ushort_t* whh_h     = U_l + 196608;
    ushort_t* whh_l     = whh_h + 49152;
    float*    s2v       = (float*)(ws + (full ? (101ull << 20) : (61ull << 20)));
    float*    g_all     = s2v;            // 16384
    float*    logits    = s2v + 16384;    // 16384
    float*    hvec      = s2v + 32768;    // 4096
    float*    cvec      = s2v + 36864;    // 4096
    float*    rpart     = s2v + 40960;    // 16384

    const size_t SPLANE = 2097152;    // state/stateT plane stride (elems)

    pack_A_kernel<<<(BB * NN * NN) / 256, 256, 0, stream>>>(L, Abits);
    convW_kernel<<<(384 * 512 + 384 * 128) / 256, 256, 0, stream>>>(
        edge_emb, gru_wih, gru_whh, U_h, U_l, whh_h, whh_l);
    embed_kernel<<<BB * NN, 128, 0, stream>>>(node_feat, node_emb, W_in, b_in,
                                              state_hi, state_hi + SPLANE);

    const int nh   = full ? 1 : 2;
    const int zdim = full ? 128 : 64;    // graphs in dispatch * E1
    const int ydim = full ? 128 : 64;    // M / 128
    const int rows = full ? 16384 : MHALF;

    for (int p = 0; p < NPROP; ++p) {
        transpose_kernel<<<256, 256, 0, stream>>>(state_hi, stateT_hi, SPLANE);
        for (int half = 0; half < nh; ++half) {
            const unsigned* Ab = Abits + (size_t)half * 16 * E1 * NN * 16;
            // S2[(bl*512+m)][e*128+h] = A_be @ state_b : per z M=512, N=128, K=512
            mm_kernel<4, true, true, 512, false, true><<<dim3(2, 4, zdim), 256, 0, stream>>>(
                Ab, 0, stateT_hi + (size_t)half * MHALF, SPLANE, nullptr,
                S2, s2plane, 0, 16384, 512);
            // gi = S2 @ U^T + bih : N=384, K=512 -> fp32   (grid = (rows, cols) for XCD locality)
            mm_kernel<3, false, false, 512, true, true><<<dim3(ydim, 6), 256, 0, stream>>>(
                S2, s2plane, U_h, 196608, gru_bih, gi, 0, 512, 512, 384);
            // gh = state @ whh^T + bhh : N=384, K=128 -> fp32
            mm_kernel<3, false, false, 128, true, true><<<dim3(ydim, 6), 256, 0, stream>>>(
                state_hi + (size_t)half * MHALF * HH, SPLANE, whh_h, 49152, gru_bhh,
                gh, 0, 128, 128, 384);
            // gates -> state planes
            gru_gate_kernel<<<(rows * HH) / 256, 256, 0, stream>>>(
                gi, gh, state_hi, state_hi + SPLANE,
                (size_t)half * MHALF * HH, rows * HH);
        }
    }
    // fresh stateT for the s2v read phase
    transpose_kernel<<<256, 256, 0, stream>>>(state_hi, stateT_hi, SPLANE);

    for (int step = 0; step < NS2V; ++step) {
        s2v_g_kernel<<<dim3(2, BB), 256, 0, stream>>>(step, hvec, rpart,
                                                      lstm_wih, lstm_whh, lstm_bih, lstm_bhh,
                                                      g_all);
        s2v_cl_kernel<<<dim3(2, BB), 256, 0, stream>>>(step, g_all, cvec, hvec,
                                                       state_hi, state_hi + SPLANE, logits);
        s2v_read_kernel<<<dim3(4, BB), 256, 0, stream>>>(logits, stateT_hi,
                                                         stateT_hi + SPLANE, rpart);
    }
    s2v_out_kernel<<<BB, 256, 0, stream>>>(hvec, rpart, W_out, b_out, out);
}

// Round 12
// 588.748 us; speedup vs baseline: 1.2295x; 1.0138x over previous
//
#include <hip/hip_runtime.h>
#include <hip/hip_bf16.h>

#define BB 32
#define NN 512
#define DA 100
#define DIN 64
#define HH 128
#define E1 4
#define DOUT 16
#define NPROP 5
#define NS2V 3
#define MHALF 8192          // rows per half-batch (16 graphs)

typedef __attribute__((ext_vector_type(8))) short bf16x8;
typedef __attribute__((ext_vector_type(4))) float f32x4;
typedef __attribute__((ext_vector_type(4))) unsigned short us4;
typedef __attribute__((ext_vector_type(8))) unsigned short us8;
typedef unsigned short ushort_t;

__device__ __forceinline__ unsigned short f2bf(float f) {
    __hip_bfloat16 h = __float2bfloat16(f);
    return *reinterpret_cast<unsigned short*>(&h);
}
__device__ __forceinline__ float bf2f(unsigned short u) {
    unsigned v = ((unsigned)u) << 16;
    float f;
    __builtin_memcpy(&f, &v, 4);
    return f;
}

// ---------------- pack A bits (coalesced + ballot)
__global__ __launch_bounds__(256) void pack_A_kernel(const float* __restrict__ L,
                                                     unsigned* __restrict__ Abits) {
    int t = blockIdx.x * 256 + threadIdx.x;    // (b, m, n)
    int n = t & (NN - 1);
    int m = (t >> 9) & (NN - 1);
    int b = t >> 18;
    float4 v = *reinterpret_cast<const float4*>(L + ((size_t)(b * NN + m) * NN + n) * E1);
    unsigned long long mk[E1];
    mk[0] = __ballot(v.x != 0.f);
    mk[1] = __ballot(v.y != 0.f);
    mk[2] = __ballot(v.z != 0.f);
    mk[3] = __ballot(v.w != 0.f);
    int lane = threadIdx.x & 63;
    if (lane < 8) {
        int e = lane >> 1, half = lane & 1;
        unsigned word = half ? (unsigned)(mk[e] >> 32) : (unsigned)mk[e];
        int wbase = (n >> 5) & ~1;             // word index of wave's first n
        Abits[((size_t)(b * E1 + e) * NN + m) * 16 + wbase + half] = word;
    }
}

// ---------------- fused-weight precompute:
// U[j, e*128+h] = sum_k wih[j, e*128+k] * edge_emb[e, h*128+k]   (fp32, then split bf16)
__global__ void convW_kernel(const float* __restrict__ EE, const float* __restrict__ wih,
                             const float* __restrict__ whh,
                             ushort_t* __restrict__ U_h, ushort_t* __restrict__ U_l,
                             ushort_t* __restrict__ whh_h, ushort_t* __restrict__ whh_l) {
    int t = blockIdx.x * blockDim.x + threadIdx.x;
    if (t < 384 * 512) {
        int col = t & 511;
        int j = t >> 9;
        int e = col >> 7, h = col & 127;
        const float4* wp = reinterpret_cast<const float4*>(wih + (size_t)j * 512 + e * 128);
        const float4* ep = reinterpret_cast<const float4*>(EE + (size_t)e * 16384 + h * 128);
        float acc = 0.f;
        #pragma unroll 8
        for (int k4 = 0; k4 < 32; ++k4) {
            float4 a = wp[k4], b = ep[k4];
            acc = fmaf(a.x, b.x, fmaf(a.y, b.y, fmaf(a.z, b.z, fmaf(a.w, b.w, acc))));
        }
        unsigned short hi = f2bf(acc);
        U_h[t] = hi;
        U_l[t] = f2bf(acc - bf2f(hi));
        return;
    }
    int t2 = t - 384 * 512;
    if (t2 < 384 * 128) {
        float v = whh[t2];
        unsigned short hi = f2bf(v);
        whh_h[t2] = hi;
        whh_l[t2] = f2bf(v - bf2f(hi));
    }
}

// ---------------- embed: state[row, h] = node_emb[nf[row]] . W_in[h,:] + b_in[h] -> split planes
__global__ void embed_kernel(const int* __restrict__ nf, const float* __restrict__ emb,
                             const float* __restrict__ Win, const float* __restrict__ bin,
                             ushort_t* __restrict__ s_hi, ushort_t* __restrict__ s_lo) {
    int row = blockIdx.x;
    int h = threadIdx.x;
    __shared__ float e[DIN];
    int a = nf[row];
    if (h < DIN) e[h] = emb[a * DIN + h];
    __syncthreads();
    float acc = bin[h];
    const float* w = Win + h * DIN;
    #pragma unroll
    for (int d = 0; d < DIN; ++d) acc = fmaf(e[d], w[d], acc);
    unsigned short hi = f2bf(acc);
    s_hi[row * HH + h] = hi;
    s_lo[row * HH + h] = f2bf(acc - bf2f(hi));
}

// ---------------- transpose state planes: [16384][128] -> [128][16384]
__global__ __launch_bounds__(256) void transpose_kernel(const ushort_t* __restrict__ src,
                                                        ushort_t* __restrict__ dst,
                                                        size_t splane) {
    __shared__ __align__(16) ushort_t tile[128][72];
    int row0 = blockIdx.x * 64;
    int tid = threadIdx.x;
    #pragma unroll
    for (int pl = 0; pl < 2; ++pl) {
        const ushort_t* s = src + pl * splane;
        ushort_t* d = dst + pl * splane;
        #pragma unroll
        for (int q = 0; q < 4; ++q) {
            int idx = q * 256 + tid;
            int r = idx >> 4, h8 = idx & 15;
            bf16x8 v = *reinterpret_cast<const bf16x8*>(s + (size_t)(row0 + r) * HH + h8 * 8);
            #pragma unroll
            for (int j = 0; j < 8; ++j) tile[h8 * 8 + j][r] = (ushort_t)v[j];
        }
        __syncthreads();
        {
            int h = tid >> 1, rseg = (tid & 1) * 32;
            #pragma unroll
            for (int s8 = 0; s8 < 4; ++s8) {
                us8 v = *reinterpret_cast<const us8*>(&tile[h][rseg + s8 * 8]);
                *reinterpret_cast<us8*>(&d[(size_t)h * 16384 + row0 + rseg + s8 * 8]) = v;
            }
        }
        __syncthreads();
    }
}

// ---------------- split-bf16 MFMA GEMM: C[M x N] = X[M x K] @ W[N x K]^T
// BM=128, BN=64, BK=32, 256 threads = 4 waves (2x2), per-wave 64x32 (4x2 16x16 frags)
// MODE 3: grid (row, col) -> col-sharers 128 ids apart -> same XCD (X panel L2-shared).
// AGG:    grid (graph, rowcol, e) -> all 32 sharers of a graph's stateT == graph (mod 8)
//         -> one XCD per graph panel.
template <int MODE, bool AGG, bool XBITS, int K, bool XSPLIT, bool WSPLIT>
__global__ __launch_bounds__(256) void mm_kernel(const void* __restrict__ Xp, size_t xplane,
                                                 const ushort_t* __restrict__ W, size_t wplane,
                                                 const float* __restrict__ bias,
                                                 void* __restrict__ outv, size_t oplane,
                                                 int ldx, int ldw, int ldo) {
    __shared__ __align__(16) ushort_t Xs[2][128 * 40];
    __shared__ __align__(16) ushort_t Ws[2][64 * 40];
    int tid = threadIdx.x;
    int row0, col0;
    if constexpr (MODE == 3) {
        row0 = blockIdx.x * 128; col0 = blockIdx.y * 64;
    } else if constexpr (AGG) {
        row0 = (blockIdx.y & 3) * 128; col0 = (blockIdx.y >> 2) * 64;
    } else {
        row0 = blockIdx.y * 128; col0 = blockIdx.x * 64;
    }
    const ushort_t* X = (const ushort_t*)Xp;
    const unsigned* Xb = (const unsigned*)Xp;
    size_t out_off = 0;
    int wko = 0;
    if constexpr (AGG) {
        int bl = blockIdx.x, e = blockIdx.z;
        Xb += (size_t)(bl * E1 + e) * NN * 16;            // A bits for (b_local, e)
        wko = bl * NN;                                    // stateT column offset (n base)
        out_off = (size_t)bl * NN * NN + (size_t)e * HH;  // S2cat[(bl*512+m)*512 + e*128 + h]
    }
    int lane = tid & 63;
    int wave = tid >> 6;
    int wm = wave & 1, wn = wave >> 1;
    int r16 = lane & 15, kg = lane >> 4;

    f32x4 acc[4][2] = {};

    for (int k0 = 0; k0 < K; k0 += 32) {
        bf16x8 xh[2], xl[2];
        unsigned xword;
        if constexpr (XBITS) {
            int m = tid >> 1;
            xword = Xb[(size_t)(row0 + m) * 16 + (k0 >> 5)];
        } else {
            #pragma unroll
            for (int q = 0; q < 2; ++q) {
                int chunk = q * 256 + tid;
                int r = chunk >> 2, kc = chunk & 3;
                const ushort_t* xp = X + (size_t)(row0 + r) * ldx + k0 + kc * 8;
                xh[q] = *reinterpret_cast<const bf16x8*>(xp);
                if constexpr (XSPLIT) xl[q] = *reinterpret_cast<const bf16x8*>(xp + xplane);
            }
        }
        bf16x8 wh, wl;
        {
            int r = tid >> 2, kc = tid & 3;
            const ushort_t* wp2 = W + (size_t)(col0 + r) * ldw + wko + k0 + kc * 8;
            wh = *reinterpret_cast<const bf16x8*>(wp2);
            if constexpr (WSPLIT) wl = *reinterpret_cast<const bf16x8*>(wp2 + wplane);
        }
        __syncthreads();
        if constexpr (XBITS) {
            int m = tid >> 1, sel = tid & 1;
            #pragma unroll
            for (int j8 = 0; j8 < 2; ++j8) {
                bf16x8 xv;
                #pragma unroll
                for (int j = 0; j < 8; ++j)
                    xv[j] = (short)(((xword >> (sel * 16 + j8 * 8 + j)) & 1u) ? 0x3F80 : 0);
                *reinterpret_cast<bf16x8*>(&Xs[0][m * 40 + sel * 16 + j8 * 8]) = xv;
            }
        } else {
            #pragma unroll
            for (int q = 0; q < 2; ++q) {
                int chunk = q * 256 + tid;
                int r = chunk >> 2, kc = chunk & 3;
                *reinterpret_cast<bf16x8*>(&Xs[0][r * 40 + kc * 8]) = xh[q];
                if constexpr (XSPLIT)
                    *reinterpret_cast<bf16x8*>(&Xs[1][r * 40 + kc * 8]) = xl[q];
            }
        }
        {
            int r = tid >> 2, kc = tid & 3;
            *reinterpret_cast<bf16x8*>(&Ws[0][r * 40 + kc * 8]) = wh;
            if constexpr (WSPLIT)
                *reinterpret_cast<bf16x8*>(&Ws[1][r * 40 + kc * 8]) = wl;
        }
        __syncthreads();
        bf16x8 af_h[4], af_l[4], bf_h[2], bf_l[2];
        #pragma unroll
        for (int mi = 0; mi < 4; ++mi) {
            af_h[mi] = *reinterpret_cast<const bf16x8*>(&Xs[0][(wm * 64 + mi * 16 + r16) * 40 + kg * 8]);
            if constexpr (XSPLIT)
                af_l[mi] = *reinterpret_cast<const bf16x8*>(&Xs[1][(wm * 64 + mi * 16 + r16) * 40 + kg * 8]);
        }
        #pragma unroll
        for (int ni = 0; ni < 2; ++ni) {
            bf_h[ni] = *reinterpret_cast<const bf16x8*>(&Ws[0][(wn * 32 + ni * 16 + r16) * 40 + kg * 8]);
            if constexpr (WSPLIT)
                bf_l[ni] = *reinterpret_cast<const bf16x8*>(&Ws[1][(wn * 32 + ni * 16 + r16) * 40 + kg * 8]);
        }
        #pragma unroll
        for (int mi = 0; mi < 4; ++mi)
            #pragma unroll
            for (int ni = 0; ni < 2; ++ni) {
                acc[mi][ni] = __builtin_amdgcn_mfma_f32_16x16x32_bf16(af_h[mi], bf_h[ni], acc[mi][ni], 0, 0, 0);
                if constexpr (XSPLIT)
                    acc[mi][ni] = __builtin_amdgcn_mfma_f32_16x16x32_bf16(af_l[mi], bf_h[ni], acc[mi][ni], 0, 0, 0);
                if constexpr (WSPLIT)
                    acc[mi][ni] = __builtin_amdgcn_mfma_f32_16x16x32_bf16(af_h[mi], bf_l[ni], acc[mi][ni], 0, 0, 0);
            }
    }

    if constexpr (MODE == 3) {
        float* out = (float*)outv;
        #pragma unroll
        for (int ni = 0; ni < 2; ++ni) {
            int col = col0 + wn * 32 + ni * 16 + r16;
            float bv = bias[col];
            #pragma unroll
            for (int mi = 0; mi < 4; ++mi) {
                int rowb = row0 + wm * 64 + mi * 16 + kg * 4;
                #pragma unroll
                for (int j = 0; j < 4; ++j)
                    out[(size_t)(rowb + j) * ldo + col] = acc[mi][ni][j] + bv;
            }
        }
    } else {
        ushort_t* out = (ushort_t*)outv + out_off;
        #pragma unroll
        for (int ni = 0; ni < 2; ++ni) {
            int col = col0 + wn * 32 + ni * 16 + r16;
            #pragma unroll
            for (int mi = 0; mi < 4; ++mi) {
                int rowb = row0 + wm * 64 + mi * 16 + kg * 4;
                #pragma unroll
                for (int j = 0; j < 4; ++j) {
                    float v = acc[mi][ni][j];
                    unsigned short hv = f2bf(v);
                    out[(size_t)(rowb + j) * ldo + col] = hv;
                    out[oplane + (size_t)(rowb + j) * ldo + col] = f2bf(v - bf2f(hv));
                }
            }
        }
    }
}

// ---------------- GRU gates from fp32 gi/gh; updates split state planes
__global__ void gru_gate_kernel(const float* __restrict__ gi, const float* __restrict__ gh,
                                ushort_t* __restrict__ s_hi, ushort_t* __restrict__ s_lo,
                                size_t half_off, int total) {
    int t = blockIdx.x * blockDim.x + threadIdx.x;
    if (t >= total) return;
    int row = t >> 7, j = t & 127;
    const float* gir = gi + (size_t)row * 384;
    const float* ghr = gh + (size_t)row * 384;
    float ir = gir[j], iz = gir[128 + j], in_ = gir[256 + j];
    float hr = ghr[j], hz = ghr[128 + j], hn = ghr[256 + j];
    float r = 1.f / (1.f + expf(-(ir + hr)));
    float z = 1.f / (1.f + expf(-(iz + hz)));
    float n = tanhf(in_ + r * hn);
    size_t g = half_off + (size_t)t;
    float h = bf2f(s_hi[g]) + bf2f(s_lo[g]);
    float v = (1.f - z) * n + z * h;
    unsigned short hv = f2bf(v);
    s_hi[g] = hv;
    s_lo[g] = f2bf(v - bf2f(hv));
}

// ================= set2vec, phase-split =================

__global__ __launch_bounds__(256) void s2v_g_kernel(int step,
        const float* __restrict__ hvec, const float* __restrict__ rpart,
        const float* __restrict__ wih, const float* __restrict__ whh,
        const float* __restrict__ bih, const float* __restrict__ bhh,
        float* __restrict__ g_all) {
    int b = blockIdx.y, tid = threadIdx.x;
    int j = blockIdx.x * 256 + tid;
    __shared__ float q[256];
    if (step > 0) {
        if (tid < 128) q[tid] = hvec[b * 128 + tid];
        else {
            int h2 = tid - 128;
            const float* rp = rpart + (size_t)b * 512;
            q[tid] = rp[h2] + rp[128 + h2] + rp[256 + h2] + rp[384 + h2];
        }
    } else {
        q[tid] = 0.f;
    }
    __syncthreads();
    float acc = bih[j] + bhh[j];
    if (step > 0) {
        const float4* wi = reinterpret_cast<const float4*>(wih + (size_t)j * 256);
        #pragma unroll 8
        for (int d4 = 0; d4 < 64; ++d4) {
            float4 w = wi[d4];
            acc = fmaf(q[d4 * 4 + 0], w.x, fmaf(q[d4 * 4 + 1], w.y,
                  fmaf(q[d4 * 4 + 2], w.z, fmaf(q[d4 * 4 + 3], w.w, acc))));
        }
        const float4* wp = reinterpret_cast<const float4*>(whh + (size_t)j * 128);
        #pragma unroll 8
        for (int d4 = 0; d4 < 32; ++d4) {
            float4 w = wp[d4];
            acc = fmaf(q[d4 * 4 + 0], w.x, fmaf(q[d4 * 4 + 1], w.y,
                  fmaf(q[d4 * 4 + 2], w.z, fmaf(q[d4 * 4 + 3], w.w, acc))));
        }
    }
    g_all[(size_t)b * 512 + j] = acc;
}

__global__ __launch_bounds__(256) void s2v_cl_kernel(int step,
        const float* __restrict__ g_all, float* __restrict__ cvec, float* __restrict__ hvec,
        const ushort_t* __restrict__ s_hi, const ushort_t* __restrict__ s_lo,
        float* __restrict__ logits) {
    int b = blockIdx.y, chunk = blockIdx.x, tid = threadIdx.x;
    __shared__ float hs[HH];
    if (tid < HH) {
        const float* g = g_all + (size_t)b * 512;
        float i_ = 1.f / (1.f + expf(-g[tid]));
        float f_ = 1.f / (1.f + expf(-g[128 + tid]));
        float g_ = tanhf(g[256 + tid]);
        float o_ = 1.f / (1.f + expf(-g[384 + tid]));
        float c0 = (step == 0) ? 0.f : cvec[b * 128 + tid];
        float c2 = f_ * c0 + i_ * g_;
        float hn = o_ * tanhf(c2);
        hs[tid] = hn;
        if (chunk == 0) { cvec[b * 128 + tid] = c2; hvec[b * 128 + tid] = hn; }
    }
    __syncthreads();
    int n = chunk * 256 + tid;
    const ushort_t* ph = s_hi + ((size_t)b * NN + n) * HH;
    const ushort_t* pl = s_lo + ((size_t)b * NN + n) * HH;
    float lg = 0.f;
    #pragma unroll
    for (int i8 = 0; i8 < 16; ++i8) {
        bf16x8 vh = *reinterpret_cast<const bf16x8*>(ph + i8 * 8);
        bf16x8 vl = *reinterpret_cast<const bf16x8*>(pl + i8 * 8);
        #pragma unroll
        for (int k = 0; k < 8; ++k)
            lg = fmaf(bf2f((ushort_t)vh[k]) + bf2f((ushort_t)vl[k]), hs[i8 * 8 + k], lg);
    }
    logits[(size_t)b * 512 + n] = lg;
}

__global__ __launch_bounds__(256) void s2v_read_kernel(const float* __restrict__ logits,
        const ushort_t* __restrict__ t_hi, const ushort_t* __restrict__ t_lo,
        float* __restrict__ rpart) {
    int b = blockIdx.y, chunk = blockIdx.x, tid = threadIdx.x;
    __shared__ float lgs[NN];
    __shared__ float att[128];
    __shared__ float wred[8];
    __shared__ float red[256];
    lgs[tid] = logits[(size_t)b * 512 + tid];
    lgs[256 + tid] = logits[(size_t)b * 512 + 256 + tid];
    __syncthreads();
    float mv = fmaxf(lgs[tid], lgs[tid + 256]);
    #pragma unroll
    for (int m = 32; m >= 1; m >>= 1) mv = fmaxf(mv, __shfl_xor(mv, m));
    if ((tid & 63) == 0) wred[tid >> 6] = mv;
    __syncthreads();
    float mx = fmaxf(fmaxf(wred[0], wred[1]), fmaxf(wred[2], wred[3]));
    float sv = expf(lgs[tid] - mx) + expf(lgs[tid + 256] - mx);
    #pragma unroll
    for (int m = 32; m >= 1; m >>= 1) sv += __shfl_xor(sv, m);
    if ((tid & 63) == 0) wred[4 + (tid >> 6)] = sv;
    __syncthreads();
    float inv = 1.f / (wred[4] + wred[5] + wred[6] + wred[7]);
    if (tid < 128) att[tid] = expf(lgs[chunk * 128 + tid] - mx) * inv;
    __syncthreads();
    int hh = tid & 127, half = tid >> 7;
    int colb = b * NN + chunk * 128 + half * 64;
    const ushort_t* ph = t_hi + (size_t)hh * 16384 + colb;
    const ushort_t* pl = t_lo + (size_t)hh * 16384 + colb;
    float racc = 0.f;
    #pragma unroll
    for (int i8 = 0; i8 < 8; ++i8) {
        bf16x8 vh = *reinterpret_cast<const bf16x8*>(ph + i8 * 8);
        bf16x8 vl = *reinterpret_cast<const bf16x8*>(pl + i8 * 8);
        #pragma unroll
        for (int k = 0; k < 8; ++k)
            racc = fmaf(att[half * 64 + i8 * 8 + k],
                        bf2f((ushort_t)vh[k]) + bf2f((ushort_t)vl[k]), racc);
    }
    red[tid] = racc;
    __syncthreads();
    if (tid < 128)
        rpart[(size_t)b * 512 + chunk * 128 + tid] = red[tid] + red[128 + tid];
}

__global__ __launch_bounds__(256) void s2v_out_kernel(const float* __restrict__ hvec,
        const float* __restrict__ rpart, const float* __restrict__ Wout,
        const float* __restrict__ bout, float* __restrict__ out) {
    int b = blockIdx.x, tid = threadIdx.x;
    __shared__ float q[256];
    if (tid < 128) q[tid] = hvec[b * 128 + tid];
    else {
        int h2 = tid - 128;
        const float* rp = rpart + (size_t)b * 512;
        q[tid] = rp[h2] + rp[128 + h2] + rp[256 + h2] + rp[384 + h2];
    }
    __syncthreads();
    if (tid < DOUT) {
        float acc = bout[tid];
        const float4* w = reinterpret_cast<const float4*>(Wout + (size_t)tid * 256);
        #pragma unroll 8
        for (int d4 = 0; d4 < 64; ++d4) {
            float4 wv = w[d4];
            acc = fmaf(q[d4 * 4 + 0], wv.x, fmaf(q[d4 * 4 + 1], wv.y,
                  fmaf(q[d4 * 4 + 2], wv.z, fmaf(q[d4 * 4 + 3], wv.w, acc))));
        }
        out[b * DOUT + tid] = acc;
    }
}

extern "C" void kernel_launch(void* const* d_in, const int* in_sizes, int n_in,
                              void* d_out, int out_size, void* d_ws, size_t ws_size,
                              hipStream_t stream) {
    const int*   node_feat = (const int*)d_in[0];
    const float* L         = (const float*)d_in[1];
    const float* node_emb  = (const float*)d_in[2];
    const float* W_in      = (const float*)d_in[3];
    const float* b_in      = (const float*)d_in[4];
    const float* edge_emb  = (const float*)d_in[5];
    const float* gru_wih   = (const float*)d_in[6];
    const float* gru_whh   = (const float*)d_in[7];
    const float* gru_bih   = (const float*)d_in[8];
    const float* gru_bhh   = (const float*)d_in[9];
    const float* lstm_wih  = (const float*)d_in[10];
    const float* lstm_whh  = (const float*)d_in[11];
    const float* lstm_bih  = (const float*)d_in[12];
    const float* lstm_bhh  = (const float*)d_in[13];
    const float* W_out     = (const float*)d_in[14];
    const float* b_out     = (const float*)d_in[15];
    float* out = (float*)d_out;

    char* ws = (char*)d_ws;
    const bool full = ws_size >= ((size_t)110 << 20);

    // common: state hi/lo [0..8), stateT hi/lo [8..16), Abits [16..20)
    // full : S2 [20..52) plane 8388608 | gi [52..76) | gh [76..100) | W [100..101) | s2v [101..]
    // half : S2 [20..36) plane 4194304 | gi [36..48) | gh [48..60) | W [60..61)  | s2v [61..]
    ushort_t* state_hi  = (ushort_t*)ws;
    ushort_t* stateT_hi = (ushort_t*)(ws + (8u << 20));
    unsigned* Abits     = (unsigned*)(ws + (16u << 20));
    ushort_t* S2        = (ushort_t*)(ws + (20u << 20));
    size_t s2plane      = full ? 8388608u : 4194304u;
    float*    gi        = (float*)(ws + (full ? (52ull << 20) : (36ull << 20)));
    float*    gh        = (float*)(ws + (full ? (76ull << 20) : (48ull << 20)));
    ushort_t* U_h       = (ushort_t*)(ws + (full ? (100ull << 20) : (60ull << 20)));
    ushort_t* U_l       = U_h + 196608;
    ushort_t* whh_h     = U_l + 196608;
    ushort_t* whh_l     = whh_h + 49152;
    float*    s2v       = (float*)(ws + (full ? (101ull << 20) : (61ull << 20)));
    float*    g_all     = s2v;            // 16384
    float*    logits    = s2v + 16384;    // 16384
    float*    hvec      = s2v + 32768;    // 4096
    float*    cvec      = s2v + 36864;    // 4096
    float*    rpart     = s2v + 40960;    // 16384

    const size_t SPLANE = 2097152;    // state/stateT plane stride (elems)

    pack_A_kernel<<<(BB * NN * NN) / 256, 256, 0, stream>>>(L, Abits);
    convW_kernel<<<(384 * 512 + 384 * 128) / 256, 256, 0, stream>>>(
        edge_emb, gru_wih, gru_whh, U_h, U_l, whh_h, whh_l);
    embed_kernel<<<BB * NN, 128, 0, stream>>>(node_feat, node_emb, W_in, b_in,
                                              state_hi, state_hi + SPLANE);

    const int nh     = full ? 1 : 2;
    const int graphs = full ? 32 : 16;   // graphs per dispatch
    const int ydim   = full ? 128 : 64;  // M / 128
    const int rows   = full ? 16384 : MHALF;

    for (int p = 0; p < NPROP; ++p) {
        transpose_kernel<<<256, 256, 0, stream>>>(state_hi, stateT_hi, SPLANE);
        for (int half = 0; half < nh; ++half) {
            const unsigned* Ab = Abits + (size_t)half * 16 * E1 * NN * 16;
            // S2: grid (graph, rowcol, e) -> per-graph stateT panel pinned to one XCD
            mm_kernel<4, true, true, 512, false, true><<<dim3(graphs, 8, 4), 256, 0, stream>>>(
                Ab, 0, stateT_hi + (size_t)half * MHALF, SPLANE, nullptr,
                S2, s2plane, 0, 16384, 512);
            // gi = S2 @ U^T + bih : N=384, K=512 -> fp32   (grid = (rows, cols) for XCD locality)
            mm_kernel<3, false, false, 512, true, true><<<dim3(ydim, 6), 256, 0, stream>>>(
                S2, s2plane, U_h, 196608, gru_bih, gi, 0, 512, 512, 384);
            // gh = state @ whh^T + bhh : N=384, K=128 -> fp32
            mm_kernel<3, false, false, 128, true, true><<<dim3(ydim, 6), 256, 0, stream>>>(
                state_hi + (size_t)half * MHALF * HH, SPLANE, whh_h, 49152, gru_bhh,
                gh, 0, 128, 128, 384);
            // gates -> state planes
            gru_gate_kernel<<<(rows * HH) / 256, 256, 0, stream>>>(
                gi, gh, state_hi, state_hi + SPLANE,
                (size_t)half * MHALF * HH, rows * HH);
        }
    }
    // fresh stateT for the s2v read phase
    transpose_kernel<<<256, 256, 0, stream>>>(state_hi, stateT_hi, SPLANE);

    for (int step = 0; step < NS2V; ++step) {
        s2v_g_kernel<<<dim3(2, BB), 256, 0, stream>>>(step, hvec, rpart,
                                                      lstm_wih, lstm_whh, lstm_bih, lstm_bhh,
                                                      g_all);
        s2v_cl_kernel<<<dim3(2, BB), 256, 0, stream>>>(step, g_all, cvec, hvec,
                                                       state_hi, state_hi + SPLANE, logits);
        s2v_read_kernel<<<dim3(4, BB), 256, 0, stream>>>(logits, stateT_hi,
                                                         stateT_hi + SPLANE, rpart);
    }
    s2v_out_kernel<<<BB, 256, 0, stream>>>(hvec, rpart, W_out, b_out, out);
}

// Round 13
// 581.097 us; speedup vs baseline: 1.2457x; 1.0132x over previous
//
#include <hip/hip_runtime.h>
#include <hip/hip_bf16.h>

#define BB 32
#define NN 512
#define DA 100
#define DIN 64
#define HH 128
#define E1 4
#define DOUT 16
#define NPROP 5
#define NS2V 3
#define MHALF 8192          // rows per half-batch (16 graphs)

typedef __attribute__((ext_vector_type(8))) short bf16x8;
typedef __attribute__((ext_vector_type(4))) float f32x4;
typedef __attribute__((ext_vector_type(4))) unsigned short us4;
typedef __attribute__((ext_vector_type(8))) unsigned short us8;
typedef unsigned short ushort_t;

__device__ __forceinline__ unsigned short f2bf(float f) {
    __hip_bfloat16 h = __float2bfloat16(f);
    return *reinterpret_cast<unsigned short*>(&h);
}
__device__ __forceinline__ float bf2f(unsigned short u) {
    unsigned v = ((unsigned)u) << 16;
    float f;
    __builtin_memcpy(&f, &v, 4);
    return f;
}

// async global->LDS DMA, 16 B per lane: LDS dest = uniform base + lane*16,
// global src = per-lane address. (m97 ladder pattern.)
__device__ __forceinline__ void gload_lds16(const void* g, void* l) {
    __builtin_amdgcn_global_load_lds(
        (const __attribute__((address_space(1))) void*)g,
        (__attribute__((address_space(3))) void*)l, 16, 0, 0);
}

// ---------------- pack A bits (coalesced + ballot)
__global__ __launch_bounds__(256) void pack_A_kernel(const float* __restrict__ L,
                                                     unsigned* __restrict__ Abits) {
    int t = blockIdx.x * 256 + threadIdx.x;    // (b, m, n)
    int n = t & (NN - 1);
    int m = (t >> 9) & (NN - 1);
    int b = t >> 18;
    float4 v = *reinterpret_cast<const float4*>(L + ((size_t)(b * NN + m) * NN + n) * E1);
    unsigned long long mk[E1];
    mk[0] = __ballot(v.x != 0.f);
    mk[1] = __ballot(v.y != 0.f);
    mk[2] = __ballot(v.z != 0.f);
    mk[3] = __ballot(v.w != 0.f);
    int lane = threadIdx.x & 63;
    if (lane < 8) {
        int e = lane >> 1, half = lane & 1;
        unsigned word = half ? (unsigned)(mk[e] >> 32) : (unsigned)mk[e];
        int wbase = (n >> 5) & ~1;             // word index of wave's first n
        Abits[((size_t)(b * E1 + e) * NN + m) * 16 + wbase + half] = word;
    }
}

// ---------------- fused-weight precompute:
// U[j, e*128+h] = sum_k wih[j, e*128+k] * edge_emb[e, h*128+k]   (fp32, then split bf16)
__global__ void convW_kernel(const float* __restrict__ EE, const float* __restrict__ wih,
                             const float* __restrict__ whh,
                             ushort_t* __restrict__ U_h, ushort_t* __restrict__ U_l,
                             ushort_t* __restrict__ whh_h, ushort_t* __restrict__ whh_l) {
    int t = blockIdx.x * blockDim.x + threadIdx.x;
    if (t < 384 * 512) {
        int col = t & 511;
        int j = t >> 9;
        int e = col >> 7, h = col & 127;
        const float4* wp = reinterpret_cast<const float4*>(wih + (size_t)j * 512 + e * 128);
        const float4* ep = reinterpret_cast<const float4*>(EE + (size_t)e * 16384 + h * 128);
        float acc = 0.f;
        #pragma unroll 8
        for (int k4 = 0; k4 < 32; ++k4) {
            float4 a = wp[k4], b = ep[k4];
            acc = fmaf(a.x, b.x, fmaf(a.y, b.y, fmaf(a.z, b.z, fmaf(a.w, b.w, acc))));
        }
        unsigned short hi = f2bf(acc);
        U_h[t] = hi;
        U_l[t] = f2bf(acc - bf2f(hi));
        return;
    }
    int t2 = t - 384 * 512;
    if (t2 < 384 * 128) {
        float v = whh[t2];
        unsigned short hi = f2bf(v);
        whh_h[t2] = hi;
        whh_l[t2] = f2bf(v - bf2f(hi));
    }
}

// ---------------- embed: state[row, h] = node_emb[nf[row]] . W_in[h,:] + b_in[h] -> split planes
__global__ void embed_kernel(const int* __restrict__ nf, const float* __restrict__ emb,
                             const float* __restrict__ Win, const float* __restrict__ bin,
                             ushort_t* __restrict__ s_hi, ushort_t* __restrict__ s_lo) {
    int row = blockIdx.x;
    int h = threadIdx.x;
    __shared__ float e[DIN];
    int a = nf[row];
    if (h < DIN) e[h] = emb[a * DIN + h];
    __syncthreads();
    float acc = bin[h];
    const float* w = Win + h * DIN;
    #pragma unroll
    for (int d = 0; d < DIN; ++d) acc = fmaf(e[d], w[d], acc);
    unsigned short hi = f2bf(acc);
    s_hi[row * HH + h] = hi;
    s_lo[row * HH + h] = f2bf(acc - bf2f(hi));
}

// ---------------- transpose state planes: [16384][128] -> [128][16384]
__global__ __launch_bounds__(256) void transpose_kernel(const ushort_t* __restrict__ src,
                                                        ushort_t* __restrict__ dst,
                                                        size_t splane) {
    __shared__ __align__(16) ushort_t tile[128][72];
    int row0 = blockIdx.x * 64;
    int tid = threadIdx.x;
    #pragma unroll
    for (int pl = 0; pl < 2; ++pl) {
        const ushort_t* s = src + pl * splane;
        ushort_t* d = dst + pl * splane;
        #pragma unroll
        for (int q = 0; q < 4; ++q) {
            int idx = q * 256 + tid;
            int r = idx >> 4, h8 = idx & 15;
            bf16x8 v = *reinterpret_cast<const bf16x8*>(s + (size_t)(row0 + r) * HH + h8 * 8);
            #pragma unroll
            for (int j = 0; j < 8; ++j) tile[h8 * 8 + j][r] = (ushort_t)v[j];
        }
        __syncthreads();
        {
            int h = tid >> 1, rseg = (tid & 1) * 32;
            #pragma unroll
            for (int s8 = 0; s8 < 4; ++s8) {
                us8 v = *reinterpret_cast<const us8*>(&tile[h][rseg + s8 * 8]);
                *reinterpret_cast<us8*>(&d[(size_t)h * 16384 + row0 + rseg + s8 * 8]) = v;
            }
        }
        __syncthreads();
    }
}

// ---------------- split-bf16 MFMA GEMM: C[M x N] = X[M x K] @ W[N x K]^T
// BM=128, BN=64, BK=32, 256 threads = 4 waves (2x2), per-wave 64x32 (4x2 16x16 frags)
// Staging via width-16 global_load_lds into LINEAR LDS (64 B rows) — m97 ladder pattern.
// MODE 3: grid (row, col) -> col-sharers 128 ids apart -> same XCD (X panel L2-shared).
// AGG:    grid (graph, rowcol, e) -> all 32 sharers of a graph's stateT == graph (mod 8).
template <int MODE, bool AGG, bool XBITS, int K, bool XSPLIT, bool WSPLIT>
__global__ __launch_bounds__(256) void mm_kernel(const void* __restrict__ Xp, size_t xplane,
                                                 const ushort_t* __restrict__ W, size_t wplane,
                                                 const float* __restrict__ bias,
                                                 void* __restrict__ outv, size_t oplane,
                                                 int ldx, int ldw, int ldo) {
    __shared__ __align__(16) ushort_t Xs[2][128 * 32];
    __shared__ __align__(16) ushort_t Ws[2][64 * 32];
    int tid = threadIdx.x;
    int row0, col0;
    if constexpr (MODE == 3) {
        row0 = blockIdx.x * 128; col0 = blockIdx.y * 64;
    } else if constexpr (AGG) {
        row0 = (blockIdx.y & 3) * 128; col0 = (blockIdx.y >> 2) * 64;
    } else {
        row0 = blockIdx.y * 128; col0 = blockIdx.x * 64;
    }
    const ushort_t* X = (const ushort_t*)Xp;
    const unsigned* Xb = (const unsigned*)Xp;
    size_t out_off = 0;
    int wko = 0;
    if constexpr (AGG) {
        int bl = blockIdx.x, e = blockIdx.z;
        Xb += (size_t)(bl * E1 + e) * NN * 16;            // A bits for (b_local, e)
        wko = bl * NN;                                    // stateT column offset (n base)
        out_off = (size_t)bl * NN * NN + (size_t)e * HH;  // S2cat[(bl*512+m)*512 + e*128 + h]
    }
    int lane = tid & 63;
    int wave = tid >> 6;
    int wm = wave & 1, wn = wave >> 1;
    int r16 = lane & 15, kg = lane >> 4;
    int lrow = lane >> 2;            // 0..15 within a 16-row DMA chunk
    int lcol = (lane & 3) * 8;       // ushort col within 32-wide row

    f32x4 acc[4][2] = {};

    for (int k0 = 0; k0 < K; k0 += 32) {
        unsigned xword;
        if constexpr (XBITS) {
            int m = tid >> 1;
            xword = Xb[(size_t)(row0 + m) * 16 + (k0 >> 5)];
        }
        __syncthreads();   // all waves done reading previous tile
        if constexpr (!XBITS) {
            #pragma unroll
            for (int q2 = 0; q2 < 2; ++q2) {
                int q = wave * 2 + q2;           // 16-row chunk 0..7
                const ushort_t* g = X + (size_t)(row0 + q * 16 + lrow) * ldx + k0 + lcol;
                gload_lds16(g, &Xs[0][q * 512]);
                if constexpr (XSPLIT) gload_lds16(g + xplane, &Xs[1][q * 512]);
            }
        } else {
            int m = tid >> 1, sel = tid & 1;
            #pragma unroll
            for (int j8 = 0; j8 < 2; ++j8) {
                bf16x8 xv;
                #pragma unroll
                for (int j = 0; j < 8; ++j)
                    xv[j] = (short)(((xword >> (sel * 16 + j8 * 8 + j)) & 1u) ? 0x3F80 : 0);
                *reinterpret_cast<bf16x8*>(&Xs[0][m * 32 + sel * 16 + j8 * 8]) = xv;
            }
        }
        {
            const ushort_t* g = W + (size_t)(col0 + wave * 16 + lrow) * ldw + wko + k0 + lcol;
            gload_lds16(g, &Ws[0][wave * 512]);
            if constexpr (WSPLIT) gload_lds16(g + wplane, &Ws[1][wave * 512]);
        }
        __syncthreads();   // drains vmcnt (DMA) + lgkm (ds_write)
        bf16x8 af_h[4], af_l[4], bf_h[2], bf_l[2];
        #pragma unroll
        for (int mi = 0; mi < 4; ++mi) {
            af_h[mi] = *reinterpret_cast<const bf16x8*>(&Xs[0][(wm * 64 + mi * 16 + r16) * 32 + kg * 8]);
            if constexpr (XSPLIT)
                af_l[mi] = *reinterpret_cast<const bf16x8*>(&Xs[1][(wm * 64 + mi * 16 + r16) * 32 + kg * 8]);
        }
        #pragma unroll
        for (int ni = 0; ni < 2; ++ni) {
            bf_h[ni] = *reinterpret_cast<const bf16x8*>(&Ws[0][(wn * 32 + ni * 16 + r16) * 32 + kg * 8]);
            if constexpr (WSPLIT)
                bf_l[ni] = *reinterpret_cast<const bf16x8*>(&Ws[1][(wn * 32 + ni * 16 + r16) * 32 + kg * 8]);
        }
        #pragma unroll
        for (int mi = 0; mi < 4; ++mi)
            #pragma unroll
            for (int ni = 0; ni < 2; ++ni) {
                acc[mi][ni] = __builtin_amdgcn_mfma_f32_16x16x32_bf16(af_h[mi], bf_h[ni], acc[mi][ni], 0, 0, 0);
                if constexpr (XSPLIT)
                    acc[mi][ni] = __builtin_amdgcn_mfma_f32_16x16x32_bf16(af_l[mi], bf_h[ni], acc[mi][ni], 0, 0, 0);
                if constexpr (WSPLIT)
                    acc[mi][ni] = __builtin_amdgcn_mfma_f32_16x16x32_bf16(af_h[mi], bf_l[ni], acc[mi][ni], 0, 0, 0);
            }
    }

    if constexpr (MODE == 3) {
        float* out = (float*)outv;
        #pragma unroll
        for (int ni = 0; ni < 2; ++ni) {
            int col = col0 + wn * 32 + ni * 16 + r16;
            float bv = bias[col];
            #pragma unroll
            for (int mi = 0; mi < 4; ++mi) {
                int rowb = row0 + wm * 64 + mi * 16 + kg * 4;
                #pragma unroll
                for (int j = 0; j < 4; ++j)
                    out[(size_t)(rowb + j) * ldo + col] = acc[mi][ni][j] + bv;
            }
        }
    } else {
        ushort_t* out = (ushort_t*)outv + out_off;
        #pragma unroll
        for (int ni = 0; ni < 2; ++ni) {
            int col = col0 + wn * 32 + ni * 16 + r16;
            #pragma unroll
            for (int mi = 0; mi < 4; ++mi) {
                int rowb = row0 + wm * 64 + mi * 16 + kg * 4;
                #pragma unroll
                for (int j = 0; j < 4; ++j) {
                    float v = acc[mi][ni][j];
                    unsigned short hv = f2bf(v);
                    out[(size_t)(rowb + j) * ldo + col] = hv;
                    out[oplane + (size_t)(rowb + j) * ldo + col] = f2bf(v - bf2f(hv));
                }
            }
        }
    }
}

// ---------------- GRU gates from fp32 gi/gh; updates split state planes
__global__ void gru_gate_kernel(const float* __restrict__ gi, const float* __restrict__ gh,
                                ushort_t* __restrict__ s_hi, ushort_t* __restrict__ s_lo,
                                size_t half_off, int total) {
    int t = blockIdx.x * blockDim.x + threadIdx.x;
    if (t >= total) return;
    int row = t >> 7, j = t & 127;
    const float* gir = gi + (size_t)row * 384;
    const float* ghr = gh + (size_t)row * 384;
    float ir = gir[j], iz = gir[128 + j], in_ = gir[256 + j];
    float hr = ghr[j], hz = ghr[128 + j], hn = ghr[256 + j];
    float r = 1.f / (1.f + expf(-(ir + hr)));
    float z = 1.f / (1.f + expf(-(iz + hz)));
    float n = tanhf(in_ + r * hn);
    size_t g = half_off + (size_t)t;
    float h = bf2f(s_hi[g]) + bf2f(s_lo[g]);
    float v = (1.f - z) * n + z * h;
    unsigned short hv = f2bf(v);
    s_hi[g] = hv;
    s_lo[g] = f2bf(v - bf2f(hv));
}

// ================= set2vec, phase-split =================

__global__ __launch_bounds__(256) void s2v_g_kernel(int step,
        const float* __restrict__ hvec, const float* __restrict__ rpart,
        const float* __restrict__ wih, const float* __restrict__ whh,
        const float* __restrict__ bih, const float* __restrict__ bhh,
        float* __restrict__ g_all) {
    int b = blockIdx.y, tid = threadIdx.x;
    int j = blockIdx.x * 256 + tid;
    __shared__ float q[256];
    if (step > 0) {
        if (tid < 128) q[tid] = hvec[b * 128 + tid];
        else {
            int h2 = tid - 128;
            const float* rp = rpart + (size_t)b * 512;
            q[tid] = rp[h2] + rp[128 + h2] + rp[256 + h2] + rp[384 + h2];
        }
    } else {
        q[tid] = 0.f;
    }
    __syncthreads();
    float acc = bih[j] + bhh[j];
    if (step > 0) {
        const float4* wi = reinterpret_cast<const float4*>(wih + (size_t)j * 256);
        #pragma unroll 8
        for (int d4 = 0; d4 < 64; ++d4) {
            float4 w = wi[d4];
            acc = fmaf(q[d4 * 4 + 0], w.x, fmaf(q[d4 * 4 + 1], w.y,
                  fmaf(q[d4 * 4 + 2], w.z, fmaf(q[d4 * 4 + 3], w.w, acc))));
        }
        const float4* wp = reinterpret_cast<const float4*>(whh + (size_t)j * 128);
        #pragma unroll 8
        for (int d4 = 0; d4 < 32; ++d4) {
            float4 w = wp[d4];
            acc = fmaf(q[d4 * 4 + 0], w.x, fmaf(q[d4 * 4 + 1], w.y,
                  fmaf(q[d4 * 4 + 2], w.z, fmaf(q[d4 * 4 + 3], w.w, acc))));
        }
    }
    g_all[(size_t)b * 512 + j] = acc;
}

__global__ __launch_bounds__(256) void s2v_cl_kernel(int step,
        const float* __restrict__ g_all, float* __restrict__ cvec, float* __restrict__ hvec,
        const ushort_t* __restrict__ s_hi, const ushort_t* __restrict__ s_lo,
        float* __restrict__ logits) {
    int b = blockIdx.y, chunk = blockIdx.x, tid = threadIdx.x;
    __shared__ float hs[HH];
    if (tid < HH) {
        const float* g = g_all + (size_t)b * 512;
        float i_ = 1.f / (1.f + expf(-g[tid]));
        float f_ = 1.f / (1.f + expf(-g[128 + tid]));
        float g_ = tanhf(g[256 + tid]);
        float o_ = 1.f / (1.f + expf(-g[384 + tid]));
        float c0 = (step == 0) ? 0.f : cvec[b * 128 + tid];
        float c2 = f_ * c0 + i_ * g_;
        float hn = o_ * tanhf(c2);
        hs[tid] = hn;
        if (chunk == 0) { cvec[b * 128 + tid] = c2; hvec[b * 128 + tid] = hn; }
    }
    __syncthreads();
    int n = chunk * 256 + tid;
    const ushort_t* ph = s_hi + ((size_t)b * NN + n) * HH;
    const ushort_t* pl = s_lo + ((size_t)b * NN + n) * HH;
    float lg = 0.f;
    #pragma unroll
    for (int i8 = 0; i8 < 16; ++i8) {
        bf16x8 vh = *reinterpret_cast<const bf16x8*>(ph + i8 * 8);
        bf16x8 vl = *reinterpret_cast<const bf16x8*>(pl + i8 * 8);
        #pragma unroll
        for (int k = 0; k < 8; ++k)
            lg = fmaf(bf2f((ushort_t)vh[k]) + bf2f((ushort_t)vl[k]), hs[i8 * 8 + k], lg);
    }
    logits[(size_t)b * 512 + n] = lg;
}

__global__ __launch_bounds__(256) void s2v_read_kernel(const float* __restrict__ logits,
        const ushort_t* __restrict__ t_hi, const ushort_t* __restrict__ t_lo,
        float* __restrict__ rpart) {
    int b = blockIdx.y, chunk = blockIdx.x, tid = threadIdx.x;
    __shared__ float lgs[NN];
    __shared__ float att[128];
    __shared__ float wred[8];
    __shared__ float red[256];
    lgs[tid] = logits[(size_t)b * 512 + tid];
    lgs[256 + tid] = logits[(size_t)b * 512 + 256 + tid];
    __syncthreads();
    float mv = fmaxf(lgs[tid], lgs[tid + 256]);
    #pragma unroll
    for (int m = 32; m >= 1; m >>= 1) mv = fmaxf(mv, __shfl_xor(mv, m));
    if ((tid & 63) == 0) wred[tid >> 6] = mv;
    __syncthreads();
    float mx = fmaxf(fmaxf(wred[0], wred[1]), fmaxf(wred[2], wred[3]));
    float sv = expf(lgs[tid] - mx) + expf(lgs[tid + 256] - mx);
    #pragma unroll
    for (int m = 32; m >= 1; m >>= 1) sv += __shfl_xor(sv, m);
    if ((tid & 63) == 0) wred[4 + (tid >> 6)] = sv;
    __syncthreads();
    float inv = 1.f / (wred[4] + wred[5] + wred[6] + wred[7]);
    if (tid < 128) att[tid] = expf(lgs[chunk * 128 + tid] - mx) * inv;
    __syncthreads();
    int hh = tid & 127, half = tid >> 7;
    int colb = b * NN + chunk * 128 + half * 64;
    const ushort_t* ph = t_hi + (size_t)hh * 16384 + colb;
    const ushort_t* pl = t_lo + (size_t)hh * 16384 + colb;
    float racc = 0.f;
    #pragma unroll
    for (int i8 = 0; i8 < 8; ++i8) {
        bf16x8 vh = *reinterpret_cast<const bf16x8*>(ph + i8 * 8);
        bf16x8 vl = *reinterpret_cast<const bf16x8*>(pl + i8 * 8);
        #pragma unroll
        for (int k = 0; k < 8; ++k)
            racc = fmaf(att[half * 64 + i8 * 8 + k],
                        bf2f((ushort_t)vh[k]) + bf2f((ushort_t)vl[k]), racc);
    }
    red[tid] = racc;
    __syncthreads();
    if (tid < 128)
        rpart[(size_t)b * 512 + chunk * 128 + tid] = red[tid] + red[128 + tid];
}

__global__ __launch_bounds__(256) void s2v_out_kernel(const float* __restrict__ hvec,
        const float* __restrict__ rpart, const float* __restrict__ Wout,
        const float* __restrict__ bout, float* __restrict__ out) {
    int b = blockIdx.x, tid = threadIdx.x;
    __shared__ float q[256];
    if (tid < 128) q[tid] = hvec[b * 128 + tid];
    else {
        int h2 = tid - 128;
        const float* rp = rpart + (size_t)b * 512;
        q[tid] = rp[h2] + rp[128 + h2] + rp[256 + h2] + rp[384 + h2];
    }
    __syncthreads();
    if (tid < DOUT) {
        float acc = bout[tid];
        const float4* w = reinterpret_cast<const float4*>(Wout + (size_t)tid * 256);
        #pragma unroll 8
        for (int d4 = 0; d4 < 64; ++d4) {
            float4 wv = w[d4];
            acc = fmaf(q[d4 * 4 + 0], wv.x, fmaf(q[d4 * 4 + 1], wv.y,
                  fmaf(q[d4 * 4 + 2], wv.z, fmaf(q[d4 * 4 + 3], wv.w, acc))));
        }
        out[b * DOUT + tid] = acc;
    }
}

extern "C" void kernel_launch(void* const* d_in, const int* in_sizes, int n_in,
                              void* d_out, int out_size, void* d_ws, size_t ws_size,
                              hipStream_t stream) {
    const int*   node_feat = (const int*)d_in[0];
    const float* L         = (const float*)d_in[1];
    const float* node_emb  = (const float*)d_in[2];
    const float* W_in      = (const float*)d_in[3];
    const float* b_in      = (const float*)d_in[4];
    const float* edge_emb  = (const float*)d_in[5];
    const float* gru_wih   = (const float*)d_in[6];
    const float* gru_whh   = (const float*)d_in[7];
    const float* gru_bih   = (const float*)d_in[8];
    const float* gru_bhh   = (const float*)d_in[9];
    const float* lstm_wih  = (const float*)d_in[10];
    const float* lstm_whh  = (const float*)d_in[11];
    const float* lstm_bih  = (const float*)d_in[12];
    const float* lstm_bhh  = (const float*)d_in[13];
    const float* W_out     = (const float*)d_in[14];
    const float* b_out     = (const float*)d_in[15];
    float* out = (float*)d_out;

    char* ws = (char*)d_ws;
    const bool full = ws_size >= ((size_t)110 << 20);

    // common: state hi/lo [0..8), stateT hi/lo [8..16), Abits [16..20)
    // full : S2 [20..52) plane 8388608 | gi [52..76) | gh [76..100) | W [100..101) | s2v [101..]
    // half : S2 [20..36) plane 4194304 | gi [36..48) | gh [48..60) | W [60..61)  | s2v [61..]
    ushort_t* state_hi  = (ushort_t*)ws;
    ushort_t* stateT_hi = (ushort_t*)(ws + (8u << 20));
    unsigned* Abits     = (unsigned*)(ws + (16u << 20));
    ushort_t* S2        = (ushort_t*)(ws + (20u << 20));
    size_t s2plane      = full ? 8388608u : 4194304u;
    float*    gi        = (float*)(ws + (full ? (52ull << 20) : (36ull << 20)));
    float*    gh        = (float*)(ws + (full ? (76ull << 20) : (48ull << 20)));
    ushort_t* U_h       = (ushort_t*)(ws + (full ? (100ull << 20) : (60ull << 20)));
    ushort_t* U_l       = U_h + 196608;
    ushort_t* whh_h     = U_l + 196608;
    ushort_t* whh_l     = whh_h + 49152;
    float*    s2v       = (float*)(ws + (full ? (101ull << 20) : (61ull << 20)));
    float*    g_all     = s2v;            // 16384
    float*    logits    = s2v + 16384;    // 16384
    float*    hvec      = s2v + 32768;    // 4096
    float*    cvec      = s2v + 36864;    // 4096
    float*    rpart     = s2v + 40960;    // 16384

    const size_t SPLANE = 2097152;    // state/stateT plane stride (elems)

    pack_A_kernel<<<(BB * NN * NN) / 256, 256, 0, stream>>>(L, Abits);
    convW_kernel<<<(384 * 512 + 384 * 128) / 256, 256, 0, stream>>>(
        edge_emb, gru_wih, gru_whh, U_h, U_l, whh_h, whh_l);
    embed_kernel<<<BB * NN, 128, 0, stream>>>(node_feat, node_emb, W_in, b_in,
                                              state_hi, state_hi + SPLANE);

    const int nh     = full ? 1 : 2;
    const int graphs = full ? 32 : 16;   // graphs per dispatch
    const int ydim   = full ? 128 : 64;  // M / 128
    const int rows   = full ? 16384 : MHALF;

    for (int p = 0; p < NPROP; ++p) {
        transpose_kernel<<<256, 256, 0, stream>>>(state_hi, stateT_hi, SPLANE);
        for (int half = 0; half < nh; ++half) {
            const unsigned* Ab = Abits + (size_t)half * 16 * E1 * NN * 16;
            // S2: grid (graph, rowcol, e) -> per-graph stateT panel pinned to one XCD
            mm_kernel<4, true, true, 512, false, true><<<dim3(graphs, 8, 4), 256, 0, stream>>>(
                Ab, 0, stateT_hi + (size_t)half * MHALF, SPLANE, nullptr,
                S2, s2plane, 0, 16384, 512);
            // gi = S2 @ U^T + bih : N=384, K=512 -> fp32   (grid = (rows, cols) for XCD locality)
            mm_kernel<3, false, false, 512, true, true><<<dim3(ydim, 6), 256, 0, stream>>>(
                S2, s2plane, U_h, 196608, gru_bih, gi, 0, 512, 512, 384);
            // gh = state @ whh^T + bhh : N=384, K=128 -> fp32
            mm_kernel<3, false, false, 128, true, true><<<dim3(ydim, 6), 256, 0, stream>>>(
                state_hi + (size_t)half * MHALF * HH, SPLANE, whh_h, 49152, gru_bhh,
                gh, 0, 128, 128, 384);
            // gates -> state planes
            gru_gate_kernel<<<(rows * HH) / 256, 256, 0, stream>>>(
                gi, gh, state_hi, state_hi + SPLANE,
                (size_t)half * MHALF * HH, rows * HH);
        }
    }
    // fresh stateT for the s2v read phase
    transpose_kernel<<<256, 256, 0, stream>>>(state_hi, stateT_hi, SPLANE);

    for (int step = 0; step < NS2V; ++step) {
        s2v_g_kernel<<<dim3(2, BB), 256, 0, stream>>>(step, hvec, rpart,
                                                      lstm_wih, lstm_whh, lstm_bih, lstm_bhh,
                                                      g_all);
        s2v_cl_kernel<<<dim3(2, BB), 256, 0, stream>>>(step, g_all, cvec, hvec,
                                                       state_hi, state_hi + SPLANE, logits);
        s2v_read_kernel<<<dim3(4, BB), 256, 0, stream>>>(logits, stateT_hi,
                                                         stateT_hi + SPLANE, rpart);
    }
    s2v_out_kernel<<<BB, 256, 0, stream>>>(hvec, rpart, W_out, b_out, out);
}

// Round 14
// 572.232 us; speedup vs baseline: 1.2650x; 1.0155x over previous
//
#include <hip/hip_runtime.h>
#include <hip/hip_bf16.h>

#define BB 32
#define NN 512
#define DA 100
#define DIN 64
#define HH 128
#define E1 4
#define DOUT 16
#define NPROP 5
#define NS2V 3
#define MHALF 8192          // rows per half-batch (16 graphs)

typedef __attribute__((ext_vector_type(8))) short bf16x8;
typedef __attribute__((ext_vector_type(4))) float f32x4;
typedef __attribute__((ext_vector_type(4))) unsigned short us4;
typedef __attribute__((ext_vector_type(8))) unsigned short us8;
typedef unsigned short ushort_t;

__device__ __forceinline__ unsigned short f2bf(float f) {
    __hip_bfloat16 h = __float2bfloat16(f);
    return *reinterpret_cast<unsigned short*>(&h);
}
__device__ __forceinline__ float bf2f(unsigned short u) {
    unsigned v = ((unsigned)u) << 16;
    float f;
    __builtin_memcpy(&f, &v, 4);
    return f;
}

// async global->LDS DMA, 16 B per lane: LDS dest = uniform base + lane*16,
// global src = per-lane address. (m97 ladder pattern.)
__device__ __forceinline__ void gload_lds16(const void* g, void* l) {
    __builtin_amdgcn_global_load_lds(
        (const __attribute__((address_space(1))) void*)g,
        (__attribute__((address_space(3))) void*)l, 16, 0, 0);
}

// ---------------- pack A bits (coalesced + ballot)
__global__ __launch_bounds__(256) void pack_A_kernel(const float* __restrict__ L,
                                                     unsigned* __restrict__ Abits) {
    int t = blockIdx.x * 256 + threadIdx.x;    // (b, m, n)
    int n = t & (NN - 1);
    int m = (t >> 9) & (NN - 1);
    int b = t >> 18;
    float4 v = *reinterpret_cast<const float4*>(L + ((size_t)(b * NN + m) * NN + n) * E1);
    unsigned long long mk[E1];
    mk[0] = __ballot(v.x != 0.f);
    mk[1] = __ballot(v.y != 0.f);
    mk[2] = __ballot(v.z != 0.f);
    mk[3] = __ballot(v.w != 0.f);
    int lane = threadIdx.x & 63;
    if (lane < 8) {
        int e = lane >> 1, half = lane & 1;
        unsigned word = half ? (unsigned)(mk[e] >> 32) : (unsigned)mk[e];
        int wbase = (n >> 5) & ~1;             // word index of wave's first n
        Abits[((size_t)(b * E1 + e) * NN + m) * 16 + wbase + half] = word;
    }
}

// ---------------- fused-weight precompute:
// U[j, e*128+h] = sum_k wih[j, e*128+k] * edge_emb[e, h*128+k]   (fp32, then split bf16)
__global__ void convW_kernel(const float* __restrict__ EE, const float* __restrict__ wih,
                             const float* __restrict__ whh,
                             ushort_t* __restrict__ U_h, ushort_t* __restrict__ U_l,
                             ushort_t* __restrict__ whh_h, ushort_t* __restrict__ whh_l) {
    int t = blockIdx.x * blockDim.x + threadIdx.x;
    if (t < 384 * 512) {
        int col = t & 511;
        int j = t >> 9;
        int e = col >> 7, h = col & 127;
        const float4* wp = reinterpret_cast<const float4*>(wih + (size_t)j * 512 + e * 128);
        const float4* ep = reinterpret_cast<const float4*>(EE + (size_t)e * 16384 + h * 128);
        float acc = 0.f;
        #pragma unroll 8
        for (int k4 = 0; k4 < 32; ++k4) {
            float4 a = wp[k4], b = ep[k4];
            acc = fmaf(a.x, b.x, fmaf(a.y, b.y, fmaf(a.z, b.z, fmaf(a.w, b.w, acc))));
        }
        unsigned short hi = f2bf(acc);
        U_h[t] = hi;
        U_l[t] = f2bf(acc - bf2f(hi));
        return;
    }
    int t2 = t - 384 * 512;
    if (t2 < 384 * 128) {
        float v = whh[t2];
        unsigned short hi = f2bf(v);
        whh_h[t2] = hi;
        whh_l[t2] = f2bf(v - bf2f(hi));
    }
}

// ---------------- embed: state[row, h] = node_emb[nf[row]] . W_in[h,:] + b_in[h] -> split planes
__global__ void embed_kernel(const int* __restrict__ nf, const float* __restrict__ emb,
                             const float* __restrict__ Win, const float* __restrict__ bin,
                             ushort_t* __restrict__ s_hi, ushort_t* __restrict__ s_lo) {
    int row = blockIdx.x;
    int h = threadIdx.x;
    __shared__ float e[DIN];
    int a = nf[row];
    if (h < DIN) e[h] = emb[a * DIN + h];
    __syncthreads();
    float acc = bin[h];
    const float* w = Win + h * DIN;
    #pragma unroll
    for (int d = 0; d < DIN; ++d) acc = fmaf(e[d], w[d], acc);
    unsigned short hi = f2bf(acc);
    s_hi[row * HH + h] = hi;
    s_lo[row * HH + h] = f2bf(acc - bf2f(hi));
}

// ---------------- transpose state planes: [16384][128] -> [128][16384]
__global__ __launch_bounds__(256) void transpose_kernel(const ushort_t* __restrict__ src,
                                                        ushort_t* __restrict__ dst,
                                                        size_t splane) {
    __shared__ __align__(16) ushort_t tile[128][72];
    int row0 = blockIdx.x * 64;
    int tid = threadIdx.x;
    #pragma unroll
    for (int pl = 0; pl < 2; ++pl) {
        const ushort_t* s = src + pl * splane;
        ushort_t* d = dst + pl * splane;
        #pragma unroll
        for (int q = 0; q < 4; ++q) {
            int idx = q * 256 + tid;
            int r = idx >> 4, h8 = idx & 15;
            bf16x8 v = *reinterpret_cast<const bf16x8*>(s + (size_t)(row0 + r) * HH + h8 * 8);
            #pragma unroll
            for (int j = 0; j < 8; ++j) tile[h8 * 8 + j][r] = (ushort_t)v[j];
        }
        __syncthreads();
        {
            int h = tid >> 1, rseg = (tid & 1) * 32;
            #pragma unroll
            for (int s8 = 0; s8 < 4; ++s8) {
                us8 v = *reinterpret_cast<const us8*>(&tile[h][rseg + s8 * 8]);
                *reinterpret_cast<us8*>(&d[(size_t)h * 16384 + row0 + rseg + s8 * 8]) = v;
            }
        }
        __syncthreads();
    }
}

// ---------------- split-bf16 MFMA GEMM: C[M x N] = X[M x K] @ W[N x K]^T
// BM=128, BN=64, BK=64, 256 threads = 4 waves (2x2), per-wave 64x32 (4x2 16x16 frags).
// Staging: width-16 global_load_lds, linear LDS dest, PRE-SWIZZLED global source slot
// ((lane&7)^lrow) + same XOR on the read side -> conflict-free 128 B rows (m173/m201).
// Halved barrier count vs BK=32; MFMA accumulation order identical (bit-exact).
// MODE 3: grid (row, col) -> col-sharers 128 ids apart -> same XCD.
// AGG:    grid (graph, rowcol, e) -> graph's stateT panel pinned to one XCD.
template <int MODE, bool AGG, bool XBITS, int K, bool XSPLIT, bool WSPLIT>
__global__ __launch_bounds__(256) void mm_kernel(const void* __restrict__ Xp, size_t xplane,
                                                 const ushort_t* __restrict__ W, size_t wplane,
                                                 const float* __restrict__ bias,
                                                 void* __restrict__ outv, size_t oplane,
                                                 int ldx, int ldw, int ldo) {
    constexpr int XP = XSPLIT ? 2 : 1;
    constexpr int WP = WSPLIT ? 2 : 1;
    __shared__ __align__(16) ushort_t Xs[XP][128 * 64];
    __shared__ __align__(16) ushort_t Ws[WP][64 * 64];
    int tid = threadIdx.x;
    int row0, col0;
    if constexpr (MODE == 3) {
        row0 = blockIdx.x * 128; col0 = blockIdx.y * 64;
    } else if constexpr (AGG) {
        row0 = (blockIdx.y & 3) * 128; col0 = (blockIdx.y >> 2) * 64;
    } else {
        row0 = blockIdx.y * 128; col0 = blockIdx.x * 64;
    }
    const ushort_t* X = (const ushort_t*)Xp;
    const unsigned* Xb = (const unsigned*)Xp;
    size_t out_off = 0;
    int wko = 0;
    if constexpr (AGG) {
        int bl = blockIdx.x, e = blockIdx.z;
        Xb += (size_t)(bl * E1 + e) * NN * 16;            // A bits for (b_local, e)
        wko = bl * NN;                                    // stateT column offset (n base)
        out_off = (size_t)bl * NN * NN + (size_t)e * HH;  // S2cat[(bl*512+m)*512 + e*128 + h]
    }
    int lane = tid & 63;
    int wave = tid >> 6;
    int wm = wave & 1, wn = wave >> 1;
    int r16 = lane & 15, kg = lane >> 4;
    int lrow = lane >> 3;            // 0..7 within an 8-row DMA chunk
    int lslot = lane & 7;            // 16B slot within 128 B row

    f32x4 acc[4][2] = {};

    for (int k0 = 0; k0 < K; k0 += 64) {
        unsigned xw0;
        if constexpr (XBITS) {
            int m = tid >> 1, sel = tid & 1;
            xw0 = Xb[(size_t)(row0 + m) * 16 + (k0 >> 5) + sel];
        }
        __syncthreads();   // all waves done reading previous tile
        if constexpr (!XBITS) {
            #pragma unroll
            for (int q2 = 0; q2 < 4; ++q2) {
                int q = wave * 4 + q2;           // 8-row chunk 0..15
                const ushort_t* g = X + (size_t)(row0 + q * 8 + lrow) * ldx + k0
                                      + ((lslot ^ lrow) * 8);
                gload_lds16(g, &Xs[0][q * 512]);
                if constexpr (XSPLIT) gload_lds16(g + xplane, &Xs[1][q * 512]);
            }
        } else {
            int m = tid >> 1, sel = tid & 1;
            #pragma unroll
            for (int j8 = 0; j8 < 4; ++j8) {
                bf16x8 xv;
                #pragma unroll
                for (int j = 0; j < 8; ++j)
                    xv[j] = (short)(((xw0 >> (j8 * 8 + j)) & 1u) ? 0x3F80 : 0);
                *reinterpret_cast<bf16x8*>(
                    &Xs[0][m * 64 + (((sel << 2) + j8) ^ (m & 7)) * 8]) = xv;
            }
        }
        {
            #pragma unroll
            for (int q2 = 0; q2 < 2; ++q2) {
                int q = wave * 2 + q2;           // 8-row chunk 0..7
                const ushort_t* g = W + (size_t)(col0 + q * 8 + lrow) * ldw + wko + k0
                                      + ((lslot ^ lrow) * 8);
                gload_lds16(g, &Ws[0][q * 512]);
                if constexpr (WSPLIT) gload_lds16(g + wplane, &Ws[1][q * 512]);
            }
        }
        __syncthreads();   // drains vmcnt (DMA) + lgkm (ds_write)
        #pragma unroll
        for (int kk = 0; kk < 2; ++kk) {
            int sbase = kg + kk * 4;             // logical 16B slot of this k-sub-step
            bf16x8 af_h[4], af_l[4], bf_h[2], bf_l[2];
            #pragma unroll
            for (int mi = 0; mi < 4; ++mi) {
                int r = wm * 64 + mi * 16 + r16;
                int off = r * 64 + (sbase ^ (r & 7)) * 8;
                af_h[mi] = *reinterpret_cast<const bf16x8*>(&Xs[0][off]);
                if constexpr (XSPLIT)
                    af_l[mi] = *reinterpret_cast<const bf16x8*>(&Xs[XP - 1][off]);
            }
            #pragma unroll
            for (int ni = 0; ni < 2; ++ni) {
                int r = wn * 32 + ni * 16 + r16;
                int off = r * 64 + (sbase ^ (r & 7)) * 8;
                bf_h[ni] = *reinterpret_cast<const bf16x8*>(&Ws[0][off]);
                if constexpr (WSPLIT)
                    bf_l[ni] = *reinterpret_cast<const bf16x8*>(&Ws[WP - 1][off]);
            }
            #pragma unroll
            for (int mi = 0; mi < 4; ++mi)
                #pragma unroll
                for (int ni = 0; ni < 2; ++ni) {
                    acc[mi][ni] = __builtin_amdgcn_mfma_f32_16x16x32_bf16(af_h[mi], bf_h[ni], acc[mi][ni], 0, 0, 0);
                    if constexpr (XSPLIT)
                        acc[mi][ni] = __builtin_amdgcn_mfma_f32_16x16x32_bf16(af_l[mi], bf_h[ni], acc[mi][ni], 0, 0, 0);
                    if constexpr (WSPLIT)
                        acc[mi][ni] = __builtin_amdgcn_mfma_f32_16x16x32_bf16(af_h[mi], bf_l[ni], acc[mi][ni], 0, 0, 0);
                }
        }
    }

    if constexpr (MODE == 3) {
        float* out = (float*)outv;
        #pragma unroll
        for (int ni = 0; ni < 2; ++ni) {
            int col = col0 + wn * 32 + ni * 16 + r16;
            float bv = bias[col];
            #pragma unroll
            for (int mi = 0; mi < 4; ++mi) {
                int rowb = row0 + wm * 64 + mi * 16 + kg * 4;
                #pragma unroll
                for (int j = 0; j < 4; ++j)
                    out[(size_t)(rowb + j) * ldo + col] = acc[mi][ni][j] + bv;
            }
        }
    } else {
        ushort_t* out = (ushort_t*)outv + out_off;
        #pragma unroll
        for (int ni = 0; ni < 2; ++ni) {
            int col = col0 + wn * 32 + ni * 16 + r16;
            #pragma unroll
            for (int mi = 0; mi < 4; ++mi) {
                int rowb = row0 + wm * 64 + mi * 16 + kg * 4;
                #pragma unroll
                for (int j = 0; j < 4; ++j) {
                    float v = acc[mi][ni][j];
                    unsigned short hv = f2bf(v);
                    out[(size_t)(rowb + j) * ldo + col] = hv;
                    out[oplane + (size_t)(rowb + j) * ldo + col] = f2bf(v - bf2f(hv));
                }
            }
        }
    }
}

// ---------------- GRU gates from fp32 gi/gh; updates split state planes
__global__ void gru_gate_kernel(const float* __restrict__ gi, const float* __restrict__ gh,
                                ushort_t* __restrict__ s_hi, ushort_t* __restrict__ s_lo,
                                size_t half_off, int total) {
    int t = blockIdx.x * blockDim.x + threadIdx.x;
    if (t >= total) return;
    int row = t >> 7, j = t & 127;
    const float* gir = gi + (size_t)row * 384;
    const float* ghr = gh + (size_t)row * 384;
    float ir = gir[j], iz = gir[128 + j], in_ = gir[256 + j];
    float hr = ghr[j], hz = ghr[128 + j], hn = ghr[256 + j];
    float r = 1.f / (1.f + expf(-(ir + hr)));
    float z = 1.f / (1.f + expf(-(iz + hz)));
    float n = tanhf(in_ + r * hn);
    size_t g = half_off + (size_t)t;
    float h = bf2f(s_hi[g]) + bf2f(s_lo[g]);
    float v = (1.f - z) * n + z * h;
    unsigned short hv = f2bf(v);
    s_hi[g] = hv;
    s_lo[g] = f2bf(v - bf2f(hv));
}

// ================= set2vec, phase-split =================

__global__ __launch_bounds__(256) void s2v_g_kernel(int step,
        const float* __restrict__ hvec, const float* __restrict__ rpart,
        const float* __restrict__ wih, const float* __restrict__ whh,
        const float* __restrict__ bih, const float* __restrict__ bhh,
        float* __restrict__ g_all) {
    int b = blockIdx.y, tid = threadIdx.x;
    int j = blockIdx.x * 256 + tid;
    __shared__ float q[256];
    if (step > 0) {
        if (tid < 128) q[tid] = hvec[b * 128 + tid];
        else {
            int h2 = tid - 128;
            const float* rp = rpart + (size_t)b * 512;
            q[tid] = rp[h2] + rp[128 + h2] + rp[256 + h2] + rp[384 + h2];
        }
    } else {
        q[tid] = 0.f;
    }
    __syncthreads();
    float acc = bih[j] + bhh[j];
    if (step > 0) {
        const float4* wi = reinterpret_cast<const float4*>(wih + (size_t)j * 256);
        #pragma unroll 8
        for (int d4 = 0; d4 < 64; ++d4) {
            float4 w = wi[d4];
            acc = fmaf(q[d4 * 4 + 0], w.x, fmaf(q[d4 * 4 + 1], w.y,
                  fmaf(q[d4 * 4 + 2], w.z, fmaf(q[d4 * 4 + 3], w.w, acc))));
        }
        const float4* wp = reinterpret_cast<const float4*>(whh + (size_t)j * 128);
        #pragma unroll 8
        for (int d4 = 0; d4 < 32; ++d4) {
            float4 w = wp[d4];
            acc = fmaf(q[d4 * 4 + 0], w.x, fmaf(q[d4 * 4 + 1], w.y,
                  fmaf(q[d4 * 4 + 2], w.z, fmaf(q[d4 * 4 + 3], w.w, acc))));
        }
    }
    g_all[(size_t)b * 512 + j] = acc;
}

__global__ __launch_bounds__(256) void s2v_cl_kernel(int step,
        const float* __restrict__ g_all, float* __restrict__ cvec, float* __restrict__ hvec,
        const ushort_t* __restrict__ s_hi, const ushort_t* __restrict__ s_lo,
        float* __restrict__ logits) {
    int b = blockIdx.y, chunk = blockIdx.x, tid = threadIdx.x;
    __shared__ float hs[HH];
    if (tid < HH) {
        const float* g = g_all + (size_t)b * 512;
        float i_ = 1.f / (1.f + expf(-g[tid]));
        float f_ = 1.f / (1.f + expf(-g[128 + tid]));
        float g_ = tanhf(g[256 + tid]);
        float o_ = 1.f / (1.f + expf(-g[384 + tid]));
        float c0 = (step == 0) ? 0.f : cvec[b * 128 + tid];
        float c2 = f_ * c0 + i_ * g_;
        float hn = o_ * tanhf(c2);
        hs[tid] = hn;
        if (chunk == 0) { cvec[b * 128 + tid] = c2; hvec[b * 128 + tid] = hn; }
    }
    __syncthreads();
    int n = chunk * 256 + tid;
    const ushort_t* ph = s_hi + ((size_t)b * NN + n) * HH;
    const ushort_t* pl = s_lo + ((size_t)b * NN + n) * HH;
    float lg = 0.f;
    #pragma unroll
    for (int i8 = 0; i8 < 16; ++i8) {
        bf16x8 vh = *reinterpret_cast<const bf16x8*>(ph + i8 * 8);
        bf16x8 vl = *reinterpret_cast<const bf16x8*>(pl + i8 * 8);
        #pragma unroll
        for (int k = 0; k < 8; ++k)
            lg = fmaf(bf2f((ushort_t)vh[k]) + bf2f((ushort_t)vl[k]), hs[i8 * 8 + k], lg);
    }
    logits[(size_t)b * 512 + n] = lg;
}

__global__ __launch_bounds__(256) void s2v_read_kernel(const float* __restrict__ logits,
        const ushort_t* __restrict__ t_hi, const ushort_t* __restrict__ t_lo,
        float* __restrict__ rpart) {
    int b = blockIdx.y, chunk = blockIdx.x, tid = threadIdx.x;
    __shared__ float lgs[NN];
    __shared__ float att[128];
    __shared__ float wred[8];
    __shared__ float red[256];
    lgs[tid] = logits[(size_t)b * 512 + tid];
    lgs[256 + tid] = logits[(size_t)b * 512 + 256 + tid];
    __syncthreads();
    float mv = fmaxf(lgs[tid], lgs[tid + 256]);
    #pragma unroll
    for (int m = 32; m >= 1; m >>= 1) mv = fmaxf(mv, __shfl_xor(mv, m));
    if ((tid & 63) == 0) wred[tid >> 6] = mv;
    __syncthreads();
    float mx = fmaxf(fmaxf(wred[0], wred[1]), fmaxf(wred[2], wred[3]));
    float sv = expf(lgs[tid] - mx) + expf(lgs[tid + 256] - mx);
    #pragma unroll
    for (int m = 32; m >= 1; m >>= 1) sv += __shfl_xor(sv, m);
    if ((tid & 63) == 0) wred[4 + (tid >> 6)] = sv;
    __syncthreads();
    float inv = 1.f / (wred[4] + wred[5] + wred[6] + wred[7]);
    if (tid < 128) att[tid] = expf(lgs[chunk * 128 + tid] - mx) * inv;
    __syncthreads();
    int hh = tid & 127, half = tid >> 7;
    int colb = b * NN + chunk * 128 + half * 64;
    const ushort_t* ph = t_hi + (size_t)hh * 16384 + colb;
    const ushort_t* pl = t_lo + (size_t)hh * 16384 + colb;
    float racc = 0.f;
    #pragma unroll
    for (int i8 = 0; i8 < 8; ++i8) {
        bf16x8 vh = *reinterpret_cast<const bf16x8*>(ph + i8 * 8);
        bf16x8 vl = *reinterpret_cast<const bf16x8*>(pl + i8 * 8);
        #pragma unroll
        for (int k = 0; k < 8; ++k)
            racc = fmaf(att[half * 64 + i8 * 8 + k],
                        bf2f((ushort_t)vh[k]) + bf2f((ushort_t)vl[k]), racc);
    }
    red[tid] = racc;
    __syncthreads();
    if (tid < 128)
        rpart[(size_t)b * 512 + chunk * 128 + tid] = red[tid] + red[128 + tid];
}

__global__ __launch_bounds__(256) void s2v_out_kernel(const float* __restrict__ hvec,
        const float* __restrict__ rpart, const float* __restrict__ Wout,
        const float* __restrict__ bout, float* __restrict__ out) {
    int b = blockIdx.x, tid = threadIdx.x;
    __shared__ float q[256];
    if (tid < 128) q[tid] = hvec[b * 128 + tid];
    else {
        int h2 = tid - 128;
        const float* rp = rpart + (size_t)b * 512;
        q[tid] = rp[h2] + rp[128 + h2] + rp[256 + h2] + rp[384 + h2];
    }
    __syncthreads();
    if (tid < DOUT) {
        float acc = bout[tid];
        const float4* w = reinterpret_cast<const float4*>(Wout + (size_t)tid * 256);
        #pragma unroll 8
        for (int d4 = 0; d4 < 64; ++d4) {
            float4 wv = w[d4];
            acc = fmaf(q[d4 * 4 + 0], wv.x, fmaf(q[d4 * 4 + 1], wv.y,
                  fmaf(q[d4 * 4 + 2], wv.z, fmaf(q[d4 * 4 + 3], wv.w, acc))));
        }
        out[b * DOUT + tid] = acc;
    }
}

extern "C" void kernel_launch(void* const* d_in, const int* in_sizes, int n_in,
                              void* d_out, int out_size, void* d_ws, size_t ws_size,
                              hipStream_t stream) {
    const int*   node_feat = (const int*)d_in[0];
    const float* L         = (const float*)d_in[1];
    const float* node_emb  = (const float*)d_in[2];
    const float* W_in      = (const float*)d_in[3];
    const float* b_in      = (const float*)d_in[4];
    const float* edge_emb  = (const float*)d_in[5];
    const float* gru_wih   = (const float*)d_in[6];
    const float* gru_whh   = (const float*)d_in[7];
    const float* gru_bih   = (const float*)d_in[8];
    const float* gru_bhh   = (const float*)d_in[9];
    const float* lstm_wih  = (const float*)d_in[10];
    const float* lstm_whh  = (const float*)d_in[11];
    const float* lstm_bih  = (const float*)d_in[12];
    const float* lstm_bhh  = (const float*)d_in[13];
    const float* W_out     = (const float*)d_in[14];
    const float* b_out     = (const float*)d_in[15];
    float* out = (float*)d_out;

    char* ws = (char*)d_ws;
    const bool full = ws_size >= ((size_t)110 << 20);

    // common: state hi/lo [0..8), stateT hi/lo [8..16), Abits [16..20)
    // full : S2 [20..52) plane 8388608 | gi [52..76) | gh [76..100) | W [100..101) | s2v [101..]
    // half : S2 [20..36) plane 4194304 | gi [36..48) | gh [48..60) | W [60..61)  | s2v [61..]
    ushort_t* state_hi  = (ushort_t*)ws;
    ushort_t* stateT_hi = (ushort_t*)(ws + (8u << 20));
    unsigned* Abits     = (unsigned*)(ws + (16u << 20));
    ushort_t* S2        = (ushort_t*)(ws + (20u << 20));
    size_t s2plane      = full ? 8388608u : 4194304u;
    float*    gi        = (float*)(ws + (full ? (52ull << 20) : (36ull << 20)));
    float*    gh        = (float*)(ws + (full ? (76ull << 20) : (48ull << 20)));
    ushort_t* U_h       = (ushort_t*)(ws + (full ? (100ull << 20) : (60ull << 20)));
    ushort_t* U_l       = U_h + 196608;
    ushort_t* whh_h     = U_l + 196608;
    ushort_t* whh_l     = whh_h + 49152;
    float*    s2v       = (float*)(ws + (full ? (101ull << 20) : (61ull << 20)));
    float*    g_all     = s2v;            // 16384
    float*    logits    = s2v + 16384;    // 16384
    float*    hvec      = s2v + 32768;    // 4096
    float*    cvec      = s2v + 36864;    // 4096
    float*    rpart     = s2v + 40960;    // 16384

    const size_t SPLANE = 2097152;    // state/stateT plane stride (elems)

    pack_A_kernel<<<(BB * NN * NN) / 256, 256, 0, stream>>>(L, Abits);
    convW_kernel<<<(384 * 512 + 384 * 128) / 256, 256, 0, stream>>>(
        edge_emb, gru_wih, gru_whh, U_h, U_l, whh_h, whh_l);
    embed_kernel<<<BB * NN, 128, 0, stream>>>(node_feat, node_emb, W_in, b_in,
                                              state_hi, state_hi + SPLANE);

    const int nh     = full ? 1 : 2;
    const int graphs = full ? 32 : 16;   // graphs per dispatch
    const int ydim   = full ? 128 : 64;  // M / 128
    const int rows   = full ? 16384 : MHALF;

    for (int p = 0; p < NPROP; ++p) {
        transpose_kernel<<<256, 256, 0, stream>>>(state_hi, stateT_hi, SPLANE);
        for (int half = 0; half < nh; ++half) {
            const unsigned* Ab = Abits + (size_t)half * 16 * E1 * NN * 16;
            // S2: grid (graph, rowcol, e) -> per-graph stateT panel pinned to one XCD
            mm_kernel<4, true, true, 512, false, true><<<dim3(graphs, 8, 4), 256, 0, stream>>>(
                Ab, 0, stateT_hi + (size_t)half * MHALF, SPLANE, nullptr,
                S2, s2plane, 0, 16384, 512);
            // gi = S2 @ U^T + bih : N=384, K=512 -> fp32   (grid = (rows, cols) for XCD locality)
            mm_kernel<3, false, false, 512, true, true><<<dim3(ydim, 6), 256, 0, stream>>>(
                S2, s2plane, U_h, 196608, gru_bih, gi, 0, 512, 512, 384);
            // gh = state @ whh^T + bhh : N=384, K=128 -> fp32
            mm_kernel<3, false, false, 128, true, true><<<dim3(ydim, 6), 256, 0, stream>>>(
                state_hi + (size_t)half * MHALF * HH, SPLANE, whh_h, 49152, gru_bhh,
                gh, 0, 128, 128, 384);
            // gates -> state planes
            gru_gate_kernel<<<(rows * HH) / 256, 256, 0, stream>>>(
                gi, gh, state_hi, state_hi + SPLANE,
                (size_t)half * MHALF * HH, rows * HH);
        }
    }
    // fresh stateT for the s2v read phase
    transpose_kernel<<<256, 256, 0, stream>>>(state_hi, stateT_hi, SPLANE);

    for (int step = 0; step < NS2V; ++step) {
        s2v_g_kernel<<<dim3(2, BB), 256, 0, stream>>>(step, hvec, rpart,
                                                      lstm_wih, lstm_whh, lstm_bih, lstm_bhh,
                                                      g_all);
        s2v_cl_kernel<<<dim3(2, BB), 256, 0, stream>>>(step, g_all, cvec, hvec,
                                                       state_hi, state_hi + SPLANE, logits);
        s2v_read_kernel<<<dim3(4, BB), 256, 0, stream>>>(logits, stateT_hi,
                                                         stateT_hi + SPLANE, rpart);
    }
    s2v_out_kernel<<<BB, 256, 0, stream>>>(hvec, rpart, W_out, b_out, out);
}